// Round 12
// baseline (148.755 us; speedup 1.0000x reference)
//
#include <hip/hip_runtime.h>
#include <math.h>

#define LSEQ 2048
#define HDIM 1024
#define BATCH 4
#define ROWS (BATCH * LSEQ)   // 8192
#define NBAND 9               // |i-j| <= 4

typedef __attribute__((ext_vector_type(8))) short bf16x8;
typedef __attribute__((ext_vector_type(4))) float f32x4;
typedef __attribute__((ext_vector_type(8))) unsigned short u16x8;

#define AS3 __attribute__((address_space(3)))
#define AS1 __attribute__((address_space(1)))

__device__ __forceinline__ void gload16(const void* gp, void* lp) {
    __builtin_amdgcn_global_load_lds((AS1 const unsigned*)gp, (AS3 unsigned*)lp, 16, 0, 0);
}

__device__ __forceinline__ unsigned short f2bf(float x) {
    unsigned u = __float_as_uint(x);
    u += 0x7FFFu + ((u >> 16) & 1u);
    return (unsigned short)(u >> 16);
}
__device__ __forceinline__ float bf2f(unsigned short h) {
    return __uint_as_float(((unsigned)h) << 16);
}

// split 8 fp32 (two float4) into bf16 hi/lo fragments
__device__ __forceinline__ void split8(float4 a, float4 b, bf16x8& hi, bf16x8& lo) {
    float v[8] = {a.x, a.y, a.z, a.w, b.x, b.y, b.z, b.w};
#pragma unroll
    for (int j = 0; j < 8; j++) {
        unsigned short h = f2bf(v[j]);
        hi[j] = (short)h;
        lo[j] = (short)f2bf(v[j] - bf2f(h));
    }
}

// ---------------------------------------------------------------------------
// w partial: wpart[blk][c] = sum_{h in blk range} Wk[h,c] * bq[h] (64 blocks)
// ---------------------------------------------------------------------------
__global__ __launch_bounds__(256) void wpart_kernel(const float* __restrict__ Wk,
                                                    const float* __restrict__ bq,
                                                    float* __restrict__ wpart) {
    const int b = blockIdx.x;
    const int c0 = threadIdx.x * 4;
    float4 acc = {0.f, 0.f, 0.f, 0.f};
#pragma unroll
    for (int hh = 0; hh < 16; hh++) {
        const int h = b * 16 + hh;
        const float s = bq[h];
        float4 v = *reinterpret_cast<const float4*>(&Wk[(size_t)h * HDIM + c0]);
        acc.x += v.x * s; acc.y += v.y * s; acc.z += v.z * s; acc.w += v.w * s;
    }
    *reinterpret_cast<float4*>(&wpart[(size_t)b * HDIM + c0]) = acc;
}

__global__ __launch_bounds__(256) void wreduce(const float* __restrict__ wpart,
                                               float* __restrict__ w) {
    const int c = blockIdx.x * 256 + threadIdx.x;
    float s = 0.f;
#pragma unroll
    for (int b = 0; b < 64; b++) s += wpart[(size_t)b * HDIM + c];
    w[c] = s;
}

// ---------------------------------------------------------------------------
// Transposed split-convert: dst[n,h] = split(src[h,n]); z=0 -> Wq, z=1 -> Wk
// ---------------------------------------------------------------------------
__global__ __launch_bounds__(256) void transpose_convert(const float* __restrict__ Wq,
                                                         const float* __restrict__ Wk,
                                                         unsigned short* __restrict__ qhi,
                                                         unsigned short* __restrict__ qlo,
                                                         unsigned short* __restrict__ khi,
                                                         unsigned short* __restrict__ klo) {
    __shared__ float tile[64][65];
    const int z = blockIdx.z;
    const float* src = z ? Wk : Wq;
    unsigned short* dh = z ? khi : qhi;
    unsigned short* dl = z ? klo : qlo;
    const int n0 = blockIdx.x * 64;
    const int h0 = blockIdx.y * 64;
    const int tid = threadIdx.x;

#pragma unroll
    for (int p = 0; p < 4; p++) {
        const int h = p * 16 + (tid >> 4);
        const int n = (tid & 15) * 4;
        float4 v = *reinterpret_cast<const float4*>(&src[(size_t)(h0 + h) * HDIM + n0 + n]);
        tile[h][n + 0] = v.x; tile[h][n + 1] = v.y; tile[h][n + 2] = v.z; tile[h][n + 3] = v.w;
    }
    __syncthreads();
#pragma unroll
    for (int p = 0; p < 2; p++) {
        const int n = p * 32 + (tid >> 3);
        const int h = (tid & 7) * 8;
        u16x8 hv, lv;
#pragma unroll
        for (int j = 0; j < 8; j++) {
            float x = tile[h + j][n];
            unsigned short hb = f2bf(x);
            hv[j] = hb;
            lv[j] = f2bf(x - bf2f(hb));
        }
        *reinterpret_cast<u16x8*>(&dh[(size_t)(n0 + n) * HDIM + h0 + h]) = hv;
        *reinterpret_cast<u16x8*>(&dl[(size_t)(n0 + n) * HDIM + h0 + h]) = lv;
    }
}

// ---------------------------------------------------------------------------
// Fused: split-convert k rows to bf16 hi/lo AND beta[r] = k_r . w
// ---------------------------------------------------------------------------
__global__ __launch_bounds__(256) void convert_k_beta(const float* __restrict__ k,
                                                      const float* __restrict__ w,
                                                      unsigned short* __restrict__ Xhi,
                                                      unsigned short* __restrict__ Xlo,
                                                      float* __restrict__ beta) {
    __shared__ float red[4];
    const int r = blockIdx.x;
    const int t = threadIdx.x;
    float4 v = *reinterpret_cast<const float4*>(&k[(size_t)r * HDIM + t * 4]);
    float4 wv = *reinterpret_cast<const float4*>(&w[t * 4]);
    ushort4 h, l;
    h.x = f2bf(v.x); l.x = f2bf(v.x - bf2f(h.x));
    h.y = f2bf(v.y); l.y = f2bf(v.y - bf2f(h.y));
    h.z = f2bf(v.z); l.z = f2bf(v.z - bf2f(h.z));
    h.w = f2bf(v.w); l.w = f2bf(v.w - bf2f(h.w));
    reinterpret_cast<ushort4*>(Xhi)[(size_t)r * 256 + t] = h;
    reinterpret_cast<ushort4*>(Xlo)[(size_t)r * 256 + t] = l;
    float d = v.x * wv.x + v.y * wv.y + v.z * wv.z + v.w * wv.w;
#pragma unroll
    for (int off = 32; off > 0; off >>= 1) d += __shfl_xor(d, off, 64);
    if ((t & 63) == 0) red[t >> 6] = d;
    __syncthreads();
    if (t == 0) beta[r] = red[0] + red[1] + red[2] + red[3];
}

// ---------------------------------------------------------------------------
// Split-K GEMM for M = WqT @ WkT^T: grid (8,8,4), K-slice 256 each.
// ---------------------------------------------------------------------------
__global__ __launch_bounds__(256, 2) void gemm_part(
        const unsigned short* __restrict__ Ahi, const unsigned short* __restrict__ Alo,
        const unsigned short* __restrict__ Bhi, const unsigned short* __restrict__ Blo,
        float* __restrict__ Cparts) {
    __shared__ unsigned short sh[4 * 4096];
    const int AHI = 0, ALO = 4096, BHI = 8192, BLO = 12288;
    const int tid = threadIdx.x;
    const int w = tid >> 6, l = tid & 63;
    const int wr = w >> 1, wc = w & 1;
    const int row0 = blockIdx.x * 128, col0 = blockIdx.y * 128;
    const int kbeg = blockIdx.z * 256;
    float* C = Cparts + (size_t)blockIdx.z * HDIM * HDIM;
    const int srow0 = (l >> 2), scbp = l & 3;

    f32x4 acc[4][4];
#pragma unroll
    for (int m = 0; m < 4; m++)
#pragma unroll
        for (int n = 0; n < 4; n++) acc[m][n] = (f32x4){0.f, 0.f, 0.f, 0.f};

    const int fr_a[4] = {wr * 64 + (l & 15), wr * 64 + 16 + (l & 15),
                         wr * 64 + 32 + (l & 15), wr * 64 + 48 + (l & 15)};
    const int fr_b[4] = {wc * 64 + (l & 15), wc * 64 + 16 + (l & 15),
                         wc * 64 + 32 + (l & 15), wc * 64 + 48 + (l & 15)};
    const int cb = l >> 4;

    for (int k0 = kbeg; k0 < kbeg + 256; k0 += 32) {
#pragma unroll
        for (int i = 0; i < 2; i++) {
            const int seg = i * 4 + w;
            const int row = seg * 16 + srow0;
            const int cbs = scbp ^ ((row >> 1) & 3);
            gload16(Ahi + (size_t)(row0 + row) * HDIM + k0 + cbs * 8, &sh[AHI + seg * 512]);
            gload16(Alo + (size_t)(row0 + row) * HDIM + k0 + cbs * 8, &sh[ALO + seg * 512]);
            gload16(Bhi + (size_t)(col0 + row) * HDIM + k0 + cbs * 8, &sh[BHI + seg * 512]);
            gload16(Blo + (size_t)(col0 + row) * HDIM + k0 + cbs * 8, &sh[BLO + seg * 512]);
        }
        __syncthreads();

        bf16x8 ah[4], al[4], bh[4], bl[4];
#pragma unroll
        for (int m = 0; m < 4; m++) {
            const int r = fr_a[m];
            const int cbs = cb ^ ((r >> 1) & 3);
            ah[m] = *reinterpret_cast<const bf16x8*>(&sh[AHI + r * 32 + cbs * 8]);
            al[m] = *reinterpret_cast<const bf16x8*>(&sh[ALO + r * 32 + cbs * 8]);
        }
#pragma unroll
        for (int n = 0; n < 4; n++) {
            const int r = fr_b[n];
            const int cbs = cb ^ ((r >> 1) & 3);
            bh[n] = *reinterpret_cast<const bf16x8*>(&sh[BHI + r * 32 + cbs * 8]);
            bl[n] = *reinterpret_cast<const bf16x8*>(&sh[BLO + r * 32 + cbs * 8]);
        }
#pragma unroll
        for (int m = 0; m < 4; m++)
#pragma unroll
            for (int n = 0; n < 4; n++) {
                acc[m][n] = __builtin_amdgcn_mfma_f32_16x16x32_bf16(ah[m], bh[n], acc[m][n], 0, 0, 0);
                acc[m][n] = __builtin_amdgcn_mfma_f32_16x16x32_bf16(ah[m], bl[n], acc[m][n], 0, 0, 0);
                acc[m][n] = __builtin_amdgcn_mfma_f32_16x16x32_bf16(al[m], bh[n], acc[m][n], 0, 0, 0);
            }
        __syncthreads();
    }

    const int lcol = l & 15, lrow = (l >> 4) * 4;
#pragma unroll
    for (int n = 0; n < 4; n++) {
        const int colg = col0 + wc * 64 + n * 16 + lcol;
#pragma unroll
        for (int m = 0; m < 4; m++) {
            const int rowg = row0 + wr * 64 + m * 16 + lrow;
#pragma unroll
            for (int v = 0; v < 4; v++)
                C[(size_t)(rowg + v) * HDIM + colg] = acc[m][n][v];
        }
    }
}

// ---------------------------------------------------------------------------
// Reduce 4 M-parts and split-convert to bf16 hi/lo.
// ---------------------------------------------------------------------------
__global__ __launch_bounds__(256) void reduceM_convert(const float* __restrict__ Mparts,
                                                       unsigned short* __restrict__ Mhi,
                                                       unsigned short* __restrict__ Mlo) {
    const int idx4 = blockIdx.x * 256 + threadIdx.x;
    float4 s = {0.f, 0.f, 0.f, 0.f};
#pragma unroll
    for (int z = 0; z < 4; z++) {
        float4 v = reinterpret_cast<const float4*>(Mparts + (size_t)z * HDIM * HDIM)[idx4];
        s.x += v.x; s.y += v.y; s.z += v.z; s.w += v.w;
    }
    ushort4 h, l;
    h.x = f2bf(s.x); l.x = f2bf(s.x - bf2f(h.x));
    h.y = f2bf(s.y); l.y = f2bf(s.y - bf2f(h.y));
    h.z = f2bf(s.z); l.z = f2bf(s.z - bf2f(h.z));
    h.w = f2bf(s.w); l.w = f2bf(s.w - bf2f(h.w));
    reinterpret_cast<ushort4*>(Mhi)[idx4] = h;
    reinterpret_cast<ushort4*>(Mlo)[idx4] = l;
}

// ---------------------------------------------------------------------------
// Big GEMM (t = K @ M^T), 128x128 tile, BK=32, 4 waves, double-buffered LDS
// (verified round 11). NATURAL block mapping (round-10 lesson: no swizzle).
// NEW: epilogue writes the bf16 hi/lo SPLIT of t (thi/tlo) instead of fp32 —
// bit-identical to the split band_mfma used to do per k-step, but computed
// once here. Same 32 MB write volume.
// ---------------------------------------------------------------------------
__global__ __launch_bounds__(256, 2) void gemm_t(
        const unsigned short* __restrict__ Ahi, const unsigned short* __restrict__ Alo,
        const unsigned short* __restrict__ Bhi, const unsigned short* __restrict__ Blo,
        unsigned short* __restrict__ Thi, unsigned short* __restrict__ Tlo) {
    __shared__ unsigned short sh[2][16384];   // 2 x 32 KB
    const int AHI = 0, ALO = 4096, BHI = 8192, BLO = 12288;
    const int tid = threadIdx.x;
    const int w = tid >> 6, l = tid & 63;
    const int wr = w >> 1, wc = w & 1;
    const int row0 = blockIdx.x * 128, col0 = blockIdx.y * 128;
    const int srow0 = (l >> 2), scbp = l & 3;

    f32x4 acc[4][4];
#pragma unroll
    for (int m = 0; m < 4; m++)
#pragma unroll
        for (int n = 0; n < 4; n++) acc[m][n] = (f32x4){0.f, 0.f, 0.f, 0.f};

    const int fr_a[4] = {wr * 64 + (l & 15), wr * 64 + 16 + (l & 15),
                         wr * 64 + 32 + (l & 15), wr * 64 + 48 + (l & 15)};
    const int fr_b[4] = {wc * 64 + (l & 15), wc * 64 + 16 + (l & 15),
                         wc * 64 + 32 + (l & 15), wc * 64 + 48 + (l & 15)};
    const int cb = l >> 4;

    auto stage = [&](int buf, int k0) {
#pragma unroll
        for (int i = 0; i < 2; i++) {
            const int seg = i * 4 + w;
            const int row = seg * 16 + srow0;
            const int cbs = scbp ^ ((row >> 1) & 3);
            gload16(Ahi + (size_t)(row0 + row) * HDIM + k0 + cbs * 8, &sh[buf][AHI + seg * 512]);
            gload16(Alo + (size_t)(row0 + row) * HDIM + k0 + cbs * 8, &sh[buf][ALO + seg * 512]);
            gload16(Bhi + (size_t)(col0 + row) * HDIM + k0 + cbs * 8, &sh[buf][BHI + seg * 512]);
            gload16(Blo + (size_t)(col0 + row) * HDIM + k0 + cbs * 8, &sh[buf][BLO + seg * 512]);
        }
    };
    auto compute = [&](int buf) {
        bf16x8 ah[4], al[4], bh[4], bl[4];
#pragma unroll
        for (int m = 0; m < 4; m++) {
            const int r = fr_a[m];
            const int cbs = cb ^ ((r >> 1) & 3);
            ah[m] = *reinterpret_cast<const bf16x8*>(&sh[buf][AHI + r * 32 + cbs * 8]);
            al[m] = *reinterpret_cast<const bf16x8*>(&sh[buf][ALO + r * 32 + cbs * 8]);
        }
#pragma unroll
        for (int n = 0; n < 4; n++) {
            const int r = fr_b[n];
            const int cbs = cb ^ ((r >> 1) & 3);
            bh[n] = *reinterpret_cast<const bf16x8*>(&sh[buf][BHI + r * 32 + cbs * 8]);
            bl[n] = *reinterpret_cast<const bf16x8*>(&sh[buf][BLO + r * 32 + cbs * 8]);
        }
#pragma unroll
        for (int m = 0; m < 4; m++)
#pragma unroll
            for (int n = 0; n < 4; n++) {
                acc[m][n] = __builtin_amdgcn_mfma_f32_16x16x32_bf16(ah[m], bh[n], acc[m][n], 0, 0, 0);
                acc[m][n] = __builtin_amdgcn_mfma_f32_16x16x32_bf16(ah[m], bl[n], acc[m][n], 0, 0, 0);
                acc[m][n] = __builtin_amdgcn_mfma_f32_16x16x32_bf16(al[m], bh[n], acc[m][n], 0, 0, 0);
            }
    };

    stage(0, 0);
    __syncthreads();
    int cur = 0;
    for (int t = 0; t < 31; t++) {
        stage(cur ^ 1, (t + 1) * 32);
        compute(cur);
        __syncthreads();
        cur ^= 1;
    }
    compute(cur);

    const int lcol = l & 15, lrow = (l >> 4) * 4;
#pragma unroll
    for (int n = 0; n < 4; n++) {
        const int colg = col0 + wc * 64 + n * 16 + lcol;
#pragma unroll
        for (int m = 0; m < 4; m++) {
            const int rowg = row0 + wr * 64 + m * 16 + lrow;
#pragma unroll
            for (int v = 0; v < 4; v++) {
                const float x = acc[m][n][v];
                const unsigned short h = f2bf(x);
                const size_t idx = (size_t)(rowg + v) * HDIM + colg;
                Thi[idx] = h;
                Tlo[idx] = f2bf(x - bf2f(h));
            }
        }
    }
}

// ---------------------------------------------------------------------------
// MFMA band kernel: block = 16 q-rows, 4 waves split K. t arrives PRE-SPLIT
// (thi/tlo bf16 from gemm_t) -> only q needs split8 here (1 of 3 calls).
// ---------------------------------------------------------------------------
__global__ __launch_bounds__(256) void band_mfma(const float* __restrict__ q,
                                                 const unsigned short* __restrict__ thi,
                                                 const unsigned short* __restrict__ tlo,
                                                 const float* __restrict__ beta,
                                                 float* __restrict__ band) {
    __shared__ float lds_c[4][16][33];
    const int tid = threadIdx.x;
    const int w = tid >> 6, l = tid & 63;
    const int r0 = blockIdx.x * 16;
    const int b = r0 >> 11;
    const int i0 = r0 & (LSEQ - 1);
    const int fr = l & 15;
    const int kb = (l >> 4) * 8;

    const float* qrow = q + (size_t)(r0 + fr) * HDIM;
    const size_t tb = (size_t)b * LSEQ * HDIM;

    const int j0 = i0 - 4 + fr;
    const int j1 = i0 + 12 + fr;
    const int j0c = min(max(j0, 0), LSEQ - 1);
    const int j1c = min(max(j1, 0), LSEQ - 1);
    const bool v0 = (j0 >= 0) && (j0 < LSEQ);
    const bool v1 = (j1 >= 0) && (j1 < LSEQ);
    const bool interior = (i0 >= 4) && (i0 + 19 < LSEQ);
    const bf16x8 bz = {0, 0, 0, 0, 0, 0, 0, 0};

    f32x4 c0 = {0.f, 0.f, 0.f, 0.f};
    f32x4 c1 = {0.f, 0.f, 0.f, 0.f};

#pragma unroll 2
    for (int ks = 0; ks < 8; ks++) {
        const int k0 = w * 256 + ks * 32 + kb;
        float4 qa = *reinterpret_cast<const float4*>(qrow + k0);
        float4 qb = *reinterpret_cast<const float4*>(qrow + k0 + 4);
        bf16x8 b0h = *reinterpret_cast<const bf16x8*>(&thi[tb + (size_t)j0c * HDIM + k0]);
        bf16x8 b0l = *reinterpret_cast<const bf16x8*>(&tlo[tb + (size_t)j0c * HDIM + k0]);
        bf16x8 b1h = *reinterpret_cast<const bf16x8*>(&thi[tb + (size_t)j1c * HDIM + k0]);
        bf16x8 b1l = *reinterpret_cast<const bf16x8*>(&tlo[tb + (size_t)j1c * HDIM + k0]);
        if (!interior) {                   // wave-uniform; 8/512 blocks
            if (!v0) { b0h = bz; b0l = bz; }
            if (!v1) { b1h = bz; b1l = bz; }
        }
        bf16x8 ah, al;
        split8(qa, qb, ah, al);
        c0 = __builtin_amdgcn_mfma_f32_16x16x32_bf16(ah, b0h, c0, 0, 0, 0);
        c0 = __builtin_amdgcn_mfma_f32_16x16x32_bf16(ah, b0l, c0, 0, 0, 0);
        c0 = __builtin_amdgcn_mfma_f32_16x16x32_bf16(al, b0h, c0, 0, 0, 0);
        c1 = __builtin_amdgcn_mfma_f32_16x16x32_bf16(ah, b1h, c1, 0, 0, 0);
        c1 = __builtin_amdgcn_mfma_f32_16x16x32_bf16(ah, b1l, c1, 0, 0, 0);
        c1 = __builtin_amdgcn_mfma_f32_16x16x32_bf16(al, b1h, c1, 0, 0, 0);
    }

#pragma unroll
    for (int v = 0; v < 4; v++) {
        lds_c[w][(l >> 4) * 4 + v][fr] = c0[v];
        lds_c[w][(l >> 4) * 4 + v][16 + fr] = c1[v];
    }
    __syncthreads();

#pragma unroll
    for (int e = tid; e < 512; e += 256) {
        const int rr = e >> 5, cc = e & 31;
        lds_c[0][rr][cc] = lds_c[0][rr][cc] + lds_c[1][rr][cc] +
                           lds_c[2][rr][cc] + lds_c[3][rr][cc];
    }
    __syncthreads();

    if (tid < 16) {
        const int il = i0 + tid;
        const int ig = r0 + tid;
        float lg[NBAND];
#pragma unroll
        for (int d = 0; d < NBAND; d++) {
            const int j = il + d - 4;
            lg[d] = (j >= 0 && j < LSEQ)
                    ? lds_c[0][tid][tid + d] + beta[(size_t)b * LSEQ + j]
                    : -1e30f;
        }
        float m = -1e30f;
#pragma unroll
        for (int d = 0; d < NBAND; d++) m = fmaxf(m, lg[d]);
        float p[NBAND], s = 0.f;
#pragma unroll
        for (int d = 0; d < NBAND; d++) { p[d] = expf(lg[d] - m); s += p[d]; }
        const float inv = 1.f / s;
#pragma unroll
        for (int d = 0; d < NBAND; d++) band[(size_t)ig * NBAND + d] = p[d] * inv;
    }
}

// ---------------------------------------------------------------------------
// Expand band probs into dense [B, L, L] output.
// ---------------------------------------------------------------------------
__global__ __launch_bounds__(256) void expand_band(const float* __restrict__ band,
                                                   float* __restrict__ out) {
    const size_t idx4 = (size_t)blockIdx.x * 256 + threadIdx.x;
    const size_t flat = idx4 * 4;
    const int j0 = (int)(flat & (LSEQ - 1));
    const size_t row = flat >> 11;
    const int i = (int)(row & (LSEQ - 1));
    float v[4];
#pragma unroll
    for (int s = 0; s < 4; s++) {
        const int dj = (j0 + s) - i + 4;
        v[s] = (dj >= 0 && dj < NBAND) ? band[row * NBAND + dj] : 0.f;
    }
    float4 o = {v[0], v[1], v[2], v[3]};
    *reinterpret_cast<float4*>(&out[flat]) = o;
}

// ---------------------------------------------------------------------------
// Fallback fp32 path (ws too small).
// ---------------------------------------------------------------------------
__global__ __launch_bounds__(256) void gemm_nt_bias(const float* __restrict__ A,
                                                    const float* __restrict__ B,
                                                    const float* __restrict__ bias,
                                                    float* __restrict__ C) {
    __shared__ float As[8][132];
    __shared__ float Bs[8][132];
    const int tid = threadIdx.x;
    const int row0 = blockIdx.x * 128, col0 = blockIdx.y * 128;
    const int lr = tid >> 1, lc = (tid & 1) * 4;
    const int tx = tid & 15, ty = tid >> 4;
    float acc[2][2][4][4];
#pragma unroll
    for (int a = 0; a < 2; a++)
#pragma unroll
        for (int b = 0; b < 2; b++)
#pragma unroll
            for (int c = 0; c < 4; c++)
#pragma unroll
                for (int d = 0; d < 4; d++) acc[a][b][c][d] = 0.f;
    for (int k0 = 0; k0 < HDIM; k0 += 8) {
        float4 av = *reinterpret_cast<const float4*>(&A[(size_t)(row0 + lr) * HDIM + k0 + lc]);
        float4 bv = *reinterpret_cast<const float4*>(&B[(size_t)(col0 + lr) * HDIM + k0 + lc]);
        __syncthreads();
        As[lc + 0][lr] = av.x; As[lc + 1][lr] = av.y; As[lc + 2][lr] = av.z; As[lc + 3][lr] = av.w;
        Bs[lc + 0][lr] = bv.x; Bs[lc + 1][lr] = bv.y; Bs[lc + 2][lr] = bv.z; Bs[lc + 3][lr] = bv.w;
        __syncthreads();
#pragma unroll
        for (int kk = 0; kk < 8; kk++) {
            float4 a0 = *reinterpret_cast<const float4*>(&As[kk][ty * 4]);
            float4 a1 = *reinterpret_cast<const float4*>(&As[kk][64 + ty * 4]);
            float4 b0 = *reinterpret_cast<const float4*>(&Bs[kk][tx * 4]);
            float4 b1 = *reinterpret_cast<const float4*>(&Bs[kk][64 + tx * 4]);
            float am[2][4] = {{a0.x, a0.y, a0.z, a0.w}, {a1.x, a1.y, a1.z, a1.w}};
            float bw[2][4] = {{b0.x, b0.y, b0.z, b0.w}, {b1.x, b1.y, b1.z, b1.w}};
#pragma unroll
            for (int mi = 0; mi < 2; mi++)
#pragma unroll
                for (int ni = 0; ni < 2; ni++)
#pragma unroll
                    for (int mm = 0; mm < 4; mm++)
#pragma unroll
                        for (int nn = 0; nn < 4; nn++)
                            acc[mi][ni][mm][nn] += am[mi][mm] * bw[ni][nn];
        }
    }
#pragma unroll
    for (int mi = 0; mi < 2; mi++)
#pragma unroll
        for (int mm = 0; mm < 4; mm++) {
            const int r = row0 + mi * 64 + ty * 4 + mm;
#pragma unroll
            for (int ni = 0; ni < 2; ni++) {
                const int c = col0 + ni * 64 + tx * 4;
                float4 o;
                o.x = acc[mi][ni][mm][0] + bias[c + 0];
                o.y = acc[mi][ni][mm][1] + bias[c + 1];
                o.z = acc[mi][ni][mm][2] + bias[c + 2];
                o.w = acc[mi][ni][mm][3] + bias[c + 3];
                *reinterpret_cast<float4*>(&C[(size_t)r * HDIM + c]) = o;
            }
        }
}

__global__ __launch_bounds__(256) void band_softmax(const float* __restrict__ qs,
                                                    const float* __restrict__ ks,
                                                    float* __restrict__ band) {
    const int wave = threadIdx.x >> 6;
    const int lane = threadIdx.x & 63;
    const int r = blockIdx.x * 4 + wave;
    const int b = r >> 11;
    const int i = r & (LSEQ - 1);
    const float* qrow = qs + (size_t)r * HDIM;
    const float* kbase = ks + (size_t)b * LSEQ * HDIM;
    float acc[NBAND];
#pragma unroll
    for (int d = 0; d < NBAND; d++) acc[d] = 0.f;
    for (int h = lane; h < HDIM; h += 64) {
        const float qv = qrow[h];
#pragma unroll
        for (int d = 0; d < NBAND; d++) {
            const int j = i + d - 4;
            if (j >= 0 && j < LSEQ)
                acc[d] += qv * kbase[(size_t)j * HDIM + h];
        }
    }
#pragma unroll
    for (int d = 0; d < NBAND; d++) {
        float v = acc[d];
#pragma unroll
        for (int off = 32; off > 0; off >>= 1) v += __shfl_xor(v, off, 64);
        acc[d] = v;
    }
    if (lane == 0) {
        float m = -1e30f;
#pragma unroll
        for (int d = 0; d < NBAND; d++) {
            const int j = i + d - 4;
            if (j >= 0 && j < LSEQ) m = fmaxf(m, acc[d]);
        }
        float p[NBAND];
        float s = 0.f;
#pragma unroll
        for (int d = 0; d < NBAND; d++) {
            const int j = i + d - 4;
            p[d] = (j >= 0 && j < LSEQ) ? expf(acc[d] - m) : 0.f;
            s += p[d];
        }
        const float inv = 1.f / s;
#pragma unroll
        for (int d = 0; d < NBAND; d++) band[(size_t)r * NBAND + d] = p[d] * inv;
    }
}

extern "C" void kernel_launch(void* const* d_in, const int* in_sizes, int n_in,
                              void* d_out, int out_size, void* d_ws, size_t ws_size,
                              hipStream_t stream) {
    const float* q  = (const float*)d_in[0];
    const float* k  = (const float*)d_in[1];
    const float* Wq = (const float*)d_in[2];
    const float* bq = (const float*)d_in[3];
    const float* Wk = (const float*)d_in[4];
    const float* bk = (const float*)d_in[5];
    float* out = (float*)d_out;

    // ---- workspace layout (~36.6 MB, proven available) ----
    const size_t bandB = (size_t)ROWS * NBAND * sizeof(float);
    char* p = (char*)d_ws;
    float* band = (float*)p;                 p += bandB;
    unsigned short* Xhi = (unsigned short*)p; p += (size_t)ROWS * HDIM * 2;   // 16 MB
    unsigned short* Xlo = (unsigned short*)p; p += (size_t)ROWS * HDIM * 2;   // 16 MB
    unsigned short* Mhi = (unsigned short*)p; p += (size_t)HDIM * HDIM * 2;   // 2 MB
    unsigned short* Mlo = (unsigned short*)p; p += (size_t)HDIM * HDIM * 2;   // 2 MB
    float* w        = (float*)p;             p += HDIM * sizeof(float);
    float* wpart    = (float*)p;             p += 64 * HDIM * sizeof(float);
    float* beta     = (float*)p;             p += ROWS * sizeof(float);
    const size_t need = (size_t)(p - (char*)d_ws);

    // WqT/WkT bf16 splits live in the (not-yet-written) Xhi region
    unsigned short* WqTh = Xhi;
    unsigned short* WqTl = Xhi + (size_t)HDIM * HDIM;
    unsigned short* WkTh = Xhi + 2 * (size_t)HDIM * HDIM;
    unsigned short* WkTl = Xhi + 3 * (size_t)HDIM * HDIM;

    // d_out scratch (64 MB): thi [0,16MB), tlo [16,32MB), Mparts [32,48MB).
    // All dead before expand_band overwrites d_out.
    unsigned short* thi = (unsigned short*)out;                       // 16 MB
    unsigned short* tlo = thi + (size_t)ROWS * HDIM;                  // 16 MB
    float* Mparts = (float*)((char*)out + 32ull * 1024 * 1024);       // 16 MB

    if (ws_size >= need) {
        wpart_kernel<<<64, 256, 0, stream>>>(Wk, bq, wpart);
        wreduce<<<4, 256, 0, stream>>>(wpart, w);
        dim3 tg(16, 16, 2);
        transpose_convert<<<tg, 256, 0, stream>>>(Wq, Wk, WqTh, WqTl, WkTh, WkTl);
        dim3 mg(8, 8, 4);
        gemm_part<<<mg, 256, 0, stream>>>(WqTh, WqTl, WkTh, WkTl, Mparts);
        reduceM_convert<<<HDIM * HDIM / 4 / 256, 256, 0, stream>>>(Mparts, Mhi, Mlo);
        convert_k_beta<<<ROWS, 256, 0, stream>>>(k, w, Xhi, Xlo, beta);
        dim3 gg(ROWS / 128, HDIM / 128);
        gemm_t<<<gg, 256, 0, stream>>>(Xhi, Xlo, Mhi, Mlo, thi, tlo);
        band_mfma<<<ROWS / 16, 256, 0, stream>>>(q, thi, tlo, beta, band);
        expand_band<<<(size_t)ROWS * LSEQ / 4 / 256, 256, 0, stream>>>(band, out);
    } else {
        float* qs = out;
        float* ks = out + (size_t)ROWS * HDIM;
        dim3 gg(ROWS / 128, HDIM / 128);
        gemm_nt_bias<<<gg, 256, 0, stream>>>(q, Wq, bq, qs);
        gemm_nt_bias<<<gg, 256, 0, stream>>>(k, Wk, bk, ks);
        band_softmax<<<ROWS / 4, 256, 0, stream>>>(qs, ks, band);
        expand_band<<<(size_t)ROWS * LSEQ / 4 / 256, 256, 0, stream>>>(band, out);
    }
}

// Round 13
// 140.562 us; speedup vs baseline: 1.0583x; 1.0583x over previous
//
#include <hip/hip_runtime.h>
#include <math.h>

#define LSEQ 2048
#define HDIM 1024
#define BATCH 4
#define ROWS (BATCH * LSEQ)   // 8192
#define NBAND 9               // |i-j| <= 4

typedef __attribute__((ext_vector_type(8))) short bf16x8;
typedef __attribute__((ext_vector_type(4))) float f32x4;
typedef __attribute__((ext_vector_type(8))) unsigned short u16x8;
typedef __attribute__((ext_vector_type(4))) unsigned uintx4;

#define AS3 __attribute__((address_space(3)))
#define AS1 __attribute__((address_space(1)))

__device__ __forceinline__ void gload16(const void* gp, void* lp) {
    __builtin_amdgcn_global_load_lds((AS1 const unsigned*)gp, (AS3 unsigned*)lp, 16, 0, 0);
}

__device__ __forceinline__ unsigned short f2bf(float x) {
    unsigned u = __float_as_uint(x);
    u += 0x7FFFu + ((u >> 16) & 1u);
    return (unsigned short)(u >> 16);
}
__device__ __forceinline__ float bf2f(unsigned short h) {
    return __uint_as_float(((unsigned)h) << 16);
}

// split 8 fp32 (two float4) into bf16 hi/lo fragments
__device__ __forceinline__ void split8(float4 a, float4 b, bf16x8& hi, bf16x8& lo) {
    float v[8] = {a.x, a.y, a.z, a.w, b.x, b.y, b.z, b.w};
#pragma unroll
    for (int j = 0; j < 8; j++) {
        unsigned short h = f2bf(v[j]);
        hi[j] = (short)h;
        lo[j] = (short)f2bf(v[j] - bf2f(h));
    }
}

// unpack 8 packed u32 (hi|lo<<16) into hi/lo bf16x8 fragments via v_perm
__device__ __forceinline__ void unpack8(uintx4 w0, uintx4 w1, bf16x8& hi, bf16x8& lo) {
    union { bf16x8 v; uintx4 u; } H, L;
    H.u[0] = __builtin_amdgcn_perm(w0[1], w0[0], 0x05040100u);
    H.u[1] = __builtin_amdgcn_perm(w0[3], w0[2], 0x05040100u);
    H.u[2] = __builtin_amdgcn_perm(w1[1], w1[0], 0x05040100u);
    H.u[3] = __builtin_amdgcn_perm(w1[3], w1[2], 0x05040100u);
    L.u[0] = __builtin_amdgcn_perm(w0[1], w0[0], 0x07060302u);
    L.u[1] = __builtin_amdgcn_perm(w0[3], w0[2], 0x07060302u);
    L.u[2] = __builtin_amdgcn_perm(w1[1], w1[0], 0x07060302u);
    L.u[3] = __builtin_amdgcn_perm(w1[3], w1[2], 0x07060302u);
    hi = H.v; lo = L.v;
}

// ---------------------------------------------------------------------------
// w partial: wpart[blk][c] = sum_{h in blk range} Wk[h,c] * bq[h] (64 blocks)
// ---------------------------------------------------------------------------
__global__ __launch_bounds__(256) void wpart_kernel(const float* __restrict__ Wk,
                                                    const float* __restrict__ bq,
                                                    float* __restrict__ wpart) {
    const int b = blockIdx.x;
    const int c0 = threadIdx.x * 4;
    float4 acc = {0.f, 0.f, 0.f, 0.f};
#pragma unroll
    for (int hh = 0; hh < 16; hh++) {
        const int h = b * 16 + hh;
        const float s = bq[h];
        float4 v = *reinterpret_cast<const float4*>(&Wk[(size_t)h * HDIM + c0]);
        acc.x += v.x * s; acc.y += v.y * s; acc.z += v.z * s; acc.w += v.w * s;
    }
    *reinterpret_cast<float4*>(&wpart[(size_t)b * HDIM + c0]) = acc;
}

__global__ __launch_bounds__(256) void wreduce(const float* __restrict__ wpart,
                                               float* __restrict__ w) {
    const int c = blockIdx.x * 256 + threadIdx.x;
    float s = 0.f;
#pragma unroll
    for (int b = 0; b < 64; b++) s += wpart[(size_t)b * HDIM + c];
    w[c] = s;
}

// ---------------------------------------------------------------------------
// Transposed split-convert: dst[n,h] = split(src[h,n]); z=0 -> Wq, z=1 -> Wk
// ---------------------------------------------------------------------------
__global__ __launch_bounds__(256) void transpose_convert(const float* __restrict__ Wq,
                                                         const float* __restrict__ Wk,
                                                         unsigned short* __restrict__ qhi,
                                                         unsigned short* __restrict__ qlo,
                                                         unsigned short* __restrict__ khi,
                                                         unsigned short* __restrict__ klo) {
    __shared__ float tile[64][65];
    const int z = blockIdx.z;
    const float* src = z ? Wk : Wq;
    unsigned short* dh = z ? khi : qhi;
    unsigned short* dl = z ? klo : qlo;
    const int n0 = blockIdx.x * 64;
    const int h0 = blockIdx.y * 64;
    const int tid = threadIdx.x;

#pragma unroll
    for (int p = 0; p < 4; p++) {
        const int h = p * 16 + (tid >> 4);
        const int n = (tid & 15) * 4;
        float4 v = *reinterpret_cast<const float4*>(&src[(size_t)(h0 + h) * HDIM + n0 + n]);
        tile[h][n + 0] = v.x; tile[h][n + 1] = v.y; tile[h][n + 2] = v.z; tile[h][n + 3] = v.w;
    }
    __syncthreads();
#pragma unroll
    for (int p = 0; p < 2; p++) {
        const int n = p * 32 + (tid >> 3);
        const int h = (tid & 7) * 8;
        u16x8 hv, lv;
#pragma unroll
        for (int j = 0; j < 8; j++) {
            float x = tile[h + j][n];
            unsigned short hb = f2bf(x);
            hv[j] = hb;
            lv[j] = f2bf(x - bf2f(hb));
        }
        *reinterpret_cast<u16x8*>(&dh[(size_t)(n0 + n) * HDIM + h0 + h]) = hv;
        *reinterpret_cast<u16x8*>(&dl[(size_t)(n0 + n) * HDIM + h0 + h]) = lv;
    }
}

// ---------------------------------------------------------------------------
// Fused: split-convert k rows to bf16 hi/lo AND beta[r] = k_r . w
// ---------------------------------------------------------------------------
__global__ __launch_bounds__(256) void convert_k_beta(const float* __restrict__ k,
                                                      const float* __restrict__ w,
                                                      unsigned short* __restrict__ Xhi,
                                                      unsigned short* __restrict__ Xlo,
                                                      float* __restrict__ beta) {
    __shared__ float red[4];
    const int r = blockIdx.x;
    const int t = threadIdx.x;
    float4 v = *reinterpret_cast<const float4*>(&k[(size_t)r * HDIM + t * 4]);
    float4 wv = *reinterpret_cast<const float4*>(&w[t * 4]);
    ushort4 h, l;
    h.x = f2bf(v.x); l.x = f2bf(v.x - bf2f(h.x));
    h.y = f2bf(v.y); l.y = f2bf(v.y - bf2f(h.y));
    h.z = f2bf(v.z); l.z = f2bf(v.z - bf2f(h.z));
    h.w = f2bf(v.w); l.w = f2bf(v.w - bf2f(h.w));
    reinterpret_cast<ushort4*>(Xhi)[(size_t)r * 256 + t] = h;
    reinterpret_cast<ushort4*>(Xlo)[(size_t)r * 256 + t] = l;
    float d = v.x * wv.x + v.y * wv.y + v.z * wv.z + v.w * wv.w;
#pragma unroll
    for (int off = 32; off > 0; off >>= 1) d += __shfl_xor(d, off, 64);
    if ((t & 63) == 0) red[t >> 6] = d;
    __syncthreads();
    if (t == 0) beta[r] = red[0] + red[1] + red[2] + red[3];
}

// ---------------------------------------------------------------------------
// Split-K GEMM for M = WqT @ WkT^T: grid (8,8,4), K-slice 256 each.
// ---------------------------------------------------------------------------
__global__ __launch_bounds__(256, 2) void gemm_part(
        const unsigned short* __restrict__ Ahi, const unsigned short* __restrict__ Alo,
        const unsigned short* __restrict__ Bhi, const unsigned short* __restrict__ Blo,
        float* __restrict__ Cparts) {
    __shared__ unsigned short sh[4 * 4096];
    const int AHI = 0, ALO = 4096, BHI = 8192, BLO = 12288;
    const int tid = threadIdx.x;
    const int w = tid >> 6, l = tid & 63;
    const int wr = w >> 1, wc = w & 1;
    const int row0 = blockIdx.x * 128, col0 = blockIdx.y * 128;
    const int kbeg = blockIdx.z * 256;
    float* C = Cparts + (size_t)blockIdx.z * HDIM * HDIM;
    const int srow0 = (l >> 2), scbp = l & 3;

    f32x4 acc[4][4];
#pragma unroll
    for (int m = 0; m < 4; m++)
#pragma unroll
        for (int n = 0; n < 4; n++) acc[m][n] = (f32x4){0.f, 0.f, 0.f, 0.f};

    const int fr_a[4] = {wr * 64 + (l & 15), wr * 64 + 16 + (l & 15),
                         wr * 64 + 32 + (l & 15), wr * 64 + 48 + (l & 15)};
    const int fr_b[4] = {wc * 64 + (l & 15), wc * 64 + 16 + (l & 15),
                         wc * 64 + 32 + (l & 15), wc * 64 + 48 + (l & 15)};
    const int cb = l >> 4;

    for (int k0 = kbeg; k0 < kbeg + 256; k0 += 32) {
#pragma unroll
        for (int i = 0; i < 2; i++) {
            const int seg = i * 4 + w;
            const int row = seg * 16 + srow0;
            const int cbs = scbp ^ ((row >> 1) & 3);
            gload16(Ahi + (size_t)(row0 + row) * HDIM + k0 + cbs * 8, &sh[AHI + seg * 512]);
            gload16(Alo + (size_t)(row0 + row) * HDIM + k0 + cbs * 8, &sh[ALO + seg * 512]);
            gload16(Bhi + (size_t)(col0 + row) * HDIM + k0 + cbs * 8, &sh[BHI + seg * 512]);
            gload16(Blo + (size_t)(col0 + row) * HDIM + k0 + cbs * 8, &sh[BLO + seg * 512]);
        }
        __syncthreads();

        bf16x8 ah[4], al[4], bh[4], bl[4];
#pragma unroll
        for (int m = 0; m < 4; m++) {
            const int r = fr_a[m];
            const int cbs = cb ^ ((r >> 1) & 3);
            ah[m] = *reinterpret_cast<const bf16x8*>(&sh[AHI + r * 32 + cbs * 8]);
            al[m] = *reinterpret_cast<const bf16x8*>(&sh[ALO + r * 32 + cbs * 8]);
        }
#pragma unroll
        for (int n = 0; n < 4; n++) {
            const int r = fr_b[n];
            const int cbs = cb ^ ((r >> 1) & 3);
            bh[n] = *reinterpret_cast<const bf16x8*>(&sh[BHI + r * 32 + cbs * 8]);
            bl[n] = *reinterpret_cast<const bf16x8*>(&sh[BLO + r * 32 + cbs * 8]);
        }
#pragma unroll
        for (int m = 0; m < 4; m++)
#pragma unroll
            for (int n = 0; n < 4; n++) {
                acc[m][n] = __builtin_amdgcn_mfma_f32_16x16x32_bf16(ah[m], bh[n], acc[m][n], 0, 0, 0);
                acc[m][n] = __builtin_amdgcn_mfma_f32_16x16x32_bf16(ah[m], bl[n], acc[m][n], 0, 0, 0);
                acc[m][n] = __builtin_amdgcn_mfma_f32_16x16x32_bf16(al[m], bh[n], acc[m][n], 0, 0, 0);
            }
        __syncthreads();
    }

    const int lcol = l & 15, lrow = (l >> 4) * 4;
#pragma unroll
    for (int n = 0; n < 4; n++) {
        const int colg = col0 + wc * 64 + n * 16 + lcol;
#pragma unroll
        for (int m = 0; m < 4; m++) {
            const int rowg = row0 + wr * 64 + m * 16 + lrow;
#pragma unroll
            for (int v = 0; v < 4; v++)
                C[(size_t)(rowg + v) * HDIM + colg] = acc[m][n][v];
        }
    }
}

// ---------------------------------------------------------------------------
// Reduce 4 M-parts and split-convert to bf16 hi/lo.
// ---------------------------------------------------------------------------
__global__ __launch_bounds__(256) void reduceM_convert(const float* __restrict__ Mparts,
                                                       unsigned short* __restrict__ Mhi,
                                                       unsigned short* __restrict__ Mlo) {
    const int idx4 = blockIdx.x * 256 + threadIdx.x;
    float4 s = {0.f, 0.f, 0.f, 0.f};
#pragma unroll
    for (int z = 0; z < 4; z++) {
        float4 v = reinterpret_cast<const float4*>(Mparts + (size_t)z * HDIM * HDIM)[idx4];
        s.x += v.x; s.y += v.y; s.z += v.z; s.w += v.w;
    }
    ushort4 h, l;
    h.x = f2bf(s.x); l.x = f2bf(s.x - bf2f(h.x));
    h.y = f2bf(s.y); l.y = f2bf(s.y - bf2f(h.y));
    h.z = f2bf(s.z); l.z = f2bf(s.z - bf2f(h.z));
    h.w = f2bf(s.w); l.w = f2bf(s.w - bf2f(h.w));
    reinterpret_cast<ushort4*>(Mhi)[idx4] = h;
    reinterpret_cast<ushort4*>(Mlo)[idx4] = l;
}

// ---------------------------------------------------------------------------
// Big GEMM (t = K @ M^T), 128x128 tile, BK=32, 4 waves, double-buffered LDS
// (verified round 11). NATURAL block mapping (round-10 lesson: no swizzle).
// Epilogue writes ONE packed u32 per element: (bf16hi | bf16lo<<16) — 4-byte
// store granularity (round-12 lesson: 2B scalar stores to two arrays caused
// 2.3x write amplification via partial-sector RMW).
// ---------------------------------------------------------------------------
__global__ __launch_bounds__(256, 2) void gemm_t(
        const unsigned short* __restrict__ Ahi, const unsigned short* __restrict__ Alo,
        const unsigned short* __restrict__ Bhi, const unsigned short* __restrict__ Blo,
        unsigned* __restrict__ Tpack) {
    __shared__ unsigned short sh[2][16384];   // 2 x 32 KB
    const int AHI = 0, ALO = 4096, BHI = 8192, BLO = 12288;
    const int tid = threadIdx.x;
    const int w = tid >> 6, l = tid & 63;
    const int wr = w >> 1, wc = w & 1;
    const int row0 = blockIdx.x * 128, col0 = blockIdx.y * 128;
    const int srow0 = (l >> 2), scbp = l & 3;

    f32x4 acc[4][4];
#pragma unroll
    for (int m = 0; m < 4; m++)
#pragma unroll
        for (int n = 0; n < 4; n++) acc[m][n] = (f32x4){0.f, 0.f, 0.f, 0.f};

    const int fr_a[4] = {wr * 64 + (l & 15), wr * 64 + 16 + (l & 15),
                         wr * 64 + 32 + (l & 15), wr * 64 + 48 + (l & 15)};
    const int fr_b[4] = {wc * 64 + (l & 15), wc * 64 + 16 + (l & 15),
                         wc * 64 + 32 + (l & 15), wc * 64 + 48 + (l & 15)};
    const int cb = l >> 4;

    auto stage = [&](int buf, int k0) {
#pragma unroll
        for (int i = 0; i < 2; i++) {
            const int seg = i * 4 + w;
            const int row = seg * 16 + srow0;
            const int cbs = scbp ^ ((row >> 1) & 3);
            gload16(Ahi + (size_t)(row0 + row) * HDIM + k0 + cbs * 8, &sh[buf][AHI + seg * 512]);
            gload16(Alo + (size_t)(row0 + row) * HDIM + k0 + cbs * 8, &sh[buf][ALO + seg * 512]);
            gload16(Bhi + (size_t)(col0 + row) * HDIM + k0 + cbs * 8, &sh[buf][BHI + seg * 512]);
            gload16(Blo + (size_t)(col0 + row) * HDIM + k0 + cbs * 8, &sh[buf][BLO + seg * 512]);
        }
    };
    auto compute = [&](int buf) {
        bf16x8 ah[4], al[4], bh[4], bl[4];
#pragma unroll
        for (int m = 0; m < 4; m++) {
            const int r = fr_a[m];
            const int cbs = cb ^ ((r >> 1) & 3);
            ah[m] = *reinterpret_cast<const bf16x8*>(&sh[buf][AHI + r * 32 + cbs * 8]);
            al[m] = *reinterpret_cast<const bf16x8*>(&sh[buf][ALO + r * 32 + cbs * 8]);
        }
#pragma unroll
        for (int n = 0; n < 4; n++) {
            const int r = fr_b[n];
            const int cbs = cb ^ ((r >> 1) & 3);
            bh[n] = *reinterpret_cast<const bf16x8*>(&sh[buf][BHI + r * 32 + cbs * 8]);
            bl[n] = *reinterpret_cast<const bf16x8*>(&sh[buf][BLO + r * 32 + cbs * 8]);
        }
#pragma unroll
        for (int m = 0; m < 4; m++)
#pragma unroll
            for (int n = 0; n < 4; n++) {
                acc[m][n] = __builtin_amdgcn_mfma_f32_16x16x32_bf16(ah[m], bh[n], acc[m][n], 0, 0, 0);
                acc[m][n] = __builtin_amdgcn_mfma_f32_16x16x32_bf16(ah[m], bl[n], acc[m][n], 0, 0, 0);
                acc[m][n] = __builtin_amdgcn_mfma_f32_16x16x32_bf16(al[m], bh[n], acc[m][n], 0, 0, 0);
            }
    };

    stage(0, 0);
    __syncthreads();
    int cur = 0;
    for (int t = 0; t < 31; t++) {
        stage(cur ^ 1, (t + 1) * 32);
        compute(cur);
        __syncthreads();
        cur ^= 1;
    }
    compute(cur);

    const int lcol = l & 15, lrow = (l >> 4) * 4;
#pragma unroll
    for (int n = 0; n < 4; n++) {
        const int colg = col0 + wc * 64 + n * 16 + lcol;
#pragma unroll
        for (int m = 0; m < 4; m++) {
            const int rowg = row0 + wr * 64 + m * 16 + lrow;
#pragma unroll
            for (int v = 0; v < 4; v++) {
                const float x = acc[m][n][v];
                const unsigned short h = f2bf(x);
                const unsigned short lo = f2bf(x - bf2f(h));
                Tpack[(size_t)(rowg + v) * HDIM + colg] = (unsigned)h | ((unsigned)lo << 16);
            }
        }
    }
}

// ---------------------------------------------------------------------------
// MFMA band kernel: block = 16 q-rows, 4 waves split K. t arrives packed
// (hi|lo<<16 u32 from gemm_t) -> unpack via v_perm; only q needs split8.
// ---------------------------------------------------------------------------
__global__ __launch_bounds__(256) void band_mfma(const float* __restrict__ q,
                                                 const unsigned* __restrict__ tpack,
                                                 const float* __restrict__ beta,
                                                 float* __restrict__ band) {
    __shared__ float lds_c[4][16][33];
    const int tid = threadIdx.x;
    const int w = tid >> 6, l = tid & 63;
    const int r0 = blockIdx.x * 16;
    const int b = r0 >> 11;
    const int i0 = r0 & (LSEQ - 1);
    const int fr = l & 15;
    const int kb = (l >> 4) * 8;

    const float* qrow = q + (size_t)(r0 + fr) * HDIM;
    const size_t tb = (size_t)b * LSEQ * HDIM;

    const int j0 = i0 - 4 + fr;
    const int j1 = i0 + 12 + fr;
    const int j0c = min(max(j0, 0), LSEQ - 1);
    const int j1c = min(max(j1, 0), LSEQ - 1);
    const bool v0 = (j0 >= 0) && (j0 < LSEQ);
    const bool v1 = (j1 >= 0) && (j1 < LSEQ);
    const bool interior = (i0 >= 4) && (i0 + 19 < LSEQ);
    const uintx4 uz = {0u, 0u, 0u, 0u};

    f32x4 c0 = {0.f, 0.f, 0.f, 0.f};
    f32x4 c1 = {0.f, 0.f, 0.f, 0.f};

#pragma unroll 2
    for (int ks = 0; ks < 8; ks++) {
        const int k0 = w * 256 + ks * 32 + kb;
        float4 qa = *reinterpret_cast<const float4*>(qrow + k0);
        float4 qb = *reinterpret_cast<const float4*>(qrow + k0 + 4);
        uintx4 w00 = *reinterpret_cast<const uintx4*>(&tpack[tb + (size_t)j0c * HDIM + k0]);
        uintx4 w01 = *reinterpret_cast<const uintx4*>(&tpack[tb + (size_t)j0c * HDIM + k0 + 4]);
        uintx4 w10 = *reinterpret_cast<const uintx4*>(&tpack[tb + (size_t)j1c * HDIM + k0]);
        uintx4 w11 = *reinterpret_cast<const uintx4*>(&tpack[tb + (size_t)j1c * HDIM + k0 + 4]);
        if (!interior) {                   // wave-uniform; 8/512 blocks
            if (!v0) { w00 = uz; w01 = uz; }
            if (!v1) { w10 = uz; w11 = uz; }
        }
        bf16x8 ah, al, b0h, b0l, b1h, b1l;
        split8(qa, qb, ah, al);
        unpack8(w00, w01, b0h, b0l);
        unpack8(w10, w11, b1h, b1l);
        c0 = __builtin_amdgcn_mfma_f32_16x16x32_bf16(ah, b0h, c0, 0, 0, 0);
        c0 = __builtin_amdgcn_mfma_f32_16x16x32_bf16(ah, b0l, c0, 0, 0, 0);
        c0 = __builtin_amdgcn_mfma_f32_16x16x32_bf16(al, b0h, c0, 0, 0, 0);
        c1 = __builtin_amdgcn_mfma_f32_16x16x32_bf16(ah, b1h, c1, 0, 0, 0);
        c1 = __builtin_amdgcn_mfma_f32_16x16x32_bf16(ah, b1l, c1, 0, 0, 0);
        c1 = __builtin_amdgcn_mfma_f32_16x16x32_bf16(al, b1h, c1, 0, 0, 0);
    }

#pragma unroll
    for (int v = 0; v < 4; v++) {
        lds_c[w][(l >> 4) * 4 + v][fr] = c0[v];
        lds_c[w][(l >> 4) * 4 + v][16 + fr] = c1[v];
    }
    __syncthreads();

#pragma unroll
    for (int e = tid; e < 512; e += 256) {
        const int rr = e >> 5, cc = e & 31;
        lds_c[0][rr][cc] = lds_c[0][rr][cc] + lds_c[1][rr][cc] +
                           lds_c[2][rr][cc] + lds_c[3][rr][cc];
    }
    __syncthreads();

    if (tid < 16) {
        const int il = i0 + tid;
        const int ig = r0 + tid;
        float lg[NBAND];
#pragma unroll
        for (int d = 0; d < NBAND; d++) {
            const int j = il + d - 4;
            lg[d] = (j >= 0 && j < LSEQ)
                    ? lds_c[0][tid][tid + d] + beta[(size_t)b * LSEQ + j]
                    : -1e30f;
        }
        float m = -1e30f;
#pragma unroll
        for (int d = 0; d < NBAND; d++) m = fmaxf(m, lg[d]);
        float p[NBAND], s = 0.f;
#pragma unroll
        for (int d = 0; d < NBAND; d++) { p[d] = expf(lg[d] - m); s += p[d]; }
        const float inv = 1.f / s;
#pragma unroll
        for (int d = 0; d < NBAND; d++) band[(size_t)ig * NBAND + d] = p[d] * inv;
    }
}

// ---------------------------------------------------------------------------
// Expand band probs into dense [B, L, L] output.
// ---------------------------------------------------------------------------
__global__ __launch_bounds__(256) void expand_band(const float* __restrict__ band,
                                                   float* __restrict__ out) {
    const size_t idx4 = (size_t)blockIdx.x * 256 + threadIdx.x;
    const size_t flat = idx4 * 4;
    const int j0 = (int)(flat & (LSEQ - 1));
    const size_t row = flat >> 11;
    const int i = (int)(row & (LSEQ - 1));
    float v[4];
#pragma unroll
    for (int s = 0; s < 4; s++) {
        const int dj = (j0 + s) - i + 4;
        v[s] = (dj >= 0 && dj < NBAND) ? band[row * NBAND + dj] : 0.f;
    }
    float4 o = {v[0], v[1], v[2], v[3]};
    *reinterpret_cast<float4*>(&out[flat]) = o;
}

// ---------------------------------------------------------------------------
// Fallback fp32 path (ws too small).
// ---------------------------------------------------------------------------
__global__ __launch_bounds__(256) void gemm_nt_bias(const float* __restrict__ A,
                                                    const float* __restrict__ B,
                                                    const float* __restrict__ bias,
                                                    float* __restrict__ C) {
    __shared__ float As[8][132];
    __shared__ float Bs[8][132];
    const int tid = threadIdx.x;
    const int row0 = blockIdx.x * 128, col0 = blockIdx.y * 128;
    const int lr = tid >> 1, lc = (tid & 1) * 4;
    const int tx = tid & 15, ty = tid >> 4;
    float acc[2][2][4][4];
#pragma unroll
    for (int a = 0; a < 2; a++)
#pragma unroll
        for (int b = 0; b < 2; b++)
#pragma unroll
            for (int c = 0; c < 4; c++)
#pragma unroll
                for (int d = 0; d < 4; d++) acc[a][b][c][d] = 0.f;
    for (int k0 = 0; k0 < HDIM; k0 += 8) {
        float4 av = *reinterpret_cast<const float4*>(&A[(size_t)(row0 + lr) * HDIM + k0 + lc]);
        float4 bv = *reinterpret_cast<const float4*>(&B[(size_t)(col0 + lr) * HDIM + k0 + lc]);
        __syncthreads();
        As[lc + 0][lr] = av.x; As[lc + 1][lr] = av.y; As[lc + 2][lr] = av.z; As[lc + 3][lr] = av.w;
        Bs[lc + 0][lr] = bv.x; Bs[lc + 1][lr] = bv.y; Bs[lc + 2][lr] = bv.z; Bs[lc + 3][lr] = bv.w;
        __syncthreads();
#pragma unroll
        for (int kk = 0; kk < 8; kk++) {
            float4 a0 = *reinterpret_cast<const float4*>(&As[kk][ty * 4]);
            float4 a1 = *reinterpret_cast<const float4*>(&As[kk][64 + ty * 4]);
            float4 b0 = *reinterpret_cast<const float4*>(&Bs[kk][tx * 4]);
            float4 b1 = *reinterpret_cast<const float4*>(&Bs[kk][64 + tx * 4]);
            float am[2][4] = {{a0.x, a0.y, a0.z, a0.w}, {a1.x, a1.y, a1.z, a1.w}};
            float bw[2][4] = {{b0.x, b0.y, b0.z, b0.w}, {b1.x, b1.y, b1.z, b1.w}};
#pragma unroll
            for (int mi = 0; mi < 2; mi++)
#pragma unroll
                for (int ni = 0; ni < 2; ni++)
#pragma unroll
                    for (int mm = 0; mm < 4; mm++)
#pragma unroll
                        for (int nn = 0; nn < 4; nn++)
                            acc[mi][ni][mm][nn] += am[mi][mm] * bw[ni][nn];
        }
    }
#pragma unroll
    for (int mi = 0; mi < 2; mi++)
#pragma unroll
        for (int mm = 0; mm < 4; mm++) {
            const int r = row0 + mi * 64 + ty * 4 + mm;
#pragma unroll
            for (int ni = 0; ni < 2; ni++) {
                const int c = col0 + ni * 64 + tx * 4;
                float4 o;
                o.x = acc[mi][ni][mm][0] + bias[c + 0];
                o.y = acc[mi][ni][mm][1] + bias[c + 1];
                o.z = acc[mi][ni][mm][2] + bias[c + 2];
                o.w = acc[mi][ni][mm][3] + bias[c + 3];
                *reinterpret_cast<float4*>(&C[(size_t)r * HDIM + c]) = o;
            }
        }
}

__global__ __launch_bounds__(256) void band_softmax(const float* __restrict__ qs,
                                                    const float* __restrict__ ks,
                                                    float* __restrict__ band) {
    const int wave = threadIdx.x >> 6;
    const int lane = threadIdx.x & 63;
    const int r = blockIdx.x * 4 + wave;
    const int b = r >> 11;
    const int i = r & (LSEQ - 1);
    const float* qrow = qs + (size_t)r * HDIM;
    const float* kbase = ks + (size_t)b * LSEQ * HDIM;
    float acc[NBAND];
#pragma unroll
    for (int d = 0; d < NBAND; d++) acc[d] = 0.f;
    for (int h = lane; h < HDIM; h += 64) {
        const float qv = qrow[h];
#pragma unroll
        for (int d = 0; d < NBAND; d++) {
            const int j = i + d - 4;
            if (j >= 0 && j < LSEQ)
                acc[d] += qv * kbase[(size_t)j * HDIM + h];
        }
    }
#pragma unroll
    for (int d = 0; d < NBAND; d++) {
        float v = acc[d];
#pragma unroll
        for (int off = 32; off > 0; off >>= 1) v += __shfl_xor(v, off, 64);
        acc[d] = v;
    }
    if (lane == 0) {
        float m = -1e30f;
#pragma unroll
        for (int d = 0; d < NBAND; d++) {
            const int j = i + d - 4;
            if (j >= 0 && j < LSEQ) m = fmaxf(m, acc[d]);
        }
        float p[NBAND];
        float s = 0.f;
#pragma unroll
        for (int d = 0; d < NBAND; d++) {
            const int j = i + d - 4;
            p[d] = (j >= 0 && j < LSEQ) ? expf(acc[d] - m) : 0.f;
            s += p[d];
        }
        const float inv = 1.f / s;
#pragma unroll
        for (int d = 0; d < NBAND; d++) band[(size_t)r * NBAND + d] = p[d] * inv;
    }
}

extern "C" void kernel_launch(void* const* d_in, const int* in_sizes, int n_in,
                              void* d_out, int out_size, void* d_ws, size_t ws_size,
                              hipStream_t stream) {
    const float* q  = (const float*)d_in[0];
    const float* k  = (const float*)d_in[1];
    const float* Wq = (const float*)d_in[2];
    const float* bq = (const float*)d_in[3];
    const float* Wk = (const float*)d_in[4];
    const float* bk = (const float*)d_in[5];
    float* out = (float*)d_out;

    // ---- workspace layout (~36.6 MB, proven available) ----
    const size_t bandB = (size_t)ROWS * NBAND * sizeof(float);
    char* p = (char*)d_ws;
    float* band = (float*)p;                 p += bandB;
    unsigned short* Xhi = (unsigned short*)p; p += (size_t)ROWS * HDIM * 2;   // 16 MB
    unsigned short* Xlo = (unsigned short*)p; p += (size_t)ROWS * HDIM * 2;   // 16 MB
    unsigned short* Mhi = (unsigned short*)p; p += (size_t)HDIM * HDIM * 2;   // 2 MB
    unsigned short* Mlo = (unsigned short*)p; p += (size_t)HDIM * HDIM * 2;   // 2 MB
    float* w        = (float*)p;             p += HDIM * sizeof(float);
    float* wpart    = (float*)p;             p += 64 * HDIM * sizeof(float);
    float* beta     = (float*)p;             p += ROWS * sizeof(float);
    const size_t need = (size_t)(p - (char*)d_ws);

    // WqT/WkT bf16 splits live in the (not-yet-written) Xhi region
    unsigned short* WqTh = Xhi;
    unsigned short* WqTl = Xhi + (size_t)HDIM * HDIM;
    unsigned short* WkTh = Xhi + 2 * (size_t)HDIM * HDIM;
    unsigned short* WkTl = Xhi + 3 * (size_t)HDIM * HDIM;

    // d_out scratch (64 MB): Tpack [0,32MB), Mparts [32,48MB).
    // All dead before expand_band overwrites d_out.
    unsigned* tpack = (unsigned*)out;                                 // 32 MB
    float* Mparts = (float*)((char*)out + 32ull * 1024 * 1024);       // 16 MB

    if (ws_size >= need) {
        wpart_kernel<<<64, 256, 0, stream>>>(Wk, bq, wpart);
        wreduce<<<4, 256, 0, stream>>>(wpart, w);
        dim3 tg(16, 16, 2);
        transpose_convert<<<tg, 256, 0, stream>>>(Wq, Wk, WqTh, WqTl, WkTh, WkTl);
        dim3 mg(8, 8, 4);
        gemm_part<<<mg, 256, 0, stream>>>(WqTh, WqTl, WkTh, WkTl, Mparts);
        reduceM_convert<<<HDIM * HDIM / 4 / 256, 256, 0, stream>>>(Mparts, Mhi, Mlo);
        convert_k_beta<<<ROWS, 256, 0, stream>>>(k, w, Xhi, Xlo, beta);
        dim3 gg(ROWS / 128, HDIM / 128);
        gemm_t<<<gg, 256, 0, stream>>>(Xhi, Xlo, Mhi, Mlo, tpack);
        band_mfma<<<ROWS / 16, 256, 0, stream>>>(q, tpack, beta, band);
        expand_band<<<(size_t)ROWS * LSEQ / 4 / 256, 256, 0, stream>>>(band, out);
    } else {
        float* qs = out;
        float* ks = out + (size_t)ROWS * HDIM;
        dim3 gg(ROWS / 128, HDIM / 128);
        gemm_nt_bias<<<gg, 256, 0, stream>>>(q, Wq, bq, qs);
        gemm_nt_bias<<<gg, 256, 0, stream>>>(k, Wk, bk, ks);
        band_softmax<<<ROWS / 4, 256, 0, stream>>>(qs, ks, band);
        expand_band<<<(size_t)ROWS * LSEQ / 4 / 256, 256, 0, stream>>>(band, out);
    }
}

// Round 14
// 133.110 us; speedup vs baseline: 1.1175x; 1.0560x over previous
//
#include <hip/hip_runtime.h>
#include <math.h>

#define LSEQ 2048
#define HDIM 1024
#define BATCH 4
#define ROWS (BATCH * LSEQ)   // 8192
#define NBAND 9               // |i-j| <= 4

typedef __attribute__((ext_vector_type(8))) short bf16x8;
typedef __attribute__((ext_vector_type(4))) float f32x4;
typedef __attribute__((ext_vector_type(8))) unsigned short u16x8;
typedef __attribute__((ext_vector_type(4))) unsigned uintx4;

#define AS3 __attribute__((address_space(3)))
#define AS1 __attribute__((address_space(1)))

__device__ __forceinline__ void gload16(const void* gp, void* lp) {
    __builtin_amdgcn_global_load_lds((AS1 const unsigned*)gp, (AS3 unsigned*)lp, 16, 0, 0);
}

__device__ __forceinline__ unsigned short f2bf(float x) {
    unsigned u = __float_as_uint(x);
    u += 0x7FFFu + ((u >> 16) & 1u);
    return (unsigned short)(u >> 16);
}
__device__ __forceinline__ float bf2f(unsigned short h) {
    return __uint_as_float(((unsigned)h) << 16);
}

// split 8 fp32 (two float4) into bf16 hi/lo fragments
__device__ __forceinline__ void split8(float4 a, float4 b, bf16x8& hi, bf16x8& lo) {
    float v[8] = {a.x, a.y, a.z, a.w, b.x, b.y, b.z, b.w};
#pragma unroll
    for (int j = 0; j < 8; j++) {
        unsigned short h = f2bf(v[j]);
        hi[j] = (short)h;
        lo[j] = (short)f2bf(v[j] - bf2f(h));
    }
}

// unpack 8 packed u32 (hi|lo<<16) into hi/lo bf16x8 fragments via v_perm
__device__ __forceinline__ void unpack8(uintx4 w0, uintx4 w1, bf16x8& hi, bf16x8& lo) {
    union { bf16x8 v; uintx4 u; } H, L;
    H.u[0] = __builtin_amdgcn_perm(w0[1], w0[0], 0x05040100u);
    H.u[1] = __builtin_amdgcn_perm(w0[3], w0[2], 0x05040100u);
    H.u[2] = __builtin_amdgcn_perm(w1[1], w1[0], 0x05040100u);
    H.u[3] = __builtin_amdgcn_perm(w1[3], w1[2], 0x05040100u);
    L.u[0] = __builtin_amdgcn_perm(w0[1], w0[0], 0x07060302u);
    L.u[1] = __builtin_amdgcn_perm(w0[3], w0[2], 0x07060302u);
    L.u[2] = __builtin_amdgcn_perm(w1[1], w1[0], 0x07060302u);
    L.u[3] = __builtin_amdgcn_perm(w1[3], w1[2], 0x07060302u);
    hi = H.v; lo = L.v;
}

// ---------------------------------------------------------------------------
// Fused: z<2 -> transposed split-convert of Wq/Wk; z==2 -> wpart (64 blocks).
// ---------------------------------------------------------------------------
__global__ __launch_bounds__(256) void tcw_kernel(const float* __restrict__ Wq,
                                                  const float* __restrict__ Wk,
                                                  const float* __restrict__ bq,
                                                  unsigned short* __restrict__ qhi,
                                                  unsigned short* __restrict__ qlo,
                                                  unsigned short* __restrict__ khi,
                                                  unsigned short* __restrict__ klo,
                                                  float* __restrict__ wpart) {
    const int z = blockIdx.z;
    const int tid = threadIdx.x;
    if (z == 2) {
        const int fid = blockIdx.y * 16 + blockIdx.x;
        if (fid >= 64) return;
        const int c0 = tid * 4;
        float4 acc = {0.f, 0.f, 0.f, 0.f};
#pragma unroll
        for (int hh = 0; hh < 16; hh++) {
            const int h = fid * 16 + hh;
            const float s = bq[h];
            float4 v = *reinterpret_cast<const float4*>(&Wk[(size_t)h * HDIM + c0]);
            acc.x += v.x * s; acc.y += v.y * s; acc.z += v.z * s; acc.w += v.w * s;
        }
        *reinterpret_cast<float4*>(&wpart[(size_t)fid * HDIM + c0]) = acc;
        return;
    }
    __shared__ float tile[64][65];
    const float* src = z ? Wk : Wq;
    unsigned short* dh = z ? khi : qhi;
    unsigned short* dl = z ? klo : qlo;
    const int n0 = blockIdx.x * 64;
    const int h0 = blockIdx.y * 64;

#pragma unroll
    for (int p = 0; p < 4; p++) {
        const int h = p * 16 + (tid >> 4);
        const int n = (tid & 15) * 4;
        float4 v = *reinterpret_cast<const float4*>(&src[(size_t)(h0 + h) * HDIM + n0 + n]);
        tile[h][n + 0] = v.x; tile[h][n + 1] = v.y; tile[h][n + 2] = v.z; tile[h][n + 3] = v.w;
    }
    __syncthreads();
#pragma unroll
    for (int p = 0; p < 2; p++) {
        const int n = p * 32 + (tid >> 3);
        const int h = (tid & 7) * 8;
        u16x8 hv, lv;
#pragma unroll
        for (int j = 0; j < 8; j++) {
            float x = tile[h + j][n];
            unsigned short hb = f2bf(x);
            hv[j] = hb;
            lv[j] = f2bf(x - bf2f(hb));
        }
        *reinterpret_cast<u16x8*>(&dh[(size_t)(n0 + n) * HDIM + h0 + h]) = hv;
        *reinterpret_cast<u16x8*>(&dl[(size_t)(n0 + n) * HDIM + h0 + h]) = lv;
    }
}

// ---------------------------------------------------------------------------
// Fused: split-convert k rows to bf16 hi/lo AND beta[r] = k_r . w
// ---------------------------------------------------------------------------
__global__ __launch_bounds__(256) void convert_k_beta(const float* __restrict__ k,
                                                      const float* __restrict__ w,
                                                      unsigned short* __restrict__ Xhi,
                                                      unsigned short* __restrict__ Xlo,
                                                      float* __restrict__ beta) {
    __shared__ float red[4];
    const int r = blockIdx.x;
    const int t = threadIdx.x;
    float4 v = *reinterpret_cast<const float4*>(&k[(size_t)r * HDIM + t * 4]);
    float4 wv = *reinterpret_cast<const float4*>(&w[t * 4]);
    ushort4 h, l;
    h.x = f2bf(v.x); l.x = f2bf(v.x - bf2f(h.x));
    h.y = f2bf(v.y); l.y = f2bf(v.y - bf2f(h.y));
    h.z = f2bf(v.z); l.z = f2bf(v.z - bf2f(h.z));
    h.w = f2bf(v.w); l.w = f2bf(v.w - bf2f(h.w));
    reinterpret_cast<ushort4*>(Xhi)[(size_t)r * 256 + t] = h;
    reinterpret_cast<ushort4*>(Xlo)[(size_t)r * 256 + t] = l;
    float d = v.x * wv.x + v.y * wv.y + v.z * wv.z + v.w * wv.w;
#pragma unroll
    for (int off = 32; off > 0; off >>= 1) d += __shfl_xor(d, off, 64);
    if ((t & 63) == 0) red[t >> 6] = d;
    __syncthreads();
    if (t == 0) beta[r] = red[0] + red[1] + red[2] + red[3];
}

// ---------------------------------------------------------------------------
// Split-K GEMM for M = WqT @ WkT^T: grid (8,8,4), K-slice 256 each.
// ---------------------------------------------------------------------------
__global__ __launch_bounds__(256, 2) void gemm_part(
        const unsigned short* __restrict__ Ahi, const unsigned short* __restrict__ Alo,
        const unsigned short* __restrict__ Bhi, const unsigned short* __restrict__ Blo,
        float* __restrict__ Cparts) {
    __shared__ unsigned short sh[4 * 4096];
    const int AHI = 0, ALO = 4096, BHI = 8192, BLO = 12288;
    const int tid = threadIdx.x;
    const int w = tid >> 6, l = tid & 63;
    const int wr = w >> 1, wc = w & 1;
    const int row0 = blockIdx.x * 128, col0 = blockIdx.y * 128;
    const int kbeg = blockIdx.z * 256;
    float* C = Cparts + (size_t)blockIdx.z * HDIM * HDIM;
    const int srow0 = (l >> 2), scbp = l & 3;

    f32x4 acc[4][4];
#pragma unroll
    for (int m = 0; m < 4; m++)
#pragma unroll
        for (int n = 0; n < 4; n++) acc[m][n] = (f32x4){0.f, 0.f, 0.f, 0.f};

    const int fr_a[4] = {wr * 64 + (l & 15), wr * 64 + 16 + (l & 15),
                         wr * 64 + 32 + (l & 15), wr * 64 + 48 + (l & 15)};
    const int fr_b[4] = {wc * 64 + (l & 15), wc * 64 + 16 + (l & 15),
                         wc * 64 + 32 + (l & 15), wc * 64 + 48 + (l & 15)};
    const int cb = l >> 4;

    for (int k0 = kbeg; k0 < kbeg + 256; k0 += 32) {
#pragma unroll
        for (int i = 0; i < 2; i++) {
            const int seg = i * 4 + w;
            const int row = seg * 16 + srow0;
            const int cbs = scbp ^ ((row >> 1) & 3);
            gload16(Ahi + (size_t)(row0 + row) * HDIM + k0 + cbs * 8, &sh[AHI + seg * 512]);
            gload16(Alo + (size_t)(row0 + row) * HDIM + k0 + cbs * 8, &sh[ALO + seg * 512]);
            gload16(Bhi + (size_t)(col0 + row) * HDIM + k0 + cbs * 8, &sh[BHI + seg * 512]);
            gload16(Blo + (size_t)(col0 + row) * HDIM + k0 + cbs * 8, &sh[BLO + seg * 512]);
        }
        __syncthreads();

        bf16x8 ah[4], al[4], bh[4], bl[4];
#pragma unroll
        for (int m = 0; m < 4; m++) {
            const int r = fr_a[m];
            const int cbs = cb ^ ((r >> 1) & 3);
            ah[m] = *reinterpret_cast<const bf16x8*>(&sh[AHI + r * 32 + cbs * 8]);
            al[m] = *reinterpret_cast<const bf16x8*>(&sh[ALO + r * 32 + cbs * 8]);
        }
#pragma unroll
        for (int n = 0; n < 4; n++) {
            const int r = fr_b[n];
            const int cbs = cb ^ ((r >> 1) & 3);
            bh[n] = *reinterpret_cast<const bf16x8*>(&sh[BHI + r * 32 + cbs * 8]);
            bl[n] = *reinterpret_cast<const bf16x8*>(&sh[BLO + r * 32 + cbs * 8]);
        }
#pragma unroll
        for (int m = 0; m < 4; m++)
#pragma unroll
            for (int n = 0; n < 4; n++) {
                acc[m][n] = __builtin_amdgcn_mfma_f32_16x16x32_bf16(ah[m], bh[n], acc[m][n], 0, 0, 0);
                acc[m][n] = __builtin_amdgcn_mfma_f32_16x16x32_bf16(ah[m], bl[n], acc[m][n], 0, 0, 0);
                acc[m][n] = __builtin_amdgcn_mfma_f32_16x16x32_bf16(al[m], bh[n], acc[m][n], 0, 0, 0);
            }
        __syncthreads();
    }

    const int lcol = l & 15, lrow = (l >> 4) * 4;
#pragma unroll
    for (int n = 0; n < 4; n++) {
        const int colg = col0 + wc * 64 + n * 16 + lcol;
#pragma unroll
        for (int m = 0; m < 4; m++) {
            const int rowg = row0 + wr * 64 + m * 16 + lrow;
#pragma unroll
            for (int v = 0; v < 4; v++)
                C[(size_t)(rowg + v) * HDIM + colg] = acc[m][n][v];
        }
    }
}

// ---------------------------------------------------------------------------
// Fused: blocks <1024 reduce 4 M-parts -> bf16 hi/lo; blocks 1024..1027 do
// wreduce (w[c] = sum over 64 wpart slices).
// ---------------------------------------------------------------------------
__global__ __launch_bounds__(256) void reduceMw_convert(const float* __restrict__ Mparts,
                                                        unsigned short* __restrict__ Mhi,
                                                        unsigned short* __restrict__ Mlo,
                                                        const float* __restrict__ wpart,
                                                        float* __restrict__ w) {
    if (blockIdx.x >= 1024) {
        const int c = (blockIdx.x - 1024) * 256 + threadIdx.x;
        float s = 0.f;
#pragma unroll
        for (int b = 0; b < 64; b++) s += wpart[(size_t)b * HDIM + c];
        w[c] = s;
        return;
    }
    const int idx4 = blockIdx.x * 256 + threadIdx.x;
    float4 s = {0.f, 0.f, 0.f, 0.f};
#pragma unroll
    for (int z = 0; z < 4; z++) {
        float4 v = reinterpret_cast<const float4*>(Mparts + (size_t)z * HDIM * HDIM)[idx4];
        s.x += v.x; s.y += v.y; s.z += v.z; s.w += v.w;
    }
    ushort4 h, l;
    h.x = f2bf(s.x); l.x = f2bf(s.x - bf2f(h.x));
    h.y = f2bf(s.y); l.y = f2bf(s.y - bf2f(h.y));
    h.z = f2bf(s.z); l.z = f2bf(s.z - bf2f(h.z));
    h.w = f2bf(s.w); l.w = f2bf(s.w - bf2f(h.w));
    reinterpret_cast<ushort4*>(Mhi)[idx4] = h;
    reinterpret_cast<ushort4*>(Mlo)[idx4] = l;
}

// ---------------------------------------------------------------------------
// Big GEMM (t = K @ M^T), 256x128 tile, BK=32, 512 thr = 8 waves (4x2),
// double-buffered LDS (stage-before-compute, round-11 technique). Round-9's
// 256x128 failed WITHOUT dbuf (no intra-block overlap); dbuf hides staging
// under MFMA. Staged bytes/CU-iter 48KB vs 64KB for 2x128^2. LDS 96KB,
// 1 block/CU, grid (32,8). Natural block mapping (round-10: no swizzle).
// Epilogue: packed u32 (hi|lo<<16), 4B stores (round-12 lesson).
// ---------------------------------------------------------------------------
__global__ __launch_bounds__(512, 2) void gemm_t(
        const unsigned short* __restrict__ Ahi, const unsigned short* __restrict__ Alo,
        const unsigned short* __restrict__ Bhi, const unsigned short* __restrict__ Blo,
        unsigned* __restrict__ Tpack) {
    __shared__ unsigned short sh[2][24576];   // 2 x 48 KB
    const int AHI = 0, ALO = 8192, BHI = 16384, BLO = 20480;
    const int tid = threadIdx.x;
    const int w = tid >> 6, l = tid & 63;       // 8 waves
    const int wr = w >> 1, wc = w & 1;          // 4 x 2 wave grid
    const int row0 = blockIdx.x * 256, col0 = blockIdx.y * 128;
    const int srow0 = (l >> 2), scbp = l & 3;

    f32x4 acc[4][4];
#pragma unroll
    for (int m = 0; m < 4; m++)
#pragma unroll
        for (int n = 0; n < 4; n++) acc[m][n] = (f32x4){0.f, 0.f, 0.f, 0.f};

    const int fr_a[4] = {wr * 64 + (l & 15), wr * 64 + 16 + (l & 15),
                         wr * 64 + 32 + (l & 15), wr * 64 + 48 + (l & 15)};
    const int fr_b[4] = {wc * 64 + (l & 15), wc * 64 + 16 + (l & 15),
                         wc * 64 + 32 + (l & 15), wc * 64 + 48 + (l & 15)};
    const int cb = l >> 4;

    auto stage = [&](int buf, int k0) {
        // A: 16 segs (2/wave), B: 8 segs (1/wave) -> 6 gload16/thread
#pragma unroll
        for (int i = 0; i < 2; i++) {
            const int seg = i * 8 + w;                 // 0..15
            const int row = seg * 16 + srow0;          // 0..255
            const int cbs = scbp ^ ((row >> 1) & 3);
            gload16(Ahi + (size_t)(row0 + row) * HDIM + k0 + cbs * 8, &sh[buf][AHI + seg * 512]);
            gload16(Alo + (size_t)(row0 + row) * HDIM + k0 + cbs * 8, &sh[buf][ALO + seg * 512]);
        }
        {
            const int seg = w;                         // 0..7
            const int row = seg * 16 + srow0;          // 0..127
            const int cbs = scbp ^ ((row >> 1) & 3);
            gload16(Bhi + (size_t)(col0 + row) * HDIM + k0 + cbs * 8, &sh[buf][BHI + seg * 512]);
            gload16(Blo + (size_t)(col0 + row) * HDIM + k0 + cbs * 8, &sh[buf][BLO + seg * 512]);
        }
    };
    auto compute = [&](int buf) {
        bf16x8 ah[4], al[4], bh[4], bl[4];
#pragma unroll
        for (int m = 0; m < 4; m++) {
            const int r = fr_a[m];
            const int cbs = cb ^ ((r >> 1) & 3);
            ah[m] = *reinterpret_cast<const bf16x8*>(&sh[buf][AHI + r * 32 + cbs * 8]);
            al[m] = *reinterpret_cast<const bf16x8*>(&sh[buf][ALO + r * 32 + cbs * 8]);
        }
#pragma unroll
        for (int n = 0; n < 4; n++) {
            const int r = fr_b[n];
            const int cbs = cb ^ ((r >> 1) & 3);
            bh[n] = *reinterpret_cast<const bf16x8*>(&sh[buf][BHI + r * 32 + cbs * 8]);
            bl[n] = *reinterpret_cast<const bf16x8*>(&sh[buf][BLO + r * 32 + cbs * 8]);
        }
#pragma unroll
        for (int m = 0; m < 4; m++)
#pragma unroll
            for (int n = 0; n < 4; n++) {
                acc[m][n] = __builtin_amdgcn_mfma_f32_16x16x32_bf16(ah[m], bh[n], acc[m][n], 0, 0, 0);
                acc[m][n] = __builtin_amdgcn_mfma_f32_16x16x32_bf16(ah[m], bl[n], acc[m][n], 0, 0, 0);
                acc[m][n] = __builtin_amdgcn_mfma_f32_16x16x32_bf16(al[m], bh[n], acc[m][n], 0, 0, 0);
            }
    };

    stage(0, 0);
    __syncthreads();
    int cur = 0;
    for (int t = 0; t < 31; t++) {
        stage(cur ^ 1, (t + 1) * 32);
        compute(cur);
        __syncthreads();
        cur ^= 1;
    }
    compute(cur);

    const int lcol = l & 15, lrow = (l >> 4) * 4;
#pragma unroll
    for (int n = 0; n < 4; n++) {
        const int colg = col0 + wc * 64 + n * 16 + lcol;
#pragma unroll
        for (int m = 0; m < 4; m++) {
            const int rowg = row0 + wr * 64 + m * 16 + lrow;
#pragma unroll
            for (int v = 0; v < 4; v++) {
                const float x = acc[m][n][v];
                const unsigned short h = f2bf(x);
                const unsigned short lo = f2bf(x - bf2f(h));
                Tpack[(size_t)(rowg + v) * HDIM + colg] = (unsigned)h | ((unsigned)lo << 16);
            }
        }
    }
}

// ---------------------------------------------------------------------------
// MFMA band kernel (verified round 13): block = 16 q-rows, 4 waves split K;
// t arrives packed (hi|lo<<16), unpack via v_perm; only q needs split8.
// ---------------------------------------------------------------------------
__global__ __launch_bounds__(256) void band_mfma(const float* __restrict__ q,
                                                 const unsigned* __restrict__ tpack,
                                                 const float* __restrict__ beta,
                                                 float* __restrict__ band) {
    __shared__ float lds_c[4][16][33];
    const int tid = threadIdx.x;
    const int w = tid >> 6, l = tid & 63;
    const int r0 = blockIdx.x * 16;
    const int b = r0 >> 11;
    const int i0 = r0 & (LSEQ - 1);
    const int fr = l & 15;
    const int kb = (l >> 4) * 8;

    const float* qrow = q + (size_t)(r0 + fr) * HDIM;
    const size_t tb = (size_t)b * LSEQ * HDIM;

    const int j0 = i0 - 4 + fr;
    const int j1 = i0 + 12 + fr;
    const int j0c = min(max(j0, 0), LSEQ - 1);
    const int j1c = min(max(j1, 0), LSEQ - 1);
    const bool v0 = (j0 >= 0) && (j0 < LSEQ);
    const bool v1 = (j1 >= 0) && (j1 < LSEQ);
    const bool interior = (i0 >= 4) && (i0 + 19 < LSEQ);
    const uintx4 uz = {0u, 0u, 0u, 0u};

    f32x4 c0 = {0.f, 0.f, 0.f, 0.f};
    f32x4 c1 = {0.f, 0.f, 0.f, 0.f};

#pragma unroll 2
    for (int ks = 0; ks < 8; ks++) {
        const int k0 = w * 256 + ks * 32 + kb;
        float4 qa = *reinterpret_cast<const float4*>(qrow + k0);
        float4 qb = *reinterpret_cast<const float4*>(qrow + k0 + 4);
        uintx4 w00 = *reinterpret_cast<const uintx4*>(&tpack[tb + (size_t)j0c * HDIM + k0]);
        uintx4 w01 = *reinterpret_cast<const uintx4*>(&tpack[tb + (size_t)j0c * HDIM + k0 + 4]);
        uintx4 w10 = *reinterpret_cast<const uintx4*>(&tpack[tb + (size_t)j1c * HDIM + k0]);
        uintx4 w11 = *reinterpret_cast<const uintx4*>(&tpack[tb + (size_t)j1c * HDIM + k0 + 4]);
        if (!interior) {
            if (!v0) { w00 = uz; w01 = uz; }
            if (!v1) { w10 = uz; w11 = uz; }
        }
        bf16x8 ah, al, b0h, b0l, b1h, b1l;
        split8(qa, qb, ah, al);
        unpack8(w00, w01, b0h, b0l);
        unpack8(w10, w11, b1h, b1l);
        c0 = __builtin_amdgcn_mfma_f32_16x16x32_bf16(ah, b0h, c0, 0, 0, 0);
        c0 = __builtin_amdgcn_mfma_f32_16x16x32_bf16(ah, b0l, c0, 0, 0, 0);
        c0 = __builtin_amdgcn_mfma_f32_16x16x32_bf16(al, b0h, c0, 0, 0, 0);
        c1 = __builtin_amdgcn_mfma_f32_16x16x32_bf16(ah, b1h, c1, 0, 0, 0);
        c1 = __builtin_amdgcn_mfma_f32_16x16x32_bf16(ah, b1l, c1, 0, 0, 0);
        c1 = __builtin_amdgcn_mfma_f32_16x16x32_bf16(al, b1h, c1, 0, 0, 0);
    }

#pragma unroll
    for (int v = 0; v < 4; v++) {
        lds_c[w][(l >> 4) * 4 + v][fr] = c0[v];
        lds_c[w][(l >> 4) * 4 + v][16 + fr] = c1[v];
    }
    __syncthreads();

#pragma unroll
    for (int e = tid; e < 512; e += 256) {
        const int rr = e >> 5, cc = e & 31;
        lds_c[0][rr][cc] = lds_c[0][rr][cc] + lds_c[1][rr][cc] +
                           lds_c[2][rr][cc] + lds_c[3][rr][cc];
    }
    __syncthreads();

    if (tid < 16) {
        const int il = i0 + tid;
        const int ig = r0 + tid;
        float lg[NBAND];
#pragma unroll
        for (int d = 0; d < NBAND; d++) {
            const int j = il + d - 4;
            lg[d] = (j >= 0 && j < LSEQ)
                    ? lds_c[0][tid][tid + d] + beta[(size_t)b * LSEQ + j]
                    : -1e30f;
        }
        float m = -1e30f;
#pragma unroll
        for (int d = 0; d < NBAND; d++) m = fmaxf(m, lg[d]);
        float p[NBAND], s = 0.f;
#pragma unroll
        for (int d = 0; d < NBAND; d++) { p[d] = expf(lg[d] - m); s += p[d]; }
        const float inv = 1.f / s;
#pragma unroll
        for (int d = 0; d < NBAND; d++) band[(size_t)ig * NBAND + d] = p[d] * inv;
    }
}

// ---------------------------------------------------------------------------
// Expand band probs into dense [B, L, L] output.
// ---------------------------------------------------------------------------
__global__ __launch_bounds__(256) void expand_band(const float* __restrict__ band,
                                                   float* __restrict__ out) {
    const size_t idx4 = (size_t)blockIdx.x * 256 + threadIdx.x;
    const size_t flat = idx4 * 4;
    const int j0 = (int)(flat & (LSEQ - 1));
    const size_t row = flat >> 11;
    const int i = (int)(row & (LSEQ - 1));
    float v[4];
#pragma unroll
    for (int s = 0; s < 4; s++) {
        const int dj = (j0 + s) - i + 4;
        v[s] = (dj >= 0 && dj < NBAND) ? band[row * NBAND + dj] : 0.f;
    }
    float4 o = {v[0], v[1], v[2], v[3]};
    *reinterpret_cast<float4*>(&out[flat]) = o;
}

// ---------------------------------------------------------------------------
// Fallback fp32 path (ws too small).
// ---------------------------------------------------------------------------
__global__ __launch_bounds__(256) void gemm_nt_bias(const float* __restrict__ A,
                                                    const float* __restrict__ B,
                                                    const float* __restrict__ bias,
                                                    float* __restrict__ C) {
    __shared__ float As[8][132];
    __shared__ float Bs[8][132];
    const int tid = threadIdx.x;
    const int row0 = blockIdx.x * 128, col0 = blockIdx.y * 128;
    const int lr = tid >> 1, lc = (tid & 1) * 4;
    const int tx = tid & 15, ty = tid >> 4;
    float acc[2][2][4][4];
#pragma unroll
    for (int a = 0; a < 2; a++)
#pragma unroll
        for (int b = 0; b < 2; b++)
#pragma unroll
            for (int c = 0; c < 4; c++)
#pragma unroll
                for (int d = 0; d < 4; d++) acc[a][b][c][d] = 0.f;
    for (int k0 = 0; k0 < HDIM; k0 += 8) {
        float4 av = *reinterpret_cast<const float4*>(&A[(size_t)(row0 + lr) * HDIM + k0 + lc]);
        float4 bv = *reinterpret_cast<const float4*>(&B[(size_t)(col0 + lr) * HDIM + k0 + lc]);
        __syncthreads();
        As[lc + 0][lr] = av.x; As[lc + 1][lr] = av.y; As[lc + 2][lr] = av.z; As[lc + 3][lr] = av.w;
        Bs[lc + 0][lr] = bv.x; Bs[lc + 1][lr] = bv.y; Bs[lc + 2][lr] = bv.z; Bs[lc + 3][lr] = bv.w;
        __syncthreads();
#pragma unroll
        for (int kk = 0; kk < 8; kk++) {
            float4 a0 = *reinterpret_cast<const float4*>(&As[kk][ty * 4]);
            float4 a1 = *reinterpret_cast<const float4*>(&As[kk][64 + ty * 4]);
            float4 b0 = *reinterpret_cast<const float4*>(&Bs[kk][tx * 4]);
            float4 b1 = *reinterpret_cast<const float4*>(&Bs[kk][64 + tx * 4]);
            float am[2][4] = {{a0.x, a0.y, a0.z, a0.w}, {a1.x, a1.y, a1.z, a1.w}};
            float bw[2][4] = {{b0.x, b0.y, b0.z, b0.w}, {b1.x, b1.y, b1.z, b1.w}};
#pragma unroll
            for (int mi = 0; mi < 2; mi++)
#pragma unroll
                for (int ni = 0; ni < 2; ni++)
#pragma unroll
                    for (int mm = 0; mm < 4; mm++)
#pragma unroll
                        for (int nn = 0; nn < 4; nn++)
                            acc[mi][ni][mm][nn] += am[mi][mm] * bw[ni][nn];
        }
    }
#pragma unroll
    for (int mi = 0; mi < 2; mi++)
#pragma unroll
        for (int mm = 0; mm < 4; mm++) {
            const int r = row0 + mi * 64 + ty * 4 + mm;
#pragma unroll
            for (int ni = 0; ni < 2; ni++) {
                const int c = col0 + ni * 64 + tx * 4;
                float4 o;
                o.x = acc[mi][ni][mm][0] + bias[c + 0];
                o.y = acc[mi][ni][mm][1] + bias[c + 1];
                o.z = acc[mi][ni][mm][2] + bias[c + 2];
                o.w = acc[mi][ni][mm][3] + bias[c + 3];
                *reinterpret_cast<float4*>(&C[(size_t)r * HDIM + c]) = o;
            }
        }
}

__global__ __launch_bounds__(256) void band_softmax(const float* __restrict__ qs,
                                                    const float* __restrict__ ks,
                                                    float* __restrict__ band) {
    const int wave = threadIdx.x >> 6;
    const int lane = threadIdx.x & 63;
    const int r = blockIdx.x * 4 + wave;
    const int b = r >> 11;
    const int i = r & (LSEQ - 1);
    const float* qrow = qs + (size_t)r * HDIM;
    const float* kbase = ks + (size_t)b * LSEQ * HDIM;
    float acc[NBAND];
#pragma unroll
    for (int d = 0; d < NBAND; d++) acc[d] = 0.f;
    for (int h = lane; h < HDIM; h += 64) {
        const float qv = qrow[h];
#pragma unroll
        for (int d = 0; d < NBAND; d++) {
            const int j = i + d - 4;
            if (j >= 0 && j < LSEQ)
                acc[d] += qv * kbase[(size_t)j * HDIM + h];
        }
    }
#pragma unroll
    for (int d = 0; d < NBAND; d++) {
        float v = acc[d];
#pragma unroll
        for (int off = 32; off > 0; off >>= 1) v += __shfl_xor(v, off, 64);
        acc[d] = v;
    }
    if (lane == 0) {
        float m = -1e30f;
#pragma unroll
        for (int d = 0; d < NBAND; d++) {
            const int j = i + d - 4;
            if (j >= 0 && j < LSEQ) m = fmaxf(m, acc[d]);
        }
        float p[NBAND];
        float s = 0.f;
#pragma unroll
        for (int d = 0; d < NBAND; d++) {
            const int j = i + d - 4;
            p[d] = (j >= 0 && j < LSEQ) ? expf(acc[d] - m) : 0.f;
            s += p[d];
        }
        const float inv = 1.f / s;
#pragma unroll
        for (int d = 0; d < NBAND; d++) band[(size_t)r * NBAND + d] = p[d] * inv;
    }
}

extern "C" void kernel_launch(void* const* d_in, const int* in_sizes, int n_in,
                              void* d_out, int out_size, void* d_ws, size_t ws_size,
                              hipStream_t stream) {
    const float* q  = (const float*)d_in[0];
    const float* k  = (const float*)d_in[1];
    const float* Wq = (const float*)d_in[2];
    const float* bq = (const float*)d_in[3];
    const float* Wk = (const float*)d_in[4];
    const float* bk = (const float*)d_in[5];
    float* out = (float*)d_out;

    // ---- workspace layout (~36.6 MB, proven available) ----
    const size_t bandB = (size_t)ROWS * NBAND * sizeof(float);
    char* p = (char*)d_ws;
    float* band = (float*)p;                 p += bandB;
    unsigned short* Xhi = (unsigned short*)p; p += (size_t)ROWS * HDIM * 2;   // 16 MB
    unsigned short* Xlo = (unsigned short*)p; p += (size_t)ROWS * HDIM * 2;   // 16 MB
    unsigned short* Mhi = (unsigned short*)p; p += (size_t)HDIM * HDIM * 2;   // 2 MB
    unsigned short* Mlo = (unsigned short*)p; p += (size_t)HDIM * HDIM * 2;   // 2 MB
    float* w        = (float*)p;             p += HDIM * sizeof(float);
    float* wpart    = (float*)p;             p += 64 * HDIM * sizeof(float);
    float* beta     = (float*)p;             p += ROWS * sizeof(float);
    const size_t need = (size_t)(p - (char*)d_ws);

    // WqT/WkT bf16 splits live in the (not-yet-written) Xhi region
    unsigned short* WqTh = Xhi;
    unsigned short* WqTl = Xhi + (size_t)HDIM * HDIM;
    unsigned short* WkTh = Xhi + 2 * (size_t)HDIM * HDIM;
    unsigned short* WkTl = Xhi + 3 * (size_t)HDIM * HDIM;

    // d_out scratch (64 MB): Tpack [0,32MB), Mparts [32,48MB).
    unsigned* tpack = (unsigned*)out;                                 // 32 MB
    float* Mparts = (float*)((char*)out + 32ull * 1024 * 1024);       // 16 MB

    if (ws_size >= need) {
        dim3 tg(16, 16, 3);
        tcw_kernel<<<tg, 256, 0, stream>>>(Wq, Wk, bq, WqTh, WqTl, WkTh, WkTl, wpart);
        dim3 mg(8, 8, 4);
        gemm_part<<<mg, 256, 0, stream>>>(WqTh, WqTl, WkTh, WkTl, Mparts);
        reduceMw_convert<<<1028, 256, 0, stream>>>(Mparts, Mhi, Mlo, wpart, w);
        convert_k_beta<<<ROWS, 256, 0, stream>>>(k, w, Xhi, Xlo, beta);
        dim3 gg(ROWS / 256, HDIM / 128);
        gemm_t<<<gg, 512, 0, stream>>>(Xhi, Xlo, Mhi, Mlo, tpack);
        band_mfma<<<ROWS / 16, 256, 0, stream>>>(q, tpack, beta, band);
        expand_band<<<(size_t)ROWS * LSEQ / 4 / 256, 256, 0, stream>>>(band, out);
    } else {
        float* qs = out;
        float* ks = out + (size_t)ROWS * HDIM;
        dim3 gg(ROWS / 128, HDIM / 128);
        gemm_nt_bias<<<gg, 256, 0, stream>>>(q, Wq, bq, qs);
        gemm_nt_bias<<<gg, 256, 0, stream>>>(k, Wk, bk, ks);
        band_softmax<<<ROWS / 4, 256, 0, stream>>>(qs, ks, band);
        expand_band<<<(size_t)ROWS * LSEQ / 4 / 256, 256, 0, stream>>>(band, out);
    }
}

// Round 15
// 130.057 us; speedup vs baseline: 1.1438x; 1.0235x over previous
//
#include <hip/hip_runtime.h>
#include <math.h>

#define LSEQ 2048
#define HDIM 1024
#define BATCH 4
#define ROWS (BATCH * LSEQ)   // 8192
#define NBAND 9               // |i-j| <= 4

typedef __attribute__((ext_vector_type(8))) short bf16x8;
typedef __attribute__((ext_vector_type(4))) float f32x4;
typedef __attribute__((ext_vector_type(8))) unsigned short u16x8;
typedef __attribute__((ext_vector_type(4))) unsigned uintx4;

#define AS3 __attribute__((address_space(3)))
#define AS1 __attribute__((address_space(1)))

__device__ __forceinline__ void gload16(const void* gp, void* lp) {
    __builtin_amdgcn_global_load_lds((AS1 const unsigned*)gp, (AS3 unsigned*)lp, 16, 0, 0);
}

__device__ __forceinline__ unsigned short f2bf(float x) {
    unsigned u = __float_as_uint(x);
    u += 0x7FFFu + ((u >> 16) & 1u);
    return (unsigned short)(u >> 16);
}
__device__ __forceinline__ float bf2f(unsigned short h) {
    return __uint_as_float(((unsigned)h) << 16);
}

__device__ __forceinline__ void split8(float4 a, float4 b, bf16x8& hi, bf16x8& lo) {
    float v[8] = {a.x, a.y, a.z, a.w, b.x, b.y, b.z, b.w};
#pragma unroll
    for (int j = 0; j < 8; j++) {
        unsigned short h = f2bf(v[j]);
        hi[j] = (short)h;
        lo[j] = (short)f2bf(v[j] - bf2f(h));
    }
}

// unpack 8 packed u32 (hi|lo<<16) into hi/lo bf16x8 fragments via v_perm
__device__ __forceinline__ void unpack8(uintx4 w0, uintx4 w1, bf16x8& hi, bf16x8& lo) {
    union { bf16x8 v; uintx4 u; } H, L;
    H.u[0] = __builtin_amdgcn_perm(w0[1], w0[0], 0x05040100u);
    H.u[1] = __builtin_amdgcn_perm(w0[3], w0[2], 0x05040100u);
    H.u[2] = __builtin_amdgcn_perm(w1[1], w1[0], 0x05040100u);
    H.u[3] = __builtin_amdgcn_perm(w1[3], w1[2], 0x05040100u);
    L.u[0] = __builtin_amdgcn_perm(w0[1], w0[0], 0x07060302u);
    L.u[1] = __builtin_amdgcn_perm(w0[3], w0[2], 0x07060302u);
    L.u[2] = __builtin_amdgcn_perm(w1[1], w1[0], 0x07060302u);
    L.u[3] = __builtin_amdgcn_perm(w1[3], w1[2], 0x07060302u);
    hi = H.v; lo = L.v;
}

// ---------------------------------------------------------------------------
// Fused: z<2 -> transposed split-convert of Wq/Wk; z==2 -> wpart (64 blocks).
// ---------------------------------------------------------------------------
__global__ __launch_bounds__(256) void tcw_kernel(const float* __restrict__ Wq,
                                                  const float* __restrict__ Wk,
                                                  const float* __restrict__ bq,
                                                  unsigned short* __restrict__ qhi,
                                                  unsigned short* __restrict__ qlo,
                                                  unsigned short* __restrict__ khi,
                                                  unsigned short* __restrict__ klo,
                                                  float* __restrict__ wpart) {
    const int z = blockIdx.z;
    const int tid = threadIdx.x;
    if (z == 2) {
        const int fid = blockIdx.y * 16 + blockIdx.x;
        if (fid >= 64) return;
        const int c0 = tid * 4;
        float4 acc = {0.f, 0.f, 0.f, 0.f};
#pragma unroll
        for (int hh = 0; hh < 16; hh++) {
            const int h = fid * 16 + hh;
            const float s = bq[h];
            float4 v = *reinterpret_cast<const float4*>(&Wk[(size_t)h * HDIM + c0]);
            acc.x += v.x * s; acc.y += v.y * s; acc.z += v.z * s; acc.w += v.w * s;
        }
        *reinterpret_cast<float4*>(&wpart[(size_t)fid * HDIM + c0]) = acc;
        return;
    }
    __shared__ float tile[64][65];
    const float* src = z ? Wk : Wq;
    unsigned short* dh = z ? khi : qhi;
    unsigned short* dl = z ? klo : qlo;
    const int n0 = blockIdx.x * 64;
    const int h0 = blockIdx.y * 64;

#pragma unroll
    for (int p = 0; p < 4; p++) {
        const int h = p * 16 + (tid >> 4);
        const int n = (tid & 15) * 4;
        float4 v = *reinterpret_cast<const float4*>(&src[(size_t)(h0 + h) * HDIM + n0 + n]);
        tile[h][n + 0] = v.x; tile[h][n + 1] = v.y; tile[h][n + 2] = v.z; tile[h][n + 3] = v.w;
    }
    __syncthreads();
#pragma unroll
    for (int p = 0; p < 2; p++) {
        const int n = p * 32 + (tid >> 3);
        const int h = (tid & 7) * 8;
        u16x8 hv, lv;
#pragma unroll
        for (int j = 0; j < 8; j++) {
            float x = tile[h + j][n];
            unsigned short hb = f2bf(x);
            hv[j] = hb;
            lv[j] = f2bf(x - bf2f(hb));
        }
        *reinterpret_cast<u16x8*>(&dh[(size_t)(n0 + n) * HDIM + h0 + h]) = hv;
        *reinterpret_cast<u16x8*>(&dl[(size_t)(n0 + n) * HDIM + h0 + h]) = lv;
    }
}

// ---------------------------------------------------------------------------
// Fused: split-convert k rows to bf16 hi/lo AND beta[r] = k_r . w
// ---------------------------------------------------------------------------
__global__ __launch_bounds__(256) void convert_k_beta(const float* __restrict__ k,
                                                      const float* __restrict__ w,
                                                      unsigned short* __restrict__ Xhi,
                                                      unsigned short* __restrict__ Xlo,
                                                      float* __restrict__ beta) {
    __shared__ float red[4];
    const int r = blockIdx.x;
    const int t = threadIdx.x;
    float4 v = *reinterpret_cast<const float4*>(&k[(size_t)r * HDIM + t * 4]);
    float4 wv = *reinterpret_cast<const float4*>(&w[t * 4]);
    ushort4 h, l;
    h.x = f2bf(v.x); l.x = f2bf(v.x - bf2f(h.x));
    h.y = f2bf(v.y); l.y = f2bf(v.y - bf2f(h.y));
    h.z = f2bf(v.z); l.z = f2bf(v.z - bf2f(h.z));
    h.w = f2bf(v.w); l.w = f2bf(v.w - bf2f(h.w));
    reinterpret_cast<ushort4*>(Xhi)[(size_t)r * 256 + t] = h;
    reinterpret_cast<ushort4*>(Xlo)[(size_t)r * 256 + t] = l;
    float d = v.x * wv.x + v.y * wv.y + v.z * wv.z + v.w * wv.w;
#pragma unroll
    for (int off = 32; off > 0; off >>= 1) d += __shfl_xor(d, off, 64);
    if ((t & 63) == 0) red[t >> 6] = d;
    __syncthreads();
    if (t == 0) beta[r] = red[0] + red[1] + red[2] + red[3];
}

// ---------------------------------------------------------------------------
// Split-K GEMM for M = WqT @ WkT^T: grid (8,8,4), K-slice 256 each.
// ---------------------------------------------------------------------------
__global__ __launch_bounds__(256, 2) void gemm_part(
        const unsigned short* __restrict__ Ahi, const unsigned short* __restrict__ Alo,
        const unsigned short* __restrict__ Bhi, const unsigned short* __restrict__ Blo,
        float* __restrict__ Cparts) {
    __shared__ unsigned short sh[4 * 4096];
    const int AHI = 0, ALO = 4096, BHI = 8192, BLO = 12288;
    const int tid = threadIdx.x;
    const int w = tid >> 6, l = tid & 63;
    const int wr = w >> 1, wc = w & 1;
    const int row0 = blockIdx.x * 128, col0 = blockIdx.y * 128;
    const int kbeg = blockIdx.z * 256;
    float* C = Cparts + (size_t)blockIdx.z * HDIM * HDIM;
    const int srow0 = (l >> 2), scbp = l & 3;

    f32x4 acc[4][4];
#pragma unroll
    for (int m = 0; m < 4; m++)
#pragma unroll
        for (int n = 0; n < 4; n++) acc[m][n] = (f32x4){0.f, 0.f, 0.f, 0.f};

    const int fr_a[4] = {wr * 64 + (l & 15), wr * 64 + 16 + (l & 15),
                         wr * 64 + 32 + (l & 15), wr * 64 + 48 + (l & 15)};
    const int fr_b[4] = {wc * 64 + (l & 15), wc * 64 + 16 + (l & 15),
                         wc * 64 + 32 + (l & 15), wc * 64 + 48 + (l & 15)};
    const int cb = l >> 4;

    for (int k0 = kbeg; k0 < kbeg + 256; k0 += 32) {
#pragma unroll
        for (int i = 0; i < 2; i++) {
            const int seg = i * 4 + w;
            const int row = seg * 16 + srow0;
            const int cbs = scbp ^ ((row >> 1) & 3);
            gload16(Ahi + (size_t)(row0 + row) * HDIM + k0 + cbs * 8, &sh[AHI + seg * 512]);
            gload16(Alo + (size_t)(row0 + row) * HDIM + k0 + cbs * 8, &sh[ALO + seg * 512]);
            gload16(Bhi + (size_t)(col0 + row) * HDIM + k0 + cbs * 8, &sh[BHI + seg * 512]);
            gload16(Blo + (size_t)(col0 + row) * HDIM + k0 + cbs * 8, &sh[BLO + seg * 512]);
        }
        __syncthreads();

        bf16x8 ah[4], al[4], bh[4], bl[4];
#pragma unroll
        for (int m = 0; m < 4; m++) {
            const int r = fr_a[m];
            const int cbs = cb ^ ((r >> 1) & 3);
            ah[m] = *reinterpret_cast<const bf16x8*>(&sh[AHI + r * 32 + cbs * 8]);
            al[m] = *reinterpret_cast<const bf16x8*>(&sh[ALO + r * 32 + cbs * 8]);
        }
#pragma unroll
        for (int n = 0; n < 4; n++) {
            const int r = fr_b[n];
            const int cbs = cb ^ ((r >> 1) & 3);
            bh[n] = *reinterpret_cast<const bf16x8*>(&sh[BHI + r * 32 + cbs * 8]);
            bl[n] = *reinterpret_cast<const bf16x8*>(&sh[BLO + r * 32 + cbs * 8]);
        }
#pragma unroll
        for (int m = 0; m < 4; m++)
#pragma unroll
            for (int n = 0; n < 4; n++) {
                acc[m][n] = __builtin_amdgcn_mfma_f32_16x16x32_bf16(ah[m], bh[n], acc[m][n], 0, 0, 0);
                acc[m][n] = __builtin_amdgcn_mfma_f32_16x16x32_bf16(ah[m], bl[n], acc[m][n], 0, 0, 0);
                acc[m][n] = __builtin_amdgcn_mfma_f32_16x16x32_bf16(al[m], bh[n], acc[m][n], 0, 0, 0);
            }
        __syncthreads();
    }

    const int lcol = l & 15, lrow = (l >> 4) * 4;
#pragma unroll
    for (int n = 0; n < 4; n++) {
        const int colg = col0 + wc * 64 + n * 16 + lcol;
#pragma unroll
        for (int m = 0; m < 4; m++) {
            const int rowg = row0 + wr * 64 + m * 16 + lrow;
#pragma unroll
            for (int v = 0; v < 4; v++)
                C[(size_t)(rowg + v) * HDIM + colg] = acc[m][n][v];
        }
    }
}

// ---------------------------------------------------------------------------
// Fused: blocks <1024 reduce 4 M-parts -> bf16 hi/lo; blocks 1024..1027 do
// wreduce (w[c] = sum over 64 wpart slices).
// ---------------------------------------------------------------------------
__global__ __launch_bounds__(256) void reduceMw_convert(const float* __restrict__ Mparts,
                                                        unsigned short* __restrict__ Mhi,
                                                        unsigned short* __restrict__ Mlo,
                                                        const float* __restrict__ wpart,
                                                        float* __restrict__ w) {
    if (blockIdx.x >= 1024) {
        const int c = (blockIdx.x - 1024) * 256 + threadIdx.x;
        float s = 0.f;
#pragma unroll
        for (int b = 0; b < 64; b++) s += wpart[(size_t)b * HDIM + c];
        w[c] = s;
        return;
    }
    const int idx4 = blockIdx.x * 256 + threadIdx.x;
    float4 s = {0.f, 0.f, 0.f, 0.f};
#pragma unroll
    for (int z = 0; z < 4; z++) {
        float4 v = reinterpret_cast<const float4*>(Mparts + (size_t)z * HDIM * HDIM)[idx4];
        s.x += v.x; s.y += v.y; s.z += v.z; s.w += v.w;
    }
    ushort4 h, l;
    h.x = f2bf(s.x); l.x = f2bf(s.x - bf2f(h.x));
    h.y = f2bf(s.y); l.y = f2bf(s.y - bf2f(h.y));
    h.z = f2bf(s.z); l.z = f2bf(s.z - bf2f(h.z));
    h.w = f2bf(s.w); l.w = f2bf(s.w - bf2f(h.w));
    reinterpret_cast<ushort4*>(Mhi)[idx4] = h;
    reinterpret_cast<ushort4*>(Mlo)[idx4] = l;
}

// ---------------------------------------------------------------------------
// Big GEMM (t = K @ M^T), 128x128 tile, BK=32, 4 waves, double-buffered LDS
// (round-11/13 proven: 51.2us). Natural block mapping (round-10: no swizzle).
// Epilogue: packed u32 (hi|lo<<16), 4B stores (round-12 lesson).
// ---------------------------------------------------------------------------
__global__ __launch_bounds__(256, 2) void gemm_t(
        const unsigned short* __restrict__ Ahi, const unsigned short* __restrict__ Alo,
        const unsigned short* __restrict__ Bhi, const unsigned short* __restrict__ Blo,
        unsigned* __restrict__ Tpack) {
    __shared__ unsigned short sh[2][16384];   // 2 x 32 KB
    const int AHI = 0, ALO = 4096, BHI = 8192, BLO = 12288;
    const int tid = threadIdx.x;
    const int w = tid >> 6, l = tid & 63;
    const int wr = w >> 1, wc = w & 1;
    const int row0 = blockIdx.x * 128, col0 = blockIdx.y * 128;
    const int srow0 = (l >> 2), scbp = l & 3;

    f32x4 acc[4][4];
#pragma unroll
    for (int m = 0; m < 4; m++)
#pragma unroll
        for (int n = 0; n < 4; n++) acc[m][n] = (f32x4){0.f, 0.f, 0.f, 0.f};

    const int fr_a[4] = {wr * 64 + (l & 15), wr * 64 + 16 + (l & 15),
                         wr * 64 + 32 + (l & 15), wr * 64 + 48 + (l & 15)};
    const int fr_b[4] = {wc * 64 + (l & 15), wc * 64 + 16 + (l & 15),
                         wc * 64 + 32 + (l & 15), wc * 64 + 48 + (l & 15)};
    const int cb = l >> 4;

    auto stage = [&](int buf, int k0) {
#pragma unroll
        for (int i = 0; i < 2; i++) {
            const int seg = i * 4 + w;
            const int row = seg * 16 + srow0;
            const int cbs = scbp ^ ((row >> 1) & 3);
            gload16(Ahi + (size_t)(row0 + row) * HDIM + k0 + cbs * 8, &sh[buf][AHI + seg * 512]);
            gload16(Alo + (size_t)(row0 + row) * HDIM + k0 + cbs * 8, &sh[buf][ALO + seg * 512]);
            gload16(Bhi + (size_t)(col0 + row) * HDIM + k0 + cbs * 8, &sh[buf][BHI + seg * 512]);
            gload16(Blo + (size_t)(col0 + row) * HDIM + k0 + cbs * 8, &sh[buf][BLO + seg * 512]);
        }
    };
    auto compute = [&](int buf) {
        bf16x8 ah[4], al[4], bh[4], bl[4];
#pragma unroll
        for (int m = 0; m < 4; m++) {
            const int r = fr_a[m];
            const int cbs = cb ^ ((r >> 1) & 3);
            ah[m] = *reinterpret_cast<const bf16x8*>(&sh[buf][AHI + r * 32 + cbs * 8]);
            al[m] = *reinterpret_cast<const bf16x8*>(&sh[buf][ALO + r * 32 + cbs * 8]);
        }
#pragma unroll
        for (int n = 0; n < 4; n++) {
            const int r = fr_b[n];
            const int cbs = cb ^ ((r >> 1) & 3);
            bh[n] = *reinterpret_cast<const bf16x8*>(&sh[buf][BHI + r * 32 + cbs * 8]);
            bl[n] = *reinterpret_cast<const bf16x8*>(&sh[buf][BLO + r * 32 + cbs * 8]);
        }
#pragma unroll
        for (int m = 0; m < 4; m++)
#pragma unroll
            for (int n = 0; n < 4; n++) {
                acc[m][n] = __builtin_amdgcn_mfma_f32_16x16x32_bf16(ah[m], bh[n], acc[m][n], 0, 0, 0);
                acc[m][n] = __builtin_amdgcn_mfma_f32_16x16x32_bf16(ah[m], bl[n], acc[m][n], 0, 0, 0);
                acc[m][n] = __builtin_amdgcn_mfma_f32_16x16x32_bf16(al[m], bh[n], acc[m][n], 0, 0, 0);
            }
    };

    stage(0, 0);
    __syncthreads();
    int cur = 0;
    for (int t = 0; t < 31; t++) {
        stage(cur ^ 1, (t + 1) * 32);
        compute(cur);
        __syncthreads();
        cur ^= 1;
    }
    compute(cur);

    const int lcol = l & 15, lrow = (l >> 4) * 4;
#pragma unroll
    for (int n = 0; n < 4; n++) {
        const int colg = col0 + wc * 64 + n * 16 + lcol;
#pragma unroll
        for (int m = 0; m < 4; m++) {
            const int rowg = row0 + wr * 64 + m * 16 + lrow;
#pragma unroll
            for (int v = 0; v < 4; v++) {
                const float x = acc[m][n][v];
                const unsigned short h = f2bf(x);
                const unsigned short lo = f2bf(x - bf2f(h));
                Tpack[(size_t)(rowg + v) * HDIM + colg] = (unsigned)h | ((unsigned)lo << 16);
            }
        }
    }
}

// ---------------------------------------------------------------------------
// Shared band-logit compute: 16 q-rows/block, 4 waves split K, logits
// reduced into lds_c[0]. Returns via lds_c.
// ---------------------------------------------------------------------------
__device__ __forceinline__ void band_core(const float* __restrict__ q,
                                          const unsigned* __restrict__ tpack,
                                          int r0, int b, int i0, int tid,
                                          float (*lds_c)[16][33]) {
    const int w = tid >> 6, l = tid & 63;
    const int fr = l & 15;
    const int kb = (l >> 4) * 8;

    const float* qrow = q + (size_t)(r0 + fr) * HDIM;
    const size_t tb = (size_t)b * LSEQ * HDIM;

    const int j0 = i0 - 4 + fr;
    const int j1 = i0 + 12 + fr;
    const int j0c = min(max(j0, 0), LSEQ - 1);
    const int j1c = min(max(j1, 0), LSEQ - 1);
    const bool v0 = (j0 >= 0) && (j0 < LSEQ);
    const bool v1 = (j1 >= 0) && (j1 < LSEQ);
    const bool interior = (i0 >= 4) && (i0 + 19 < LSEQ);
    const uintx4 uz = {0u, 0u, 0u, 0u};

    f32x4 c0 = {0.f, 0.f, 0.f, 0.f};
    f32x4 c1 = {0.f, 0.f, 0.f, 0.f};

#pragma unroll 2
    for (int ks = 0; ks < 8; ks++) {
        const int k0 = w * 256 + ks * 32 + kb;
        float4 qa = *reinterpret_cast<const float4*>(qrow + k0);
        float4 qb = *reinterpret_cast<const float4*>(qrow + k0 + 4);
        uintx4 w00 = *reinterpret_cast<const uintx4*>(&tpack[tb + (size_t)j0c * HDIM + k0]);
        uintx4 w01 = *reinterpret_cast<const uintx4*>(&tpack[tb + (size_t)j0c * HDIM + k0 + 4]);
        uintx4 w10 = *reinterpret_cast<const uintx4*>(&tpack[tb + (size_t)j1c * HDIM + k0]);
        uintx4 w11 = *reinterpret_cast<const uintx4*>(&tpack[tb + (size_t)j1c * HDIM + k0 + 4]);
        if (!interior) {
            if (!v0) { w00 = uz; w01 = uz; }
            if (!v1) { w10 = uz; w11 = uz; }
        }
        bf16x8 ah, al, b0h, b0l, b1h, b1l;
        split8(qa, qb, ah, al);
        unpack8(w00, w01, b0h, b0l);
        unpack8(w10, w11, b1h, b1l);
        c0 = __builtin_amdgcn_mfma_f32_16x16x32_bf16(ah, b0h, c0, 0, 0, 0);
        c0 = __builtin_amdgcn_mfma_f32_16x16x32_bf16(ah, b0l, c0, 0, 0, 0);
        c0 = __builtin_amdgcn_mfma_f32_16x16x32_bf16(al, b0h, c0, 0, 0, 0);
        c1 = __builtin_amdgcn_mfma_f32_16x16x32_bf16(ah, b1h, c1, 0, 0, 0);
        c1 = __builtin_amdgcn_mfma_f32_16x16x32_bf16(ah, b1l, c1, 0, 0, 0);
        c1 = __builtin_amdgcn_mfma_f32_16x16x32_bf16(al, b1h, c1, 0, 0, 0);
    }

#pragma unroll
    for (int v = 0; v < 4; v++) {
        lds_c[w][(l >> 4) * 4 + v][fr] = c0[v];
        lds_c[w][(l >> 4) * 4 + v][16 + fr] = c1[v];
    }
    __syncthreads();

#pragma unroll
    for (int e = tid; e < 512; e += 256) {
        const int rr = e >> 5, cc = e & 31;
        lds_c[0][rr][cc] = lds_c[0][rr][cc] + lds_c[1][rr][cc] +
                           lds_c[2][rr][cc] + lds_c[3][rr][cc];
    }
    __syncthreads();
}

// ---------------------------------------------------------------------------
// band_mfma (fallback path): writes 9 probs per row to band buffer.
// ---------------------------------------------------------------------------
__global__ __launch_bounds__(256) void band_mfma(const float* __restrict__ q,
                                                 const unsigned* __restrict__ tpack,
                                                 const float* __restrict__ beta,
                                                 float* __restrict__ band) {
    __shared__ float lds_c[4][16][33];
    const int tid = threadIdx.x;
    const int r0 = blockIdx.x * 16;
    const int b = r0 >> 11;
    const int i0 = r0 & (LSEQ - 1);
    band_core(q, tpack, r0, b, i0, tid, lds_c);

    if (tid < 16) {
        const int il = i0 + tid;
        const int ig = r0 + tid;
        float lg[NBAND];
#pragma unroll
        for (int d = 0; d < NBAND; d++) {
            const int j = il + d - 4;
            lg[d] = (j >= 0 && j < LSEQ)
                    ? lds_c[0][tid][tid + d] + beta[(size_t)b * LSEQ + j]
                    : -1e30f;
        }
        float m = -1e30f;
#pragma unroll
        for (int d = 0; d < NBAND; d++) m = fmaxf(m, lg[d]);
        float p[NBAND], s = 0.f;
#pragma unroll
        for (int d = 0; d < NBAND; d++) { p[d] = expf(lg[d] - m); s += p[d]; }
        const float inv = 1.f / s;
#pragma unroll
        for (int d = 0; d < NBAND; d++) band[(size_t)ig * NBAND + d] = p[d] * inv;
    }
}

// ---------------------------------------------------------------------------
// band_fuse (ws-large path): computes probs in-block and writes the dense
// 16x2048 output tile directly (zeros + band). tpack MUST live in d_ws
// (d_out is fully overwritten). Eliminates the expand kernel.
// ---------------------------------------------------------------------------
__global__ __launch_bounds__(256) void band_fuse(const float* __restrict__ q,
                                                 const unsigned* __restrict__ tpack,
                                                 const float* __restrict__ beta,
                                                 float* __restrict__ out) {
    __shared__ float lds_c[4][16][33];
    const int tid = threadIdx.x;
    const int r0 = blockIdx.x * 16;
    const int b = r0 >> 11;
    const int i0 = r0 & (LSEQ - 1);
    band_core(q, tpack, r0, b, i0, tid, lds_c);

    float* pr = &lds_c[1][0][0];   // 144 floats, region dead after reduce
    if (tid < 16) {
        const int il = i0 + tid;
        float lg[NBAND];
#pragma unroll
        for (int d = 0; d < NBAND; d++) {
            const int j = il + d - 4;
            lg[d] = (j >= 0 && j < LSEQ)
                    ? lds_c[0][tid][tid + d] + beta[(size_t)b * LSEQ + j]
                    : -1e30f;
        }
        float m = -1e30f;
#pragma unroll
        for (int d = 0; d < NBAND; d++) m = fmaxf(m, lg[d]);
        float p[NBAND], s = 0.f;
#pragma unroll
        for (int d = 0; d < NBAND; d++) { p[d] = expf(lg[d] - m); s += p[d]; }
        const float inv = 1.f / s;
#pragma unroll
        for (int d = 0; d < NBAND; d++) pr[tid * NBAND + d] = p[d] * inv;
    }
    __syncthreads();

    // write 16 rows x 2048 cols (8192 float4, 32 per thread), coalesced
    for (int e = tid; e < 8192; e += 256) {
        const int rr = e >> 9;           // row within tile
        const int c0 = (e & 511) * 4;    // col
        const int il = i0 + rr;
        float v[4];
#pragma unroll
        for (int s = 0; s < 4; s++) {
            const int dj = c0 + s - il + 4;
            v[s] = (dj >= 0 && dj < NBAND) ? pr[rr * NBAND + dj] : 0.f;
        }
        float4 o = {v[0], v[1], v[2], v[3]};
        *reinterpret_cast<float4*>(&out[(size_t)(r0 + rr) * LSEQ + c0]) = o;
    }
}

// ---------------------------------------------------------------------------
// Expand band probs into dense [B, L, L] output (fallback path).
// ---------------------------------------------------------------------------
__global__ __launch_bounds__(256) void expand_band(const float* __restrict__ band,
                                                   float* __restrict__ out) {
    const size_t idx4 = (size_t)blockIdx.x * 256 + threadIdx.x;
    const size_t flat = idx4 * 4;
    const int j0 = (int)(flat & (LSEQ - 1));
    const size_t row = flat >> 11;
    const int i = (int)(row & (LSEQ - 1));
    float v[4];
#pragma unroll
    for (int s = 0; s < 4; s++) {
        const int dj = (j0 + s) - i + 4;
        v[s] = (dj >= 0 && dj < NBAND) ? band[row * NBAND + dj] : 0.f;
    }
    float4 o = {v[0], v[1], v[2], v[3]};
    *reinterpret_cast<float4*>(&out[flat]) = o;
}

// ---------------------------------------------------------------------------
// Fallback fp32 path (ws too small).
// ---------------------------------------------------------------------------
__global__ __launch_bounds__(256) void gemm_nt_bias(const float* __restrict__ A,
                                                    const float* __restrict__ B,
                                                    const float* __restrict__ bias,
                                                    float* __restrict__ C) {
    __shared__ float As[8][132];
    __shared__ float Bs[8][132];
    const int tid = threadIdx.x;
    const int row0 = blockIdx.x * 128, col0 = blockIdx.y * 128;
    const int lr = tid >> 1, lc = (tid & 1) * 4;
    const int tx = tid & 15, ty = tid >> 4;
    float acc[2][2][4][4];
#pragma unroll
    for (int a = 0; a < 2; a++)
#pragma unroll
        for (int b = 0; b < 2; b++)
#pragma unroll
            for (int c = 0; c < 4; c++)
#pragma unroll
                for (int d = 0; d < 4; d++) acc[a][b][c][d] = 0.f;
    for (int k0 = 0; k0 < HDIM; k0 += 8) {
        float4 av = *reinterpret_cast<const float4*>(&A[(size_t)(row0 + lr) * HDIM + k0 + lc]);
        float4 bv = *reinterpret_cast<const float4*>(&B[(size_t)(col0 + lr) * HDIM + k0 + lc]);
        __syncthreads();
        As[lc + 0][lr] = av.x; As[lc + 1][lr] = av.y; As[lc + 2][lr] = av.z; As[lc + 3][lr] = av.w;
        Bs[lc + 0][lr] = bv.x; Bs[lc + 1][lr] = bv.y; Bs[lc + 2][lr] = bv.z; Bs[lc + 3][lr] = bv.w;
        __syncthreads();
#pragma unroll
        for (int kk = 0; kk < 8; kk++) {
            float4 a0 = *reinterpret_cast<const float4*>(&As[kk][ty * 4]);
            float4 a1 = *reinterpret_cast<const float4*>(&As[kk][64 + ty * 4]);
            float4 b0 = *reinterpret_cast<const float4*>(&Bs[kk][tx * 4]);
            float4 b1 = *reinterpret_cast<const float4*>(&Bs[kk][64 + tx * 4]);
            float am[2][4] = {{a0.x, a0.y, a0.z, a0.w}, {a1.x, a1.y, a1.z, a1.w}};
            float bw[2][4] = {{b0.x, b0.y, b0.z, b0.w}, {b1.x, b1.y, b1.z, b1.w}};
#pragma unroll
            for (int mi = 0; mi < 2; mi++)
#pragma unroll
                for (int ni = 0; ni < 2; ni++)
#pragma unroll
                    for (int mm = 0; mm < 4; mm++)
#pragma unroll
                        for (int nn = 0; nn < 4; nn++)
                            acc[mi][ni][mm][nn] += am[mi][mm] * bw[ni][nn];
        }
    }
#pragma unroll
    for (int mi = 0; mi < 2; mi++)
#pragma unroll
        for (int mm = 0; mm < 4; mm++) {
            const int r = row0 + mi * 64 + ty * 4 + mm;
#pragma unroll
            for (int ni = 0; ni < 2; ni++) {
                const int c = col0 + ni * 64 + tx * 4;
                float4 o;
                o.x = acc[mi][ni][mm][0] + bias[c + 0];
                o.y = acc[mi][ni][mm][1] + bias[c + 1];
                o.z = acc[mi][ni][mm][2] + bias[c + 2];
                o.w = acc[mi][ni][mm][3] + bias[c + 3];
                *reinterpret_cast<float4*>(&C[(size_t)r * HDIM + c]) = o;
            }
        }
}

__global__ __launch_bounds__(256) void band_softmax(const float* __restrict__ qs,
                                                    const float* __restrict__ ks,
                                                    float* __restrict__ band) {
    const int wave = threadIdx.x >> 6;
    const int lane = threadIdx.x & 63;
    const int r = blockIdx.x * 4 + wave;
    const int b = r >> 11;
    const int i = r & (LSEQ - 1);
    const float* qrow = qs + (size_t)r * HDIM;
    const float* kbase = ks + (size_t)b * LSEQ * HDIM;
    float acc[NBAND];
#pragma unroll
    for (int d = 0; d < NBAND; d++) acc[d] = 0.f;
    for (int h = lane; h < HDIM; h += 64) {
        const float qv = qrow[h];
#pragma unroll
        for (int d = 0; d < NBAND; d++) {
            const int j = i + d - 4;
            if (j >= 0 && j < LSEQ)
                acc[d] += qv * kbase[(size_t)j * HDIM + h];
        }
    }
#pragma unroll
    for (int d = 0; d < NBAND; d++) {
        float v = acc[d];
#pragma unroll
        for (int off = 32; off > 0; off >>= 1) v += __shfl_xor(v, off, 64);
        acc[d] = v;
    }
    if (lane == 0) {
        float m = -1e30f;
#pragma unroll
        for (int d = 0; d < NBAND; d++) {
            const int j = i + d - 4;
            if (j >= 0 && j < LSEQ) m = fmaxf(m, acc[d]);
        }
        float p[NBAND];
        float s = 0.f;
#pragma unroll
        for (int d = 0; d < NBAND; d++) {
            const int j = i + d - 4;
            p[d] = (j >= 0 && j < LSEQ) ? expf(acc[d] - m) : 0.f;
            s += p[d];
        }
        const float inv = 1.f / s;
#pragma unroll
        for (int d = 0; d < NBAND; d++) band[(size_t)r * NBAND + d] = p[d] * inv;
    }
}

extern "C" void kernel_launch(void* const* d_in, const int* in_sizes, int n_in,
                              void* d_out, int out_size, void* d_ws, size_t ws_size,
                              hipStream_t stream) {
    const float* q  = (const float*)d_in[0];
    const float* k  = (const float*)d_in[1];
    const float* Wq = (const float*)d_in[2];
    const float* bq = (const float*)d_in[3];
    const float* Wk = (const float*)d_in[4];
    const float* bk = (const float*)d_in[5];
    float* out = (float*)d_out;

    // ---- workspace layout ----
    const size_t bandB = (size_t)ROWS * NBAND * sizeof(float);
    char* p = (char*)d_ws;
    float* band = (float*)p;                 p += bandB;
    unsigned short* Xhi = (unsigned short*)p; p += (size_t)ROWS * HDIM * 2;   // 16 MB
    unsigned short* Xlo = (unsigned short*)p; p += (size_t)ROWS * HDIM * 2;   // 16 MB
    unsigned short* Mhi = (unsigned short*)p; p += (size_t)HDIM * HDIM * 2;   // 2 MB
    unsigned short* Mlo = (unsigned short*)p; p += (size_t)HDIM * HDIM * 2;   // 2 MB
    float* w        = (float*)p;             p += HDIM * sizeof(float);
    float* wpart    = (float*)p;             p += 64 * HDIM * sizeof(float);
    float* beta     = (float*)p;             p += ROWS * sizeof(float);
    const size_t need = (size_t)(p - (char*)d_ws);
    // optional tpack in ws (fused path): align to 256
    const size_t tpackOff = (need + 255) & ~(size_t)255;
    const size_t need2 = tpackOff + (size_t)ROWS * HDIM * sizeof(unsigned);   // +32 MB

    unsigned short* WqTh = Xhi;
    unsigned short* WqTl = Xhi + (size_t)HDIM * HDIM;
    unsigned short* WkTh = Xhi + 2 * (size_t)HDIM * HDIM;
    unsigned short* WkTl = Xhi + 3 * (size_t)HDIM * HDIM;

    // Mparts always in d_out [32,48MB) (dead before final output writes)
    float* Mparts = (float*)((char*)out + 32ull * 1024 * 1024);

    if (ws_size >= need) {
        dim3 tg(16, 16, 3);
        tcw_kernel<<<tg, 256, 0, stream>>>(Wq, Wk, bq, WqTh, WqTl, WkTh, WkTl, wpart);
        dim3 mg(8, 8, 4);
        gemm_part<<<mg, 256, 0, stream>>>(WqTh, WqTl, WkTh, WkTl, Mparts);
        reduceMw_convert<<<1028, 256, 0, stream>>>(Mparts, Mhi, Mlo, wpart, w);
        convert_k_beta<<<ROWS, 256, 0, stream>>>(k, w, Xhi, Xlo, beta);
        dim3 gg(ROWS / 128, HDIM / 128);
        if (ws_size >= need2) {
            // fused path: tpack in ws -> band_fuse writes d_out directly
            unsigned* tpack = (unsigned*)((char*)d_ws + tpackOff);
            gemm_t<<<gg, 256, 0, stream>>>(Xhi, Xlo, Mhi, Mlo, tpack);
            band_fuse<<<ROWS / 16, 256, 0, stream>>>(q, tpack, beta, out);
        } else {
            // tpack in d_out [0,32MB): need separate expand (race-free)
            unsigned* tpack = (unsigned*)out;
            gemm_t<<<gg, 256, 0, stream>>>(Xhi, Xlo, Mhi, Mlo, tpack);
            band_mfma<<<ROWS / 16, 256, 0, stream>>>(q, tpack, beta, band);
            expand_band<<<(size_t)ROWS * LSEQ / 4 / 256, 256, 0, stream>>>(band, out);
        }
    } else {
        float* qs = out;
        float* ks = out + (size_t)ROWS * HDIM;
        dim3 gg(ROWS / 128, HDIM / 128);
        gemm_nt_bias<<<gg, 256, 0, stream>>>(q, Wq, bq, qs);
        gemm_nt_bias<<<gg, 256, 0, stream>>>(k, Wk, bk, ks);
        band_softmax<<<ROWS / 4, 256, 0, stream>>>(qs, ks, band);
        expand_band<<<(size_t)ROWS * LSEQ / 4 / 256, 256, 0, stream>>>(band, out);
    }
}

// Round 16
// 126.919 us; speedup vs baseline: 1.1721x; 1.0247x over previous
//
#include <hip/hip_runtime.h>
#include <math.h>

#define LSEQ 2048
#define HDIM 1024
#define BATCH 4
#define ROWS (BATCH * LSEQ)   // 8192
#define NBAND 9               // |i-j| <= 4

typedef __attribute__((ext_vector_type(8))) short bf16x8;
typedef __attribute__((ext_vector_type(4))) float f32x4;
typedef __attribute__((ext_vector_type(8))) unsigned short u16x8;
typedef __attribute__((ext_vector_type(4))) unsigned uintx4;

#define AS3 __attribute__((address_space(3)))
#define AS1 __attribute__((address_space(1)))

__device__ __forceinline__ void gload16(const void* gp, void* lp) {
    __builtin_amdgcn_global_load_lds((AS1 const unsigned*)gp, (AS3 unsigned*)lp, 16, 0, 0);
}

__device__ __forceinline__ unsigned short f2bf(float x) {
    unsigned u = __float_as_uint(x);
    u += 0x7FFFu + ((u >> 16) & 1u);
    return (unsigned short)(u >> 16);
}
__device__ __forceinline__ float bf2f(unsigned short h) {
    return __uint_as_float(((unsigned)h) << 16);
}

__device__ __forceinline__ void split8(float4 a, float4 b, bf16x8& hi, bf16x8& lo) {
    float v[8] = {a.x, a.y, a.z, a.w, b.x, b.y, b.z, b.w};
#pragma unroll
    for (int j = 0; j < 8; j++) {
        unsigned short h = f2bf(v[j]);
        hi[j] = (short)h;
        lo[j] = (short)f2bf(v[j] - bf2f(h));
    }
}

// unpack 8 packed u32 (hi|lo<<16) into hi/lo bf16x8 fragments via v_perm
__device__ __forceinline__ void unpack8(uintx4 w0, uintx4 w1, bf16x8& hi, bf16x8& lo) {
    union { bf16x8 v; uintx4 u; } H, L;
    H.u[0] = __builtin_amdgcn_perm(w0[1], w0[0], 0x05040100u);
    H.u[1] = __builtin_amdgcn_perm(w0[3], w0[2], 0x05040100u);
    H.u[2] = __builtin_amdgcn_perm(w1[1], w1[0], 0x05040100u);
    H.u[3] = __builtin_amdgcn_perm(w1[3], w1[2], 0x05040100u);
    L.u[0] = __builtin_amdgcn_perm(w0[1], w0[0], 0x07060302u);
    L.u[1] = __builtin_amdgcn_perm(w0[3], w0[2], 0x07060302u);
    L.u[2] = __builtin_amdgcn_perm(w1[1], w1[0], 0x07060302u);
    L.u[3] = __builtin_amdgcn_perm(w1[3], w1[2], 0x07060302u);
    hi = H.v; lo = L.v;
}

// ---------------------------------------------------------------------------
// Fused: z<2 -> transposed split-convert of Wq/Wk; z==2 -> wpart (64 blocks).
// ---------------------------------------------------------------------------
__global__ __launch_bounds__(256) void tcw_kernel(const float* __restrict__ Wq,
                                                  const float* __restrict__ Wk,
                                                  const float* __restrict__ bq,
                                                  unsigned short* __restrict__ qhi,
                                                  unsigned short* __restrict__ qlo,
                                                  unsigned short* __restrict__ khi,
                                                  unsigned short* __restrict__ klo,
                                                  float* __restrict__ wpart) {
    const int z = blockIdx.z;
    const int tid = threadIdx.x;
    if (z == 2) {
        const int fid = blockIdx.y * 16 + blockIdx.x;
        if (fid >= 64) return;
        const int c0 = tid * 4;
        float4 acc = {0.f, 0.f, 0.f, 0.f};
#pragma unroll
        for (int hh = 0; hh < 16; hh++) {
            const int h = fid * 16 + hh;
            const float s = bq[h];
            float4 v = *reinterpret_cast<const float4*>(&Wk[(size_t)h * HDIM + c0]);
            acc.x += v.x * s; acc.y += v.y * s; acc.z += v.z * s; acc.w += v.w * s;
        }
        *reinterpret_cast<float4*>(&wpart[(size_t)fid * HDIM + c0]) = acc;
        return;
    }
    __shared__ float tile[64][65];
    const float* src = z ? Wk : Wq;
    unsigned short* dh = z ? khi : qhi;
    unsigned short* dl = z ? klo : qlo;
    const int n0 = blockIdx.x * 64;
    const int h0 = blockIdx.y * 64;

#pragma unroll
    for (int p = 0; p < 4; p++) {
        const int h = p * 16 + (tid >> 4);
        const int n = (tid & 15) * 4;
        float4 v = *reinterpret_cast<const float4*>(&src[(size_t)(h0 + h) * HDIM + n0 + n]);
        tile[h][n + 0] = v.x; tile[h][n + 1] = v.y; tile[h][n + 2] = v.z; tile[h][n + 3] = v.w;
    }
    __syncthreads();
#pragma unroll
    for (int p = 0; p < 2; p++) {
        const int n = p * 32 + (tid >> 3);
        const int h = (tid & 7) * 8;
        u16x8 hv, lv;
#pragma unroll
        for (int j = 0; j < 8; j++) {
            float x = tile[h + j][n];
            unsigned short hb = f2bf(x);
            hv[j] = hb;
            lv[j] = f2bf(x - bf2f(hb));
        }
        *reinterpret_cast<u16x8*>(&dh[(size_t)(n0 + n) * HDIM + h0 + h]) = hv;
        *reinterpret_cast<u16x8*>(&dl[(size_t)(n0 + n) * HDIM + h0 + h]) = lv;
    }
}

// ---------------------------------------------------------------------------
// Fused convert+beta, 4 rows per block: wave w owns row r0+w (1 wave/row),
// 4 float4 per lane, beta via wave-local shfl reduce (no block barrier).
// ---------------------------------------------------------------------------
__global__ __launch_bounds__(256) void convert_k_beta(const float* __restrict__ k,
                                                      const float* __restrict__ w,
                                                      unsigned short* __restrict__ Xhi,
                                                      unsigned short* __restrict__ Xlo,
                                                      float* __restrict__ beta) {
    const int wv = threadIdx.x >> 6;
    const int l = threadIdx.x & 63;
    const int r = blockIdx.x * 4 + wv;
    const float4* krow = reinterpret_cast<const float4*>(k + (size_t)r * HDIM);
    const float4* wrow = reinterpret_cast<const float4*>(w);
    ushort4* XH = reinterpret_cast<ushort4*>(Xhi) + (size_t)r * 256;
    ushort4* XL = reinterpret_cast<ushort4*>(Xlo) + (size_t)r * 256;

    float d = 0.f;
#pragma unroll
    for (int p = 0; p < 4; p++) {
        const int idx = p * 64 + l;
        float4 v = krow[idx];
        float4 ww = wrow[idx];
        ushort4 h, lo;
        h.x = f2bf(v.x); lo.x = f2bf(v.x - bf2f(h.x));
        h.y = f2bf(v.y); lo.y = f2bf(v.y - bf2f(h.y));
        h.z = f2bf(v.z); lo.z = f2bf(v.z - bf2f(h.z));
        h.w = f2bf(v.w); lo.w = f2bf(v.w - bf2f(h.w));
        XH[idx] = h;
        XL[idx] = lo;
        d += v.x * ww.x + v.y * ww.y + v.z * ww.z + v.w * ww.w;
    }
#pragma unroll
    for (int off = 32; off > 0; off >>= 1) d += __shfl_xor(d, off, 64);
    if (l == 0) beta[r] = d;
}

// ---------------------------------------------------------------------------
// Split-K GEMM for M = WqT @ WkT^T: grid (8,8,4), K-slice 256, BK=32,
// double-buffered LDS (round-11 proven structure ported).
// ---------------------------------------------------------------------------
__global__ __launch_bounds__(256, 2) void gemm_part(
        const unsigned short* __restrict__ Ahi, const unsigned short* __restrict__ Alo,
        const unsigned short* __restrict__ Bhi, const unsigned short* __restrict__ Blo,
        float* __restrict__ Cparts) {
    __shared__ unsigned short sh[2][16384];   // 2 x 32 KB
    const int AHI = 0, ALO = 4096, BHI = 8192, BLO = 12288;
    const int tid = threadIdx.x;
    const int w = tid >> 6, l = tid & 63;
    const int wr = w >> 1, wc = w & 1;
    const int row0 = blockIdx.x * 128, col0 = blockIdx.y * 128;
    const int kbeg = blockIdx.z * 256;
    float* C = Cparts + (size_t)blockIdx.z * HDIM * HDIM;
    const int srow0 = (l >> 2), scbp = l & 3;

    f32x4 acc[4][4];
#pragma unroll
    for (int m = 0; m < 4; m++)
#pragma unroll
        for (int n = 0; n < 4; n++) acc[m][n] = (f32x4){0.f, 0.f, 0.f, 0.f};

    const int fr_a[4] = {wr * 64 + (l & 15), wr * 64 + 16 + (l & 15),
                         wr * 64 + 32 + (l & 15), wr * 64 + 48 + (l & 15)};
    const int fr_b[4] = {wc * 64 + (l & 15), wc * 64 + 16 + (l & 15),
                         wc * 64 + 32 + (l & 15), wc * 64 + 48 + (l & 15)};
    const int cb = l >> 4;

    auto stage = [&](int buf, int k0) {
#pragma unroll
        for (int i = 0; i < 2; i++) {
            const int seg = i * 4 + w;
            const int row = seg * 16 + srow0;
            const int cbs = scbp ^ ((row >> 1) & 3);
            gload16(Ahi + (size_t)(row0 + row) * HDIM + k0 + cbs * 8, &sh[buf][AHI + seg * 512]);
            gload16(Alo + (size_t)(row0 + row) * HDIM + k0 + cbs * 8, &sh[buf][ALO + seg * 512]);
            gload16(Bhi + (size_t)(col0 + row) * HDIM + k0 + cbs * 8, &sh[buf][BHI + seg * 512]);
            gload16(Blo + (size_t)(col0 + row) * HDIM + k0 + cbs * 8, &sh[buf][BLO + seg * 512]);
        }
    };
    auto compute = [&](int buf) {
        bf16x8 ah[4], al[4], bh[4], bl[4];
#pragma unroll
        for (int m = 0; m < 4; m++) {
            const int r = fr_a[m];
            const int cbs = cb ^ ((r >> 1) & 3);
            ah[m] = *reinterpret_cast<const bf16x8*>(&sh[buf][AHI + r * 32 + cbs * 8]);
            al[m] = *reinterpret_cast<const bf16x8*>(&sh[buf][ALO + r * 32 + cbs * 8]);
        }
#pragma unroll
        for (int n = 0; n < 4; n++) {
            const int r = fr_b[n];
            const int cbs = cb ^ ((r >> 1) & 3);
            bh[n] = *reinterpret_cast<const bf16x8*>(&sh[buf][BHI + r * 32 + cbs * 8]);
            bl[n] = *reinterpret_cast<const bf16x8*>(&sh[buf][BLO + r * 32 + cbs * 8]);
        }
#pragma unroll
        for (int m = 0; m < 4; m++)
#pragma unroll
            for (int n = 0; n < 4; n++) {
                acc[m][n] = __builtin_amdgcn_mfma_f32_16x16x32_bf16(ah[m], bh[n], acc[m][n], 0, 0, 0);
                acc[m][n] = __builtin_amdgcn_mfma_f32_16x16x32_bf16(ah[m], bl[n], acc[m][n], 0, 0, 0);
                acc[m][n] = __builtin_amdgcn_mfma_f32_16x16x32_bf16(al[m], bh[n], acc[m][n], 0, 0, 0);
            }
    };

    stage(0, kbeg);
    __syncthreads();
    int cur = 0;
    for (int t = 0; t < 7; t++) {
        stage(cur ^ 1, kbeg + (t + 1) * 32);
        compute(cur);
        __syncthreads();
        cur ^= 1;
    }
    compute(cur);

    const int lcol = l & 15, lrow = (l >> 4) * 4;
#pragma unroll
    for (int n = 0; n < 4; n++) {
        const int colg = col0 + wc * 64 + n * 16 + lcol;
#pragma unroll
        for (int m = 0; m < 4; m++) {
            const int rowg = row0 + wr * 64 + m * 16 + lrow;
#pragma unroll
            for (int v = 0; v < 4; v++)
                C[(size_t)(rowg + v) * HDIM + colg] = acc[m][n][v];
        }
    }
}

// ---------------------------------------------------------------------------
// Fused: blocks <1024 reduce 4 M-parts -> bf16 hi/lo; blocks 1024..1027 do
// wreduce (w[c] = sum over 64 wpart slices).
// ---------------------------------------------------------------------------
__global__ __launch_bounds__(256) void reduceMw_convert(const float* __restrict__ Mparts,
                                                        unsigned short* __restrict__ Mhi,
                                                        unsigned short* __restrict__ Mlo,
                                                        const float* __restrict__ wpart,
                                                        float* __restrict__ w) {
    if (blockIdx.x >= 1024) {
        const int c = (blockIdx.x - 1024) * 256 + threadIdx.x;
        float s = 0.f;
#pragma unroll
        for (int b = 0; b < 64; b++) s += wpart[(size_t)b * HDIM + c];
        w[c] = s;
        return;
    }
    const int idx4 = blockIdx.x * 256 + threadIdx.x;
    float4 s = {0.f, 0.f, 0.f, 0.f};
#pragma unroll
    for (int z = 0; z < 4; z++) {
        float4 v = reinterpret_cast<const float4*>(Mparts + (size_t)z * HDIM * HDIM)[idx4];
        s.x += v.x; s.y += v.y; s.z += v.z; s.w += v.w;
    }
    ushort4 h, l;
    h.x = f2bf(s.x); l.x = f2bf(s.x - bf2f(h.x));
    h.y = f2bf(s.y); l.y = f2bf(s.y - bf2f(h.y));
    h.z = f2bf(s.z); l.z = f2bf(s.z - bf2f(h.z));
    h.w = f2bf(s.w); l.w = f2bf(s.w - bf2f(h.w));
    reinterpret_cast<ushort4*>(Mhi)[idx4] = h;
    reinterpret_cast<ushort4*>(Mlo)[idx4] = l;
}

// ---------------------------------------------------------------------------
// Big GEMM (t = K @ M^T), 128x128 tile, BK=32, 4 waves, double-buffered LDS
// (round-11/13 proven: 51.2us). Natural block mapping (round-10: no swizzle).
// Epilogue: packed u32 (hi|lo<<16), 4B stores (round-12 lesson).
// ---------------------------------------------------------------------------
__global__ __launch_bounds__(256, 2) void gemm_t(
        const unsigned short* __restrict__ Ahi, const unsigned short* __restrict__ Alo,
        const unsigned short* __restrict__ Bhi, const unsigned short* __restrict__ Blo,
        unsigned* __restrict__ Tpack) {
    __shared__ unsigned short sh[2][16384];   // 2 x 32 KB
    const int AHI = 0, ALO = 4096, BHI = 8192, BLO = 12288;
    const int tid = threadIdx.x;
    const int w = tid >> 6, l = tid & 63;
    const int wr = w >> 1, wc = w & 1;
    const int row0 = blockIdx.x * 128, col0 = blockIdx.y * 128;
    const int srow0 = (l >> 2), scbp = l & 3;

    f32x4 acc[4][4];
#pragma unroll
    for (int m = 0; m < 4; m++)
#pragma unroll
        for (int n = 0; n < 4; n++) acc[m][n] = (f32x4){0.f, 0.f, 0.f, 0.f};

    const int fr_a[4] = {wr * 64 + (l & 15), wr * 64 + 16 + (l & 15),
                         wr * 64 + 32 + (l & 15), wr * 64 + 48 + (l & 15)};
    const int fr_b[4] = {wc * 64 + (l & 15), wc * 64 + 16 + (l & 15),
                         wc * 64 + 32 + (l & 15), wc * 64 + 48 + (l & 15)};
    const int cb = l >> 4;

    auto stage = [&](int buf, int k0) {
#pragma unroll
        for (int i = 0; i < 2; i++) {
            const int seg = i * 4 + w;
            const int row = seg * 16 + srow0;
            const int cbs = scbp ^ ((row >> 1) & 3);
            gload16(Ahi + (size_t)(row0 + row) * HDIM + k0 + cbs * 8, &sh[buf][AHI + seg * 512]);
            gload16(Alo + (size_t)(row0 + row) * HDIM + k0 + cbs * 8, &sh[buf][ALO + seg * 512]);
            gload16(Bhi + (size_t)(col0 + row) * HDIM + k0 + cbs * 8, &sh[buf][BHI + seg * 512]);
            gload16(Blo + (size_t)(col0 + row) * HDIM + k0 + cbs * 8, &sh[buf][BLO + seg * 512]);
        }
    };
    auto compute = [&](int buf) {
        bf16x8 ah[4], al[4], bh[4], bl[4];
#pragma unroll
        for (int m = 0; m < 4; m++) {
            const int r = fr_a[m];
            const int cbs = cb ^ ((r >> 1) & 3);
            ah[m] = *reinterpret_cast<const bf16x8*>(&sh[buf][AHI + r * 32 + cbs * 8]);
            al[m] = *reinterpret_cast<const bf16x8*>(&sh[buf][ALO + r * 32 + cbs * 8]);
        }
#pragma unroll
        for (int n = 0; n < 4; n++) {
            const int r = fr_b[n];
            const int cbs = cb ^ ((r >> 1) & 3);
            bh[n] = *reinterpret_cast<const bf16x8*>(&sh[buf][BHI + r * 32 + cbs * 8]);
            bl[n] = *reinterpret_cast<const bf16x8*>(&sh[buf][BLO + r * 32 + cbs * 8]);
        }
#pragma unroll
        for (int m = 0; m < 4; m++)
#pragma unroll
            for (int n = 0; n < 4; n++) {
                acc[m][n] = __builtin_amdgcn_mfma_f32_16x16x32_bf16(ah[m], bh[n], acc[m][n], 0, 0, 0);
                acc[m][n] = __builtin_amdgcn_mfma_f32_16x16x32_bf16(ah[m], bl[n], acc[m][n], 0, 0, 0);
                acc[m][n] = __builtin_amdgcn_mfma_f32_16x16x32_bf16(al[m], bh[n], acc[m][n], 0, 0, 0);
            }
    };

    stage(0, 0);
    __syncthreads();
    int cur = 0;
    for (int t = 0; t < 31; t++) {
        stage(cur ^ 1, (t + 1) * 32);
        compute(cur);
        __syncthreads();
        cur ^= 1;
    }
    compute(cur);

    const int lcol = l & 15, lrow = (l >> 4) * 4;
#pragma unroll
    for (int n = 0; n < 4; n++) {
        const int colg = col0 + wc * 64 + n * 16 + lcol;
#pragma unroll
        for (int m = 0; m < 4; m++) {
            const int rowg = row0 + wr * 64 + m * 16 + lrow;
#pragma unroll
            for (int v = 0; v < 4; v++) {
                const float x = acc[m][n][v];
                const unsigned short h = f2bf(x);
                const unsigned short lo = f2bf(x - bf2f(h));
                Tpack[(size_t)(rowg + v) * HDIM + colg] = (unsigned)h | ((unsigned)lo << 16);
            }
        }
    }
}

// ---------------------------------------------------------------------------
// Shared band-logit compute: 16 q-rows/block, 4 waves split K, logits
// reduced into lds_c[0].
// ---------------------------------------------------------------------------
__device__ __forceinline__ void band_core(const float* __restrict__ q,
                                          const unsigned* __restrict__ tpack,
                                          int r0, int b, int i0, int tid,
                                          float (*lds_c)[16][33]) {
    const int w = tid >> 6, l = tid & 63;
    const int fr = l & 15;
    const int kb = (l >> 4) * 8;

    const float* qrow = q + (size_t)(r0 + fr) * HDIM;
    const size_t tb = (size_t)b * LSEQ * HDIM;

    const int j0 = i0 - 4 + fr;
    const int j1 = i0 + 12 + fr;
    const int j0c = min(max(j0, 0), LSEQ - 1);
    const int j1c = min(max(j1, 0), LSEQ - 1);
    const bool v0 = (j0 >= 0) && (j0 < LSEQ);
    const bool v1 = (j1 >= 0) && (j1 < LSEQ);
    const bool interior = (i0 >= 4) && (i0 + 19 < LSEQ);
    const uintx4 uz = {0u, 0u, 0u, 0u};

    f32x4 c0 = {0.f, 0.f, 0.f, 0.f};
    f32x4 c1 = {0.f, 0.f, 0.f, 0.f};

#pragma unroll 2
    for (int ks = 0; ks < 8; ks++) {
        const int k0 = w * 256 + ks * 32 + kb;
        float4 qa = *reinterpret_cast<const float4*>(qrow + k0);
        float4 qb = *reinterpret_cast<const float4*>(qrow + k0 + 4);
        uintx4 w00 = *reinterpret_cast<const uintx4*>(&tpack[tb + (size_t)j0c * HDIM + k0]);
        uintx4 w01 = *reinterpret_cast<const uintx4*>(&tpack[tb + (size_t)j0c * HDIM + k0 + 4]);
        uintx4 w10 = *reinterpret_cast<const uintx4*>(&tpack[tb + (size_t)j1c * HDIM + k0]);
        uintx4 w11 = *reinterpret_cast<const uintx4*>(&tpack[tb + (size_t)j1c * HDIM + k0 + 4]);
        if (!interior) {
            if (!v0) { w00 = uz; w01 = uz; }
            if (!v1) { w10 = uz; w11 = uz; }
        }
        bf16x8 ah, al, b0h, b0l, b1h, b1l;
        split8(qa, qb, ah, al);
        unpack8(w00, w01, b0h, b0l);
        unpack8(w10, w11, b1h, b1l);
        c0 = __builtin_amdgcn_mfma_f32_16x16x32_bf16(ah, b0h, c0, 0, 0, 0);
        c0 = __builtin_amdgcn_mfma_f32_16x16x32_bf16(ah, b0l, c0, 0, 0, 0);
        c0 = __builtin_amdgcn_mfma_f32_16x16x32_bf16(al, b0h, c0, 0, 0, 0);
        c1 = __builtin_amdgcn_mfma_f32_16x16x32_bf16(ah, b1h, c1, 0, 0, 0);
        c1 = __builtin_amdgcn_mfma_f32_16x16x32_bf16(ah, b1l, c1, 0, 0, 0);
        c1 = __builtin_amdgcn_mfma_f32_16x16x32_bf16(al, b1h, c1, 0, 0, 0);
    }

#pragma unroll
    for (int v = 0; v < 4; v++) {
        lds_c[w][(l >> 4) * 4 + v][fr] = c0[v];
        lds_c[w][(l >> 4) * 4 + v][16 + fr] = c1[v];
    }
    __syncthreads();

#pragma unroll
    for (int e = tid; e < 512; e += 256) {
        const int rr = e >> 5, cc = e & 31;
        lds_c[0][rr][cc] = lds_c[0][rr][cc] + lds_c[1][rr][cc] +
                           lds_c[2][rr][cc] + lds_c[3][rr][cc];
    }
    __syncthreads();
}

// ---------------------------------------------------------------------------
// band_mfma (fallback path): writes 9 probs per row to band buffer.
// ---------------------------------------------------------------------------
__global__ __launch_bounds__(256) void band_mfma(const float* __restrict__ q,
                                                 const unsigned* __restrict__ tpack,
                                                 const float* __restrict__ beta,
                                                 float* __restrict__ band) {
    __shared__ float lds_c[4][16][33];
    const int tid = threadIdx.x;
    const int r0 = blockIdx.x * 16;
    const int b = r0 >> 11;
    const int i0 = r0 & (LSEQ - 1);
    band_core(q, tpack, r0, b, i0, tid, lds_c);

    if (tid < 16) {
        const int il = i0 + tid;
        const int ig = r0 + tid;
        float lg[NBAND];
#pragma unroll
        for (int d = 0; d < NBAND; d++) {
            const int j = il + d - 4;
            lg[d] = (j >= 0 && j < LSEQ)
                    ? lds_c[0][tid][tid + d] + beta[(size_t)b * LSEQ + j]
                    : -1e30f;
        }
        float m = -1e30f;
#pragma unroll
        for (int d = 0; d < NBAND; d++) m = fmaxf(m, lg[d]);
        float p[NBAND], s = 0.f;
#pragma unroll
        for (int d = 0; d < NBAND; d++) { p[d] = expf(lg[d] - m); s += p[d]; }
        const float inv = 1.f / s;
#pragma unroll
        for (int d = 0; d < NBAND; d++) band[(size_t)ig * NBAND + d] = p[d] * inv;
    }
}

// ---------------------------------------------------------------------------
// band_fuse (ws-large path): computes probs in-block and writes the dense
// 16x2048 output tile directly. tpack lives in d_ws.
// ---------------------------------------------------------------------------
__global__ __launch_bounds__(256) void band_fuse(const float* __restrict__ q,
                                                 const unsigned* __restrict__ tpack,
                                                 const float* __restrict__ beta,
                                                 float* __restrict__ out) {
    __shared__ float lds_c[4][16][33];
    const int tid = threadIdx.x;
    const int r0 = blockIdx.x * 16;
    const int b = r0 >> 11;
    const int i0 = r0 & (LSEQ - 1);
    band_core(q, tpack, r0, b, i0, tid, lds_c);

    float* pr = &lds_c[1][0][0];   // 144 floats, region dead after reduce
    if (tid < 16) {
        const int il = i0 + tid;
        float lg[NBAND];
#pragma unroll
        for (int d = 0; d < NBAND; d++) {
            const int j = il + d - 4;
            lg[d] = (j >= 0 && j < LSEQ)
                    ? lds_c[0][tid][tid + d] + beta[(size_t)b * LSEQ + j]
                    : -1e30f;
        }
        float m = -1e30f;
#pragma unroll
        for (int d = 0; d < NBAND; d++) m = fmaxf(m, lg[d]);
        float p[NBAND], s = 0.f;
#pragma unroll
        for (int d = 0; d < NBAND; d++) { p[d] = expf(lg[d] - m); s += p[d]; }
        const float inv = 1.f / s;
#pragma unroll
        for (int d = 0; d < NBAND; d++) pr[tid * NBAND + d] = p[d] * inv;
    }
    __syncthreads();

    for (int e = tid; e < 8192; e += 256) {
        const int rr = e >> 9;
        const int c0 = (e & 511) * 4;
        const int il = i0 + rr;
        float v[4];
#pragma unroll
        for (int s = 0; s < 4; s++) {
            const int dj = c0 + s - il + 4;
            v[s] = (dj >= 0 && dj < NBAND) ? pr[rr * NBAND + dj] : 0.f;
        }
        float4 o = {v[0], v[1], v[2], v[3]};
        *reinterpret_cast<float4*>(&out[(size_t)(r0 + rr) * LSEQ + c0]) = o;
    }
}

// ---------------------------------------------------------------------------
// Expand band probs into dense [B, L, L] output (fallback path).
// ---------------------------------------------------------------------------
__global__ __launch_bounds__(256) void expand_band(const float* __restrict__ band,
                                                   float* __restrict__ out) {
    const size_t idx4 = (size_t)blockIdx.x * 256 + threadIdx.x;
    const size_t flat = idx4 * 4;
    const int j0 = (int)(flat & (LSEQ - 1));
    const size_t row = flat >> 11;
    const int i = (int)(row & (LSEQ - 1));
    float v[4];
#pragma unroll
    for (int s = 0; s < 4; s++) {
        const int dj = (j0 + s) - i + 4;
        v[s] = (dj >= 0 && dj < NBAND) ? band[row * NBAND + dj] : 0.f;
    }
    float4 o = {v[0], v[1], v[2], v[3]};
    *reinterpret_cast<float4*>(&out[flat]) = o;
}

// ---------------------------------------------------------------------------
// Fallback fp32 path (ws too small).
// ---------------------------------------------------------------------------
__global__ __launch_bounds__(256) void gemm_nt_bias(const float* __restrict__ A,
                                                    const float* __restrict__ B,
                                                    const float* __restrict__ bias,
                                                    float* __restrict__ C) {
    __shared__ float As[8][132];
    __shared__ float Bs[8][132];
    const int tid = threadIdx.x;
    const int row0 = blockIdx.x * 128, col0 = blockIdx.y * 128;
    const int lr = tid >> 1, lc = (tid & 1) * 4;
    const int tx = tid & 15, ty = tid >> 4;
    float acc[2][2][4][4];
#pragma unroll
    for (int a = 0; a < 2; a++)
#pragma unroll
        for (int b = 0; b < 2; b++)
#pragma unroll
            for (int c = 0; c < 4; c++)
#pragma unroll
                for (int d = 0; d < 4; d++) acc[a][b][c][d] = 0.f;
    for (int k0 = 0; k0 < HDIM; k0 += 8) {
        float4 av = *reinterpret_cast<const float4*>(&A[(size_t)(row0 + lr) * HDIM + k0 + lc]);
        float4 bv = *reinterpret_cast<const float4*>(&B[(size_t)(col0 + lr) * HDIM + k0 + lc]);
        __syncthreads();
        As[lc + 0][lr] = av.x; As[lc + 1][lr] = av.y; As[lc + 2][lr] = av.z; As[lc + 3][lr] = av.w;
        Bs[lc + 0][lr] = bv.x; Bs[lc + 1][lr] = bv.y; Bs[lc + 2][lr] = bv.z; Bs[lc + 3][lr] = bv.w;
        __syncthreads();
#pragma unroll
        for (int kk = 0; kk < 8; kk++) {
            float4 a0 = *reinterpret_cast<const float4*>(&As[kk][ty * 4]);
            float4 a1 = *reinterpret_cast<const float4*>(&As[kk][64 + ty * 4]);
            float4 b0 = *reinterpret_cast<const float4*>(&Bs[kk][tx * 4]);
            float4 b1 = *reinterpret_cast<const float4*>(&Bs[kk][64 + tx * 4]);
            float am[2][4] = {{a0.x, a0.y, a0.z, a0.w}, {a1.x, a1.y, a1.z, a1.w}};
            float bw[2][4] = {{b0.x, b0.y, b0.z, b0.w}, {b1.x, b1.y, b1.z, b1.w}};
#pragma unroll
            for (int mi = 0; mi < 2; mi++)
#pragma unroll
                for (int ni = 0; ni < 2; ni++)
#pragma unroll
                    for (int mm = 0; mm < 4; mm++)
#pragma unroll
                        for (int nn = 0; nn < 4; nn++)
                            acc[mi][ni][mm][nn] += am[mi][mm] * bw[ni][nn];
        }
    }
#pragma unroll
    for (int mi = 0; mi < 2; mi++)
#pragma unroll
        for (int mm = 0; mm < 4; mm++) {
            const int r = row0 + mi * 64 + ty * 4 + mm;
#pragma unroll
            for (int ni = 0; ni < 2; ni++) {
                const int c = col0 + ni * 64 + tx * 4;
                float4 o;
                o.x = acc[mi][ni][mm][0] + bias[c + 0];
                o.y = acc[mi][ni][mm][1] + bias[c + 1];
                o.z = acc[mi][ni][mm][2] + bias[c + 2];
                o.w = acc[mi][ni][mm][3] + bias[c + 3];
                *reinterpret_cast<float4*>(&C[(size_t)r * HDIM + c]) = o;
            }
        }
}

__global__ __launch_bounds__(256) void band_softmax(const float* __restrict__ qs,
                                                    const float* __restrict__ ks,
                                                    float* __restrict__ band) {
    const int wave = threadIdx.x >> 6;
    const int lane = threadIdx.x & 63;
    const int r = blockIdx.x * 4 + wave;
    const int b = r >> 11;
    const int i = r & (LSEQ - 1);
    const float* qrow = qs + (size_t)r * HDIM;
    const float* kbase = ks + (size_t)b * LSEQ * HDIM;
    float acc[NBAND];
#pragma unroll
    for (int d = 0; d < NBAND; d++) acc[d] = 0.f;
    for (int h = lane; h < HDIM; h += 64) {
        const float qv = qrow[h];
#pragma unroll
        for (int d = 0; d < NBAND; d++) {
            const int j = i + d - 4;
            if (j >= 0 && j < LSEQ)
                acc[d] += qv * kbase[(size_t)j * HDIM + h];
        }
    }
#pragma unroll
    for (int d = 0; d < NBAND; d++) {
        float v = acc[d];
#pragma unroll
        for (int off = 32; off > 0; off >>= 1) v += __shfl_xor(v, off, 64);
        acc[d] = v;
    }
    if (lane == 0) {
        float m = -1e30f;
#pragma unroll
        for (int d = 0; d < NBAND; d++) {
            const int j = i + d - 4;
            if (j >= 0 && j < LSEQ) m = fmaxf(m, acc[d]);
        }
        float p[NBAND];
        float s = 0.f;
#pragma unroll
        for (int d = 0; d < NBAND; d++) {
            const int j = i + d - 4;
            p[d] = (j >= 0 && j < LSEQ) ? expf(acc[d] - m) : 0.f;
            s += p[d];
        }
        const float inv = 1.f / s;
#pragma unroll
        for (int d = 0; d < NBAND; d++) band[(size_t)r * NBAND + d] = p[d] * inv;
    }
}

extern "C" void kernel_launch(void* const* d_in, const int* in_sizes, int n_in,
                              void* d_out, int out_size, void* d_ws, size_t ws_size,
                              hipStream_t stream) {
    const float* q  = (const float*)d_in[0];
    const float* k  = (const float*)d_in[1];
    const float* Wq = (const float*)d_in[2];
    const float* bq = (const float*)d_in[3];
    const float* Wk = (const float*)d_in[4];
    const float* bk = (const float*)d_in[5];
    float* out = (float*)d_out;

    // ---- workspace layout ----
    const size_t bandB = (size_t)ROWS * NBAND * sizeof(float);
    char* p = (char*)d_ws;
    float* band = (float*)p;                 p += bandB;
    unsigned short* Xhi = (unsigned short*)p; p += (size_t)ROWS * HDIM * 2;   // 16 MB
    unsigned short* Xlo = (unsigned short*)p; p += (size_t)ROWS * HDIM * 2;   // 16 MB
    unsigned short* Mhi = (unsigned short*)p; p += (size_t)HDIM * HDIM * 2;   // 2 MB
    unsigned short* Mlo = (unsigned short*)p; p += (size_t)HDIM * HDIM * 2;   // 2 MB
    float* w        = (float*)p;             p += HDIM * sizeof(float);
    float* wpart    = (float*)p;             p += 64 * HDIM * sizeof(float);
    float* beta     = (float*)p;             p += ROWS * sizeof(float);
    const size_t need = (size_t)(p - (char*)d_ws);
    const size_t tpackOff = (need + 255) & ~(size_t)255;
    const size_t need2 = tpackOff + (size_t)ROWS * HDIM * sizeof(unsigned);   // +32 MB

    unsigned short* WqTh = Xhi;
    unsigned short* WqTl = Xhi + (size_t)HDIM * HDIM;
    unsigned short* WkTh = Xhi + 2 * (size_t)HDIM * HDIM;
    unsigned short* WkTl = Xhi + 3 * (size_t)HDIM * HDIM;

    // Mparts always in d_out [32,48MB) (dead before final output writes)
    float* Mparts = (float*)((char*)out + 32ull * 1024 * 1024);

    if (ws_size >= need) {
        dim3 tg(16, 16, 3);
        tcw_kernel<<<tg, 256, 0, stream>>>(Wq, Wk, bq, WqTh, WqTl, WkTh, WkTl, wpart);
        dim3 mg(8, 8, 4);
        gemm_part<<<mg, 256, 0, stream>>>(WqTh, WqTl, WkTh, WkTl, Mparts);
        reduceMw_convert<<<1028, 256, 0, stream>>>(Mparts, Mhi, Mlo, wpart, w);
        convert_k_beta<<<ROWS / 4, 256, 0, stream>>>(k, w, Xhi, Xlo, beta);
        dim3 gg(ROWS / 128, HDIM / 128);
        if (ws_size >= need2) {
            unsigned* tpack = (unsigned*)((char*)d_ws + tpackOff);
            gemm_t<<<gg, 256, 0, stream>>>(Xhi, Xlo, Mhi, Mlo, tpack);
            band_fuse<<<ROWS / 16, 256, 0, stream>>>(q, tpack, beta, out);
        } else {
            unsigned* tpack = (unsigned*)out;
            gemm_t<<<gg, 256, 0, stream>>>(Xhi, Xlo, Mhi, Mlo, tpack);
            band_mfma<<<ROWS / 16, 256, 0, stream>>>(q, tpack, beta, band);
            expand_band<<<(size_t)ROWS * LSEQ / 4 / 256, 256, 0, stream>>>(band, out);
        }
    } else {
        float* qs = out;
        float* ks = out + (size_t)ROWS * HDIM;
        dim3 gg(ROWS / 128, HDIM / 128);
        gemm_nt_bias<<<gg, 256, 0, stream>>>(q, Wq, bq, qs);
        gemm_nt_bias<<<gg, 256, 0, stream>>>(k, Wk, bk, ks);
        band_softmax<<<ROWS / 4, 256, 0, stream>>>(qs, ks, band);
        expand_band<<<(size_t)ROWS * LSEQ / 4 / 256, 256, 0, stream>>>(band, out);
    }
}

// Round 17
// 126.425 us; speedup vs baseline: 1.1766x; 1.0039x over previous
//
#include <hip/hip_runtime.h>
#include <math.h>

#define LSEQ 2048
#define HDIM 1024
#define BATCH 4
#define ROWS (BATCH * LSEQ)   // 8192
#define NBAND 9               // |i-j| <= 4

typedef __attribute__((ext_vector_type(8))) short bf16x8;
typedef __attribute__((ext_vector_type(4))) float f32x4;
typedef __attribute__((ext_vector_type(8))) unsigned short u16x8;
typedef __attribute__((ext_vector_type(4))) unsigned uintx4;

#define AS3 __attribute__((address_space(3)))
#define AS1 __attribute__((address_space(1)))

__device__ __forceinline__ void gload16(const void* gp, void* lp) {
    __builtin_amdgcn_global_load_lds((AS1 const unsigned*)gp, (AS3 unsigned*)lp, 16, 0, 0);
}

__device__ __forceinline__ unsigned short f2bf(float x) {
    unsigned u = __float_as_uint(x);
    u += 0x7FFFu + ((u >> 16) & 1u);
    return (unsigned short)(u >> 16);
}
__device__ __forceinline__ float bf2f(unsigned short h) {
    return __uint_as_float(((unsigned)h) << 16);
}

__device__ __forceinline__ void split8(float4 a, float4 b, bf16x8& hi, bf16x8& lo) {
    float v[8] = {a.x, a.y, a.z, a.w, b.x, b.y, b.z, b.w};
#pragma unroll
    for (int j = 0; j < 8; j++) {
        unsigned short h = f2bf(v[j]);
        hi[j] = (short)h;
        lo[j] = (short)f2bf(v[j] - bf2f(h));
    }
}

// unpack 8 packed u32 (hi|lo<<16) into hi/lo bf16x8 fragments via v_perm
__device__ __forceinline__ void unpack8(uintx4 w0, uintx4 w1, bf16x8& hi, bf16x8& lo) {
    union { bf16x8 v; uintx4 u; } H, L;
    H.u[0] = __builtin_amdgcn_perm(w0[1], w0[0], 0x05040100u);
    H.u[1] = __builtin_amdgcn_perm(w0[3], w0[2], 0x05040100u);
    H.u[2] = __builtin_amdgcn_perm(w1[1], w1[0], 0x05040100u);
    H.u[3] = __builtin_amdgcn_perm(w1[3], w1[2], 0x05040100u);
    L.u[0] = __builtin_amdgcn_perm(w0[1], w0[0], 0x07060302u);
    L.u[1] = __builtin_amdgcn_perm(w0[3], w0[2], 0x07060302u);
    L.u[2] = __builtin_amdgcn_perm(w1[1], w1[0], 0x07060302u);
    L.u[3] = __builtin_amdgcn_perm(w1[3], w1[2], 0x07060302u);
    hi = H.v; lo = L.v;
}

// ---------------------------------------------------------------------------
// Fused: z<2 -> transposed split-convert of Wq/Wk; z==2 -> wpart (64 blocks).
// ---------------------------------------------------------------------------
__global__ __launch_bounds__(256) void tcw_kernel(const float* __restrict__ Wq,
                                                  const float* __restrict__ Wk,
                                                  const float* __restrict__ bq,
                                                  unsigned short* __restrict__ qhi,
                                                  unsigned short* __restrict__ qlo,
                                                  unsigned short* __restrict__ khi,
                                                  unsigned short* __restrict__ klo,
                                                  float* __restrict__ wpart) {
    const int z = blockIdx.z;
    const int tid = threadIdx.x;
    if (z == 2) {
        const int fid = blockIdx.y * 16 + blockIdx.x;
        if (fid >= 64) return;
        const int c0 = tid * 4;
        float4 acc = {0.f, 0.f, 0.f, 0.f};
#pragma unroll
        for (int hh = 0; hh < 16; hh++) {
            const int h = fid * 16 + hh;
            const float s = bq[h];
            float4 v = *reinterpret_cast<const float4*>(&Wk[(size_t)h * HDIM + c0]);
            acc.x += v.x * s; acc.y += v.y * s; acc.z += v.z * s; acc.w += v.w * s;
        }
        *reinterpret_cast<float4*>(&wpart[(size_t)fid * HDIM + c0]) = acc;
        return;
    }
    __shared__ float tile[64][65];
    const float* src = z ? Wk : Wq;
    unsigned short* dh = z ? khi : qhi;
    unsigned short* dl = z ? klo : qlo;
    const int n0 = blockIdx.x * 64;
    const int h0 = blockIdx.y * 64;

#pragma unroll
    for (int p = 0; p < 4; p++) {
        const int h = p * 16 + (tid >> 4);
        const int n = (tid & 15) * 4;
        float4 v = *reinterpret_cast<const float4*>(&src[(size_t)(h0 + h) * HDIM + n0 + n]);
        tile[h][n + 0] = v.x; tile[h][n + 1] = v.y; tile[h][n + 2] = v.z; tile[h][n + 3] = v.w;
    }
    __syncthreads();
#pragma unroll
    for (int p = 0; p < 2; p++) {
        const int n = p * 32 + (tid >> 3);
        const int h = (tid & 7) * 8;
        u16x8 hv, lv;
#pragma unroll
        for (int j = 0; j < 8; j++) {
            float x = tile[h + j][n];
            unsigned short hb = f2bf(x);
            hv[j] = hb;
            lv[j] = f2bf(x - bf2f(hb));
        }
        *reinterpret_cast<u16x8*>(&dh[(size_t)(n0 + n) * HDIM + h0 + h]) = hv;
        *reinterpret_cast<u16x8*>(&dl[(size_t)(n0 + n) * HDIM + h0 + h]) = lv;
    }
}

// ---------------------------------------------------------------------------
// Fused convert+beta, 4 rows per block (verified round 16).
// ---------------------------------------------------------------------------
__global__ __launch_bounds__(256) void convert_k_beta(const float* __restrict__ k,
                                                      const float* __restrict__ w,
                                                      unsigned short* __restrict__ Xhi,
                                                      unsigned short* __restrict__ Xlo,
                                                      float* __restrict__ beta) {
    const int wv = threadIdx.x >> 6;
    const int l = threadIdx.x & 63;
    const int r = blockIdx.x * 4 + wv;
    const float4* krow = reinterpret_cast<const float4*>(k + (size_t)r * HDIM);
    const float4* wrow = reinterpret_cast<const float4*>(w);
    ushort4* XH = reinterpret_cast<ushort4*>(Xhi) + (size_t)r * 256;
    ushort4* XL = reinterpret_cast<ushort4*>(Xlo) + (size_t)r * 256;

    float d = 0.f;
#pragma unroll
    for (int p = 0; p < 4; p++) {
        const int idx = p * 64 + l;
        float4 v = krow[idx];
        float4 ww = wrow[idx];
        ushort4 h, lo;
        h.x = f2bf(v.x); lo.x = f2bf(v.x - bf2f(h.x));
        h.y = f2bf(v.y); lo.y = f2bf(v.y - bf2f(h.y));
        h.z = f2bf(v.z); lo.z = f2bf(v.z - bf2f(h.z));
        h.w = f2bf(v.w); lo.w = f2bf(v.w - bf2f(h.w));
        XH[idx] = h;
        XL[idx] = lo;
        d += v.x * ww.x + v.y * ww.y + v.z * ww.z + v.w * ww.w;
    }
#pragma unroll
    for (int off = 32; off > 0; off >>= 1) d += __shfl_xor(d, off, 64);
    if (l == 0) beta[r] = d;
}

// ---------------------------------------------------------------------------
// Split-K GEMM for M = WqT @ WkT^T: grid (8,8,4), dbuf (verified round 16).
// ---------------------------------------------------------------------------
__global__ __launch_bounds__(256, 2) void gemm_part(
        const unsigned short* __restrict__ Ahi, const unsigned short* __restrict__ Alo,
        const unsigned short* __restrict__ Bhi, const unsigned short* __restrict__ Blo,
        float* __restrict__ Cparts) {
    __shared__ unsigned short sh[2][16384];
    const int AHI = 0, ALO = 4096, BHI = 8192, BLO = 12288;
    const int tid = threadIdx.x;
    const int w = tid >> 6, l = tid & 63;
    const int wr = w >> 1, wc = w & 1;
    const int row0 = blockIdx.x * 128, col0 = blockIdx.y * 128;
    const int kbeg = blockIdx.z * 256;
    float* C = Cparts + (size_t)blockIdx.z * HDIM * HDIM;
    const int srow0 = (l >> 2), scbp = l & 3;

    f32x4 acc[4][4];
#pragma unroll
    for (int m = 0; m < 4; m++)
#pragma unroll
        for (int n = 0; n < 4; n++) acc[m][n] = (f32x4){0.f, 0.f, 0.f, 0.f};

    const int fr_a[4] = {wr * 64 + (l & 15), wr * 64 + 16 + (l & 15),
                         wr * 64 + 32 + (l & 15), wr * 64 + 48 + (l & 15)};
    const int fr_b[4] = {wc * 64 + (l & 15), wc * 64 + 16 + (l & 15),
                         wc * 64 + 32 + (l & 15), wc * 64 + 48 + (l & 15)};
    const int cb = l >> 4;

    auto stage = [&](int buf, int k0) {
#pragma unroll
        for (int i = 0; i < 2; i++) {
            const int seg = i * 4 + w;
            const int row = seg * 16 + srow0;
            const int cbs = scbp ^ ((row >> 1) & 3);
            gload16(Ahi + (size_t)(row0 + row) * HDIM + k0 + cbs * 8, &sh[buf][AHI + seg * 512]);
            gload16(Alo + (size_t)(row0 + row) * HDIM + k0 + cbs * 8, &sh[buf][ALO + seg * 512]);
            gload16(Bhi + (size_t)(col0 + row) * HDIM + k0 + cbs * 8, &sh[buf][BHI + seg * 512]);
            gload16(Blo + (size_t)(col0 + row) * HDIM + k0 + cbs * 8, &sh[buf][BLO + seg * 512]);
        }
    };
    auto compute = [&](int buf) {
        bf16x8 ah[4], al[4], bh[4], bl[4];
#pragma unroll
        for (int m = 0; m < 4; m++) {
            const int r = fr_a[m];
            const int cbs = cb ^ ((r >> 1) & 3);
            ah[m] = *reinterpret_cast<const bf16x8*>(&sh[buf][AHI + r * 32 + cbs * 8]);
            al[m] = *reinterpret_cast<const bf16x8*>(&sh[buf][ALO + r * 32 + cbs * 8]);
        }
#pragma unroll
        for (int n = 0; n < 4; n++) {
            const int r = fr_b[n];
            const int cbs = cb ^ ((r >> 1) & 3);
            bh[n] = *reinterpret_cast<const bf16x8*>(&sh[buf][BHI + r * 32 + cbs * 8]);
            bl[n] = *reinterpret_cast<const bf16x8*>(&sh[buf][BLO + r * 32 + cbs * 8]);
        }
#pragma unroll
        for (int m = 0; m < 4; m++)
#pragma unroll
            for (int n = 0; n < 4; n++) {
                acc[m][n] = __builtin_amdgcn_mfma_f32_16x16x32_bf16(ah[m], bh[n], acc[m][n], 0, 0, 0);
                acc[m][n] = __builtin_amdgcn_mfma_f32_16x16x32_bf16(ah[m], bl[n], acc[m][n], 0, 0, 0);
                acc[m][n] = __builtin_amdgcn_mfma_f32_16x16x32_bf16(al[m], bh[n], acc[m][n], 0, 0, 0);
            }
    };

    stage(0, kbeg);
    __syncthreads();
    int cur = 0;
    for (int t = 0; t < 7; t++) {
        stage(cur ^ 1, kbeg + (t + 1) * 32);
        compute(cur);
        __syncthreads();
        cur ^= 1;
    }
    compute(cur);

    const int lcol = l & 15, lrow = (l >> 4) * 4;
#pragma unroll
    for (int n = 0; n < 4; n++) {
        const int colg = col0 + wc * 64 + n * 16 + lcol;
#pragma unroll
        for (int m = 0; m < 4; m++) {
            const int rowg = row0 + wr * 64 + m * 16 + lrow;
#pragma unroll
            for (int v = 0; v < 4; v++)
                C[(size_t)(rowg + v) * HDIM + colg] = acc[m][n][v];
        }
    }
}

// ---------------------------------------------------------------------------
// Fused: blocks <1024 reduce 4 M-parts -> bf16 hi/lo; blocks 1024..1027 do
// wreduce.
// ---------------------------------------------------------------------------
__global__ __launch_bounds__(256) void reduceMw_convert(const float* __restrict__ Mparts,
                                                        unsigned short* __restrict__ Mhi,
                                                        unsigned short* __restrict__ Mlo,
                                                        const float* __restrict__ wpart,
                                                        float* __restrict__ w) {
    if (blockIdx.x >= 1024) {
        const int c = (blockIdx.x - 1024) * 256 + threadIdx.x;
        float s = 0.f;
#pragma unroll
        for (int b = 0; b < 64; b++) s += wpart[(size_t)b * HDIM + c];
        w[c] = s;
        return;
    }
    const int idx4 = blockIdx.x * 256 + threadIdx.x;
    float4 s = {0.f, 0.f, 0.f, 0.f};
#pragma unroll
    for (int z = 0; z < 4; z++) {
        float4 v = reinterpret_cast<const float4*>(Mparts + (size_t)z * HDIM * HDIM)[idx4];
        s.x += v.x; s.y += v.y; s.z += v.z; s.w += v.w;
    }
    ushort4 h, l;
    h.x = f2bf(s.x); l.x = f2bf(s.x - bf2f(h.x));
    h.y = f2bf(s.y); l.y = f2bf(s.y - bf2f(h.y));
    h.z = f2bf(s.z); l.z = f2bf(s.z - bf2f(h.z));
    h.w = f2bf(s.w); l.w = f2bf(s.w - bf2f(h.w));
    reinterpret_cast<ushort4*>(Mhi)[idx4] = h;
    reinterpret_cast<ushort4*>(Mlo)[idx4] = l;
}

// ---------------------------------------------------------------------------
// Big GEMM (t = K @ M^T), 128x128 tile, BK=32, dbuf — NOW 8 WAVES (512 thr):
// wave grid 2x4, each wave 64x32 output (4x2 frags, 24 MFMA/K-step).
// 16 waves/CU (2 blocks) = 4 waves/SIMD -> 2x latency hiding vs 4-wave.
// Staging: each wave stages seg w of all 4 arrays (4 gload16/thread).
// Natural block mapping; packed-u32 epilogue (round-12 lesson).
// ---------------------------------------------------------------------------
__global__ __launch_bounds__(512, 2) void gemm_t(
        const unsigned short* __restrict__ Ahi, const unsigned short* __restrict__ Alo,
        const unsigned short* __restrict__ Bhi, const unsigned short* __restrict__ Blo,
        unsigned* __restrict__ Tpack) {
    __shared__ unsigned short sh[2][16384];   // 2 x 32 KB
    const int AHI = 0, ALO = 4096, BHI = 8192, BLO = 12288;
    const int tid = threadIdx.x;
    const int w = tid >> 6, l = tid & 63;     // 8 waves
    const int wr = w >> 2, wc = w & 3;        // 2 x 4 wave grid
    const int row0 = blockIdx.x * 128, col0 = blockIdx.y * 128;
    const int srow0 = (l >> 2), scbp = l & 3;

    f32x4 acc[4][2];
#pragma unroll
    for (int m = 0; m < 4; m++)
#pragma unroll
        for (int n = 0; n < 2; n++) acc[m][n] = (f32x4){0.f, 0.f, 0.f, 0.f};

    const int fr_a[4] = {wr * 64 + (l & 15), wr * 64 + 16 + (l & 15),
                         wr * 64 + 32 + (l & 15), wr * 64 + 48 + (l & 15)};
    const int fr_b[2] = {wc * 32 + (l & 15), wc * 32 + 16 + (l & 15)};
    const int cb = l >> 4;

    auto stage = [&](int buf, int k0) {
        const int seg = w;                        // 0..7, one seg per wave
        const int row = seg * 16 + srow0;         // 0..127
        const int cbs = scbp ^ ((row >> 1) & 3);
        gload16(Ahi + (size_t)(row0 + row) * HDIM + k0 + cbs * 8, &sh[buf][AHI + seg * 512]);
        gload16(Alo + (size_t)(row0 + row) * HDIM + k0 + cbs * 8, &sh[buf][ALO + seg * 512]);
        gload16(Bhi + (size_t)(col0 + row) * HDIM + k0 + cbs * 8, &sh[buf][BHI + seg * 512]);
        gload16(Blo + (size_t)(col0 + row) * HDIM + k0 + cbs * 8, &sh[buf][BLO + seg * 512]);
    };
    auto compute = [&](int buf) {
        bf16x8 ah[4], al[4], bh[2], bl[2];
#pragma unroll
        for (int m = 0; m < 4; m++) {
            const int r = fr_a[m];
            const int cbs = cb ^ ((r >> 1) & 3);
            ah[m] = *reinterpret_cast<const bf16x8*>(&sh[buf][AHI + r * 32 + cbs * 8]);
            al[m] = *reinterpret_cast<const bf16x8*>(&sh[buf][ALO + r * 32 + cbs * 8]);
        }
#pragma unroll
        for (int n = 0; n < 2; n++) {
            const int r = fr_b[n];
            const int cbs = cb ^ ((r >> 1) & 3);
            bh[n] = *reinterpret_cast<const bf16x8*>(&sh[buf][BHI + r * 32 + cbs * 8]);
            bl[n] = *reinterpret_cast<const bf16x8*>(&sh[buf][BLO + r * 32 + cbs * 8]);
        }
#pragma unroll
        for (int m = 0; m < 4; m++)
#pragma unroll
            for (int n = 0; n < 2; n++) {
                acc[m][n] = __builtin_amdgcn_mfma_f32_16x16x32_bf16(ah[m], bh[n], acc[m][n], 0, 0, 0);
                acc[m][n] = __builtin_amdgcn_mfma_f32_16x16x32_bf16(ah[m], bl[n], acc[m][n], 0, 0, 0);
                acc[m][n] = __builtin_amdgcn_mfma_f32_16x16x32_bf16(al[m], bh[n], acc[m][n], 0, 0, 0);
            }
    };

    stage(0, 0);
    __syncthreads();
    int cur = 0;
    for (int t = 0; t < 31; t++) {
        stage(cur ^ 1, (t + 1) * 32);
        compute(cur);
        __syncthreads();
        cur ^= 1;
    }
    compute(cur);

    const int lcol = l & 15, lrow = (l >> 4) * 4;
#pragma unroll
    for (int n = 0; n < 2; n++) {
        const int colg = col0 + wc * 32 + n * 16 + lcol;
#pragma unroll
        for (int m = 0; m < 4; m++) {
            const int rowg = row0 + wr * 64 + m * 16 + lrow;
#pragma unroll
            for (int v = 0; v < 4; v++) {
                const float x = acc[m][n][v];
                const unsigned short h = f2bf(x);
                const unsigned short lo = f2bf(x - bf2f(h));
                Tpack[(size_t)(rowg + v) * HDIM + colg] = (unsigned)h | ((unsigned)lo << 16);
            }
        }
    }
}

// ---------------------------------------------------------------------------
// Shared band-logit compute: 16 q-rows/block, 4 waves split K, logits
// reduced into lds_c[0].
// ---------------------------------------------------------------------------
__device__ __forceinline__ void band_core(const float* __restrict__ q,
                                          const unsigned* __restrict__ tpack,
                                          int r0, int b, int i0, int tid,
                                          float (*lds_c)[16][33]) {
    const int w = tid >> 6, l = tid & 63;
    const int fr = l & 15;
    const int kb = (l >> 4) * 8;

    const float* qrow = q + (size_t)(r0 + fr) * HDIM;
    const size_t tb = (size_t)b * LSEQ * HDIM;

    const int j0 = i0 - 4 + fr;
    const int j1 = i0 + 12 + fr;
    const int j0c = min(max(j0, 0), LSEQ - 1);
    const int j1c = min(max(j1, 0), LSEQ - 1);
    const bool v0 = (j0 >= 0) && (j0 < LSEQ);
    const bool v1 = (j1 >= 0) && (j1 < LSEQ);
    const bool interior = (i0 >= 4) && (i0 + 19 < LSEQ);
    const uintx4 uz = {0u, 0u, 0u, 0u};

    f32x4 c0 = {0.f, 0.f, 0.f, 0.f};
    f32x4 c1 = {0.f, 0.f, 0.f, 0.f};

#pragma unroll 2
    for (int ks = 0; ks < 8; ks++) {
        const int k0 = w * 256 + ks * 32 + kb;
        float4 qa = *reinterpret_cast<const float4*>(qrow + k0);
        float4 qb = *reinterpret_cast<const float4*>(qrow + k0 + 4);
        uintx4 w00 = *reinterpret_cast<const uintx4*>(&tpack[tb + (size_t)j0c * HDIM + k0]);
        uintx4 w01 = *reinterpret_cast<const uintx4*>(&tpack[tb + (size_t)j0c * HDIM + k0 + 4]);
        uintx4 w10 = *reinterpret_cast<const uintx4*>(&tpack[tb + (size_t)j1c * HDIM + k0]);
        uintx4 w11 = *reinterpret_cast<const uintx4*>(&tpack[tb + (size_t)j1c * HDIM + k0 + 4]);
        if (!interior) {
            if (!v0) { w00 = uz; w01 = uz; }
            if (!v1) { w10 = uz; w11 = uz; }
        }
        bf16x8 ah, al, b0h, b0l, b1h, b1l;
        split8(qa, qb, ah, al);
        unpack8(w00, w01, b0h, b0l);
        unpack8(w10, w11, b1h, b1l);
        c0 = __builtin_amdgcn_mfma_f32_16x16x32_bf16(ah, b0h, c0, 0, 0, 0);
        c0 = __builtin_amdgcn_mfma_f32_16x16x32_bf16(ah, b0l, c0, 0, 0, 0);
        c0 = __builtin_amdgcn_mfma_f32_16x16x32_bf16(al, b0h, c0, 0, 0, 0);
        c1 = __builtin_amdgcn_mfma_f32_16x16x32_bf16(ah, b1h, c1, 0, 0, 0);
        c1 = __builtin_amdgcn_mfma_f32_16x16x32_bf16(ah, b1l, c1, 0, 0, 0);
        c1 = __builtin_amdgcn_mfma_f32_16x16x32_bf16(al, b1h, c1, 0, 0, 0);
    }

#pragma unroll
    for (int v = 0; v < 4; v++) {
        lds_c[w][(l >> 4) * 4 + v][fr] = c0[v];
        lds_c[w][(l >> 4) * 4 + v][16 + fr] = c1[v];
    }
    __syncthreads();

#pragma unroll
    for (int e = tid; e < 512; e += 256) {
        const int rr = e >> 5, cc = e & 31;
        lds_c[0][rr][cc] = lds_c[0][rr][cc] + lds_c[1][rr][cc] +
                           lds_c[2][rr][cc] + lds_c[3][rr][cc];
    }
    __syncthreads();
}

// ---------------------------------------------------------------------------
// band_mfma (fallback path): writes 9 probs per row to band buffer.
// ---------------------------------------------------------------------------
__global__ __launch_bounds__(256) void band_mfma(const float* __restrict__ q,
                                                 const unsigned* __restrict__ tpack,
                                                 const float* __restrict__ beta,
                                                 float* __restrict__ band) {
    __shared__ float lds_c[4][16][33];
    const int tid = threadIdx.x;
    const int r0 = blockIdx.x * 16;
    const int b = r0 >> 11;
    const int i0 = r0 & (LSEQ - 1);
    band_core(q, tpack, r0, b, i0, tid, lds_c);

    if (tid < 16) {
        const int il = i0 + tid;
        const int ig = r0 + tid;
        float lg[NBAND];
#pragma unroll
        for (int d = 0; d < NBAND; d++) {
            const int j = il + d - 4;
            lg[d] = (j >= 0 && j < LSEQ)
                    ? lds_c[0][tid][tid + d] + beta[(size_t)b * LSEQ + j]
                    : -1e30f;
        }
        float m = -1e30f;
#pragma unroll
        for (int d = 0; d < NBAND; d++) m = fmaxf(m, lg[d]);
        float p[NBAND], s = 0.f;
#pragma unroll
        for (int d = 0; d < NBAND; d++) { p[d] = expf(lg[d] - m); s += p[d]; }
        const float inv = 1.f / s;
#pragma unroll
        for (int d = 0; d < NBAND; d++) band[(size_t)ig * NBAND + d] = p[d] * inv;
    }
}

// ---------------------------------------------------------------------------
// band_fuse (ws-large path): computes probs in-block and writes the dense
// 16x2048 output tile directly. tpack lives in d_ws.
// ---------------------------------------------------------------------------
__global__ __launch_bounds__(256) void band_fuse(const float* __restrict__ q,
                                                 const unsigned* __restrict__ tpack,
                                                 const float* __restrict__ beta,
                                                 float* __restrict__ out) {
    __shared__ float lds_c[4][16][33];
    const int tid = threadIdx.x;
    const int r0 = blockIdx.x * 16;
    const int b = r0 >> 11;
    const int i0 = r0 & (LSEQ - 1);
    band_core(q, tpack, r0, b, i0, tid, lds_c);

    float* pr = &lds_c[1][0][0];
    if (tid < 16) {
        const int il = i0 + tid;
        float lg[NBAND];
#pragma unroll
        for (int d = 0; d < NBAND; d++) {
            const int j = il + d - 4;
            lg[d] = (j >= 0 && j < LSEQ)
                    ? lds_c[0][tid][tid + d] + beta[(size_t)b * LSEQ + j]
                    : -1e30f;
        }
        float m = -1e30f;
#pragma unroll
        for (int d = 0; d < NBAND; d++) m = fmaxf(m, lg[d]);
        float p[NBAND], s = 0.f;
#pragma unroll
        for (int d = 0; d < NBAND; d++) { p[d] = expf(lg[d] - m); s += p[d]; }
        const float inv = 1.f / s;
#pragma unroll
        for (int d = 0; d < NBAND; d++) pr[tid * NBAND + d] = p[d] * inv;
    }
    __syncthreads();

    for (int e = tid; e < 8192; e += 256) {
        const int rr = e >> 9;
        const int c0 = (e & 511) * 4;
        const int il = i0 + rr;
        float v[4];
#pragma unroll
        for (int s = 0; s < 4; s++) {
            const int dj = c0 + s - il + 4;
            v[s] = (dj >= 0 && dj < NBAND) ? pr[rr * NBAND + dj] : 0.f;
        }
        float4 o = {v[0], v[1], v[2], v[3]};
        *reinterpret_cast<float4*>(&out[(size_t)(r0 + rr) * LSEQ + c0]) = o;
    }
}

// ---------------------------------------------------------------------------
// Expand band probs into dense [B, L, L] output (fallback path).
// ---------------------------------------------------------------------------
__global__ __launch_bounds__(256) void expand_band(const float* __restrict__ band,
                                                   float* __restrict__ out) {
    const size_t idx4 = (size_t)blockIdx.x * 256 + threadIdx.x;
    const size_t flat = idx4 * 4;
    const int j0 = (int)(flat & (LSEQ - 1));
    const size_t row = flat >> 11;
    const int i = (int)(row & (LSEQ - 1));
    float v[4];
#pragma unroll
    for (int s = 0; s < 4; s++) {
        const int dj = (j0 + s) - i + 4;
        v[s] = (dj >= 0 && dj < NBAND) ? band[row * NBAND + dj] : 0.f;
    }
    float4 o = {v[0], v[1], v[2], v[3]};
    *reinterpret_cast<float4*>(&out[flat]) = o;
}

// ---------------------------------------------------------------------------
// Fallback fp32 path (ws too small).
// ---------------------------------------------------------------------------
__global__ __launch_bounds__(256) void gemm_nt_bias(const float* __restrict__ A,
                                                    const float* __restrict__ B,
                                                    const float* __restrict__ bias,
                                                    float* __restrict__ C) {
    __shared__ float As[8][132];
    __shared__ float Bs[8][132];
    const int tid = threadIdx.x;
    const int row0 = blockIdx.x * 128, col0 = blockIdx.y * 128;
    const int lr = tid >> 1, lc = (tid & 1) * 4;
    const int tx = tid & 15, ty = tid >> 4;
    float acc[2][2][4][4];
#pragma unroll
    for (int a = 0; a < 2; a++)
#pragma unroll
        for (int b = 0; b < 2; b++)
#pragma unroll
            for (int c = 0; c < 4; c++)
#pragma unroll
                for (int d = 0; d < 4; d++) acc[a][b][c][d] = 0.f;
    for (int k0 = 0; k0 < HDIM; k0 += 8) {
        float4 av = *reinterpret_cast<const float4*>(&A[(size_t)(row0 + lr) * HDIM + k0 + lc]);
        float4 bv = *reinterpret_cast<const float4*>(&B[(size_t)(col0 + lr) * HDIM + k0 + lc]);
        __syncthreads();
        As[lc + 0][lr] = av.x; As[lc + 1][lr] = av.y; As[lc + 2][lr] = av.z; As[lc + 3][lr] = av.w;
        Bs[lc + 0][lr] = bv.x; Bs[lc + 1][lr] = bv.y; Bs[lc + 2][lr] = bv.z; Bs[lc + 3][lr] = bv.w;
        __syncthreads();
#pragma unroll
        for (int kk = 0; kk < 8; kk++) {
            float4 a0 = *reinterpret_cast<const float4*>(&As[kk][ty * 4]);
            float4 a1 = *reinterpret_cast<const float4*>(&As[kk][64 + ty * 4]);
            float4 b0 = *reinterpret_cast<const float4*>(&Bs[kk][tx * 4]);
            float4 b1 = *reinterpret_cast<const float4*>(&Bs[kk][64 + tx * 4]);
            float am[2][4] = {{a0.x, a0.y, a0.z, a0.w}, {a1.x, a1.y, a1.z, a1.w}};
            float bw[2][4] = {{b0.x, b0.y, b0.z, b0.w}, {b1.x, b1.y, b1.z, b1.w}};
#pragma unroll
            for (int mi = 0; mi < 2; mi++)
#pragma unroll
                for (int ni = 0; ni < 2; ni++)
#pragma unroll
                    for (int mm = 0; mm < 4; mm++)
#pragma unroll
                        for (int nn = 0; nn < 4; nn++)
                            acc[mi][ni][mm][nn] += am[mi][mm] * bw[ni][nn];
        }
    }
#pragma unroll
    for (int mi = 0; mi < 2; mi++)
#pragma unroll
        for (int mm = 0; mm < 4; mm++) {
            const int r = row0 + mi * 64 + ty * 4 + mm;
#pragma unroll
            for (int ni = 0; ni < 2; ni++) {
                const int c = col0 + ni * 64 + tx * 4;
                float4 o;
                o.x = acc[mi][ni][mm][0] + bias[c + 0];
                o.y = acc[mi][ni][mm][1] + bias[c + 1];
                o.z = acc[mi][ni][mm][2] + bias[c + 2];
                o.w = acc[mi][ni][mm][3] + bias[c + 3];
                *reinterpret_cast<float4*>(&C[(size_t)r * HDIM + c]) = o;
            }
        }
}

__global__ __launch_bounds__(256) void band_softmax(const float* __restrict__ qs,
                                                    const float* __restrict__ ks,
                                                    float* __restrict__ band) {
    const int wave = threadIdx.x >> 6;
    const int lane = threadIdx.x & 63;
    const int r = blockIdx.x * 4 + wave;
    const int b = r >> 11;
    const int i = r & (LSEQ - 1);
    const float* qrow = qs + (size_t)r * HDIM;
    const float* kbase = ks + (size_t)b * LSEQ * HDIM;
    float acc[NBAND];
#pragma unroll
    for (int d = 0; d < NBAND; d++) acc[d] = 0.f;
    for (int h = lane; h < HDIM; h += 64) {
        const float qv = qrow[h];
#pragma unroll
        for (int d = 0; d < NBAND; d++) {
            const int j = i + d - 4;
            if (j >= 0 && j < LSEQ)
                acc[d] += qv * kbase[(size_t)j * HDIM + h];
        }
    }
#pragma unroll
    for (int d = 0; d < NBAND; d++) {
        float v = acc[d];
#pragma unroll
        for (int off = 32; off > 0; off >>= 1) v += __shfl_xor(v, off, 64);
        acc[d] = v;
    }
    if (lane == 0) {
        float m = -1e30f;
#pragma unroll
        for (int d = 0; d < NBAND; d++) {
            const int j = i + d - 4;
            if (j >= 0 && j < LSEQ) m = fmaxf(m, acc[d]);
        }
        float p[NBAND];
        float s = 0.f;
#pragma unroll
        for (int d = 0; d < NBAND; d++) {
            const int j = i + d - 4;
            p[d] = (j >= 0 && j < LSEQ) ? expf(acc[d] - m) : 0.f;
            s += p[d];
        }
        const float inv = 1.f / s;
#pragma unroll
        for (int d = 0; d < NBAND; d++) band[(size_t)r * NBAND + d] = p[d] * inv;
    }
}

extern "C" void kernel_launch(void* const* d_in, const int* in_sizes, int n_in,
                              void* d_out, int out_size, void* d_ws, size_t ws_size,
                              hipStream_t stream) {
    const float* q  = (const float*)d_in[0];
    const float* k  = (const float*)d_in[1];
    const float* Wq = (const float*)d_in[2];
    const float* bq = (const float*)d_in[3];
    const float* Wk = (const float*)d_in[4];
    const float* bk = (const float*)d_in[5];
    float* out = (float*)d_out;

    // ---- workspace layout ----
    const size_t bandB = (size_t)ROWS * NBAND * sizeof(float);
    char* p = (char*)d_ws;
    float* band = (float*)p;                 p += bandB;
    unsigned short* Xhi = (unsigned short*)p; p += (size_t)ROWS * HDIM * 2;   // 16 MB
    unsigned short* Xlo = (unsigned short*)p; p += (size_t)ROWS * HDIM * 2;   // 16 MB
    unsigned short* Mhi = (unsigned short*)p; p += (size_t)HDIM * HDIM * 2;   // 2 MB
    unsigned short* Mlo = (unsigned short*)p; p += (size_t)HDIM * HDIM * 2;   // 2 MB
    float* w        = (float*)p;             p += HDIM * sizeof(float);
    float* wpart    = (float*)p;             p += 64 * HDIM * sizeof(float);
    float* beta     = (float*)p;             p += ROWS * sizeof(float);
    const size_t need = (size_t)(p - (char*)d_ws);
    const size_t tpackOff = (need + 255) & ~(size_t)255;
    const size_t need2 = tpackOff + (size_t)ROWS * HDIM * sizeof(unsigned);   // +32 MB

    unsigned short* WqTh = Xhi;
    unsigned short* WqTl = Xhi + (size_t)HDIM * HDIM;
    unsigned short* WkTh = Xhi + 2 * (size_t)HDIM * HDIM;
    unsigned short* WkTl = Xhi + 3 * (size_t)HDIM * HDIM;

    // Mparts always in d_out [32,48MB) (dead before final output writes)
    float* Mparts = (float*)((char*)out + 32ull * 1024 * 1024);

    if (ws_size >= need) {
        dim3 tg(16, 16, 3);
        tcw_kernel<<<tg, 256, 0, stream>>>(Wq, Wk, bq, WqTh, WqTl, WkTh, WkTl, wpart);
        dim3 mg(8, 8, 4);
        gemm_part<<<mg, 256, 0, stream>>>(WqTh, WqTl, WkTh, WkTl, Mparts);
        reduceMw_convert<<<1028, 256, 0, stream>>>(Mparts, Mhi, Mlo, wpart, w);
        convert_k_beta<<<ROWS / 4, 256, 0, stream>>>(k, w, Xhi, Xlo, beta);
        dim3 gg(ROWS / 128, HDIM / 128);
        if (ws_size >= need2) {
            unsigned* tpack = (unsigned*)((char*)d_ws + tpackOff);
            gemm_t<<<gg, 512, 0, stream>>>(Xhi, Xlo, Mhi, Mlo, tpack);
            band_fuse<<<ROWS / 16, 256, 0, stream>>>(q, tpack, beta, out);
        } else {
            unsigned* tpack = (unsigned*)out;
            gemm_t<<<gg, 512, 0, stream>>>(Xhi, Xlo, Mhi, Mlo, tpack);
            band_mfma<<<ROWS / 16, 256, 0, stream>>>(q, tpack, beta, band);
            expand_band<<<(size_t)ROWS * LSEQ / 4 / 256, 256, 0, stream>>>(band, out);
        }
    } else {
        float* qs = out;
        float* ks = out + (size_t)ROWS * HDIM;
        dim3 gg(ROWS / 128, HDIM / 128);
        gemm_nt_bias<<<gg, 256, 0, stream>>>(q, Wq, bq, qs);
        gemm_nt_bias<<<gg, 256, 0, stream>>>(k, Wk, bk, ks);
        band_softmax<<<ROWS / 4, 256, 0, stream>>>(qs, ks, band);
        expand_band<<<(size_t)ROWS * LSEQ / 4 / 256, 256, 0, stream>>>(band, out);
    }
}